// Round 1
// baseline (3961.336 us; speedup 1.0000x reference)
//
#include <hip/hip_runtime.h>
#include <cstddef>

#define TPB 256

static const int NB   = 32;    // batch
static const int NPIX = 1024;  // 32x32
static const int CIN  = 264;
static const int C1   = 128;
static const int C2   = 256;
static const int VF_  = 258;
static const int DS_  = 300;
static const int LL   = 20;

// ---------------- utility kernels ----------------

__global__ void k_concat(const float* __restrict__ video, const float* __restrict__ spatial,
                         float* __restrict__ x0, int total) {
  int i = blockIdx.x * TPB + threadIdx.x;
  if (i >= total) return;
  int n = i & 1023;
  int t = i >> 10;
  int c = t % CIN;
  int b = t / CIN;
  float v = (c < 256) ? video[(((size_t)b * 256 + c) << 10) + n]
                      : spatial[(((size_t)b * 8 + (c - 256)) << 10) + n];
  x0[i] = v;
}

// out[c][r] = in[r][c]   (tiny weight matrices only)
__global__ void k_transpose(const float* __restrict__ in, float* __restrict__ out, int R, int C) {
  int i = blockIdx.x * TPB + threadIdx.x;
  if (i >= R * C) return;
  int r = i / C, c = i % C;
  out[(size_t)c * R + r] = in[i];
}

// y2(normalized,relu) -> vsoT[b][c][n] (c-major), plus coord channels 256,257
__global__ void k_build_vsoT(const float* __restrict__ y2, float* __restrict__ vsoT, int total) {
  int i = blockIdx.x * TPB + threadIdx.x;
  if (i >= total) return;
  int n = i & 1023;
  int t = i >> 10;
  int c = t % VF_;
  int b = t / VF_;
  float v;
  if (c < 256)      v = y2[(((size_t)b * 256 + c) << 10) + n];
  else if (c == 256) v = -1.f + (2.f / 31.f) * (float)(n & 31);   // xx (width)
  else               v = -1.f + (2.f / 31.f) * (float)(n >> 5);   // yy (height)
  vsoT[i] = v;
}

// mod[b][oc] = sum_d max_l(txt[b][d][l]) * inc_w[oc][d] + inc_b[oc]
__global__ void k_tmaxmod(const float* __restrict__ txt, const float* __restrict__ inc_w,
                          const float* __restrict__ inc_b, float* __restrict__ mod) {
  int b = blockIdx.x;
  __shared__ float tm[DS_];
  for (int d = threadIdx.x; d < DS_; d += TPB) {
    const float* p = txt + ((size_t)b * DS_ + d) * LL;
    float m = p[0];
    for (int l = 1; l < LL; ++l) m = fmaxf(m, p[l]);
    tm[d] = m;
  }
  __syncthreads();
  for (int oc = threadIdx.x; oc < VF_; oc += TPB) {
    const float* wr = inc_w + (size_t)oc * DS_;
    float s = inc_b[oc];
    for (int d = 0; d < DS_; ++d) s += tm[d] * wr[d];
    mod[(size_t)b * VF_ + oc] = s;
  }
}

// ---------------- conv 3x3 (pad 1) ----------------
// block: 16 oc x (4 rows x 32 cols); thread: 4 oc x 2 pixels; IC chunk 8
__global__ __launch_bounds__(TPB) void k_conv3x3(const float* __restrict__ in,
                                                 const float* __restrict__ w,
                                                 const float* __restrict__ bias,
                                                 float* __restrict__ out,
                                                 int Cin, int Cout) {
  const int b   = blockIdx.z;
  const int oc0 = blockIdx.y << 4;
  const int r0  = blockIdx.x << 2;
  const int tid = threadIdx.x;
  const int ocq  = tid >> 6;   // wave id 0..3
  const int lane = tid & 63;
  const int col  = lane & 31;
  const int rowh = lane >> 5;  // 0,1

  __shared__ __align__(16) float in_t[8][6][34];
  __shared__ __align__(16) float w_t[72][17];  // [k][oc_l], padded stride 17

  float acc[4][2];
#pragma unroll
  for (int j = 0; j < 4; ++j) { acc[j][0] = 0.f; acc[j][1] = 0.f; }

  const int nchunks = Cin >> 3;
  for (int cc = 0; cc < nchunks; ++cc) {
    for (int idx = tid; idx < 8 * 6 * 34; idx += TPB) {
      int ic = idx / 204;
      int rem = idx - ic * 204;
      int rr = rem / 34;
      int cx = rem - rr * 34;
      int gy = r0 - 1 + rr;
      int gx = cx - 1;
      float v = 0.f;
      if ((unsigned)gy < 32u && (unsigned)gx < 32u)
        v = in[(((size_t)b * Cin + (cc << 3) + ic) << 10) + (gy << 5) + gx];
      in_t[ic][rr][cx] = v;
    }
    for (int idx = tid; idx < 16 * 72; idx += TPB) {
      int ocl = idx / 72;
      int kk = idx - ocl * 72;
      w_t[kk][ocl] = w[(size_t)(oc0 + ocl) * Cin * 9 + (size_t)cc * 72 + kk];
    }
    __syncthreads();

    for (int icl = 0; icl < 8; ++icl) {
#pragma unroll
      for (int ky = 0; ky < 3; ++ky) {
#pragma unroll
        for (int kx = 0; kx < 3; ++kx) {
          const int kk = icl * 9 + ky * 3 + kx;
          float i0 = in_t[icl][rowh * 2 + ky][col + kx];
          float i1 = in_t[icl][rowh * 2 + 1 + ky][col + kx];
#pragma unroll
          for (int j = 0; j < 4; ++j) {
            float wv = w_t[kk][ocq * 4 + j];
            acc[j][0] += wv * i0;
            acc[j][1] += wv * i1;
          }
        }
      }
    }
    __syncthreads();
  }

#pragma unroll
  for (int j = 0; j < 4; ++j) {
    int oc = oc0 + ocq * 4 + j;
    float bv = bias[oc];
#pragma unroll
    for (int rj = 0; rj < 2; ++rj) {
      int y = r0 + rowh * 2 + rj;
      out[(((size_t)b * Cout + oc) << 10) + (y << 5) + col] = acc[j][rj] + bv;
    }
  }
}

// ---------------- GroupNorm + ReLU, in place ----------------
// grid (32 groups, B); one block per (b, group)
__global__ __launch_bounds__(TPB) void k_gnrelu(float* __restrict__ x,
                                                const float* __restrict__ gamma,
                                                const float* __restrict__ beta,
                                                int C, int cpg) {
  const int g = blockIdx.x, b = blockIdx.y;
  const int M = cpg << 10;
  float* base = x + (((size_t)b * C + g * cpg) << 10);
  float s = 0.f, ss = 0.f;
  for (int i = threadIdx.x; i < M; i += TPB) {
    float v = base[i];
    s += v;
    ss += v * v;
  }
  __shared__ float rs[4], rss[4];
#pragma unroll
  for (int off = 32; off > 0; off >>= 1) {
    s += __shfl_down(s, off);
    ss += __shfl_down(ss, off);
  }
  if ((threadIdx.x & 63) == 0) { rs[threadIdx.x >> 6] = s; rss[threadIdx.x >> 6] = ss; }
  __syncthreads();
  if (threadIdx.x == 0) {
    float S = 0.f, SS = 0.f;
    for (int i = 0; i < 4; ++i) { S += rs[i]; SS += rss[i]; }
    float mean = S / (float)M;
    float var = SS / (float)M - mean * mean;
    rs[0] = mean;
    rss[0] = rsqrtf(var + 1e-5f);
  }
  __syncthreads();
  float mean = rs[0], rsig = rss[0];
  for (int i = threadIdx.x; i < M; i += TPB) {
    int c = g * cpg + (i >> 10);
    float v = (base[i] - mean) * rsig * gamma[c] + beta[c];
    base[i] = v > 0.f ? v : 0.f;
  }
}

// ---------------- generic TN GEMM ----------------
// C[m][n] = (sum_k A[k][m]*B[k][n] + bias[n]) * scale[b][n]
// A batched by strideA, B shared, C batched by strideC. M multiple of 64.
__global__ __launch_bounds__(TPB) void k_gemm_tn(const float* __restrict__ A, size_t strideA, int lda,
                                                 const float* __restrict__ Bm, int ldb,
                                                 float* __restrict__ Cm, size_t strideC, int ldc,
                                                 int M, int N, int K,
                                                 const float* __restrict__ bias,
                                                 const float* __restrict__ scale, int sstride) {
  const int b = blockIdx.z;
  const float* Ab = A + (size_t)b * strideA;
  float* Cb = Cm + (size_t)b * strideC;
  const int n0 = blockIdx.x << 6, m0 = blockIdx.y << 6;
  const int tid = threadIdx.x, tx = tid & 15, ty = tid >> 4;
  __shared__ __align__(16) float As[16][64];
  __shared__ __align__(16) float Bs[16][64];
  float acc[4][4];
#pragma unroll
  for (int i = 0; i < 4; ++i)
#pragma unroll
    for (int j = 0; j < 4; ++j) acc[i][j] = 0.f;

  for (int k0 = 0; k0 < K; k0 += 16) {
    for (int idx = tid; idx < 1024; idx += TPB) {
      int kk = idx >> 6, mm = idx & 63;
      bool kv = (k0 + kk) < K;
      As[kk][mm] = kv ? Ab[(size_t)(k0 + kk) * lda + m0 + mm] : 0.f;
      Bs[kk][mm] = (kv && (n0 + mm) < N) ? Bm[(size_t)(k0 + kk) * ldb + n0 + mm] : 0.f;
    }
    __syncthreads();
#pragma unroll
    for (int kk = 0; kk < 16; ++kk) {
      float4 a = *(const float4*)&As[kk][ty << 2];
      float4 bb = *(const float4*)&Bs[kk][tx << 2];
      float av[4] = {a.x, a.y, a.z, a.w};
      float bv[4] = {bb.x, bb.y, bb.z, bb.w};
#pragma unroll
      for (int i = 0; i < 4; ++i)
#pragma unroll
        for (int j = 0; j < 4; ++j) acc[i][j] += av[i] * bv[j];
    }
    __syncthreads();
  }

#pragma unroll
  for (int j = 0; j < 4; ++j) {
    int n = n0 + (tx << 2) + j;
    if (n >= N) continue;
    float bv = bias ? bias[n] : 0.f;
    float sc = scale ? scale[(size_t)b * sstride + n] : 1.f;
#pragma unroll
    for (int i = 0; i < 4; ++i) {
      int m = m0 + (ty << 2) + i;
      Cb[(size_t)m * ldc + n] = (acc[i][j] + bv) * sc;
    }
  }
}

// ---------------- txt cross-attention ----------------
// per pixel: logits = vsr_row . txt[:,l] /sqrt(300); softmax over 20; out = txt @ p
__global__ __launch_bounds__(TPB) void k_txtattn(const float* __restrict__ vsr,
                                                 const float* __restrict__ txt,
                                                 float* __restrict__ out) {
  const int b = blockIdx.y;
  const int p = blockIdx.x * TPB + threadIdx.x;
  __shared__ float tl[DS_ * LL];
  for (int i = threadIdx.x; i < DS_ * LL; i += TPB) tl[i] = txt[(size_t)b * DS_ * LL + i];
  __syncthreads();
  const float* vr = vsr + ((size_t)b * NPIX + p) * DS_;
  float lg[LL];
#pragma unroll
  for (int l = 0; l < LL; ++l) lg[l] = 0.f;
  for (int d = 0; d < DS_; ++d) {
    float v = vr[d];
    const float* tr = tl + d * LL;
#pragma unroll
    for (int l = 0; l < LL; ++l) lg[l] += v * tr[l];
  }
  const float sc = 0.057735026919f;  // 1/sqrt(300)
  float mx = lg[0] * sc;
#pragma unroll
  for (int l = 1; l < LL; ++l) mx = fmaxf(mx, lg[l] * sc);
  float sum = 0.f;
#pragma unroll
  for (int l = 0; l < LL; ++l) {
    lg[l] = __expf(lg[l] * sc - mx);
    sum += lg[l];
  }
  float inv = 1.f / sum;
#pragma unroll
  for (int l = 0; l < LL; ++l) lg[l] *= inv;
  float* ob = out + (((size_t)b * 558 + VF_) << 10) + p;
  for (int d = 0; d < DS_; ++d) {
    const float* tr = tl + d * LL;
    float s = 0.f;
#pragma unroll
    for (int l = 0; l < LL; ++l) s += lg[l] * tr[l];
    ob[(size_t)d << 10] = s;
  }
}

// ---------------- video self-attention (online softmax flash, fp32) ----------------
// score[n,m] = k[n].q[m]/sqrt(258); softmax over m; out[n] = sum_m p*v[m]
// block: (b, 16 n-rows); chunks of 16 m. D padded to 260 (65 float4, odd -> bank spread).
__global__ __launch_bounds__(TPB) void k_flash(const float* __restrict__ Km,
                                               const float* __restrict__ Qm,
                                               const float* __restrict__ Vm,
                                               float* __restrict__ out) {
  const int b = blockIdx.y;
  const int r0 = blockIdx.x << 4;
  const int tid = threadIdx.x;
  const int r = tid & 15;
  const int dg = tid >> 4;  // 0..15

  __shared__ __align__(16) float k_l[16][260];
  __shared__ __align__(16) float q_l[16][260];
  __shared__ __align__(16) float v_l[16][260];
  __shared__ float s_l[16][16];
  __shared__ float p_l[16][16];
  __shared__ float mrow[16], lrow[16], arow[16];

  for (int idx = tid; idx < 16 * 260; idx += TPB) {
    int rr = idx / 260, d = idx - rr * 260;
    k_l[rr][d] = (d < VF_) ? Km[((size_t)(b * NPIX + r0 + rr)) * VF_ + d] : 0.f;
  }
  if (tid < 16) { mrow[tid] = -1e30f; lrow[tid] = 0.f; }

  float4 a0 = {0, 0, 0, 0}, a1 = {0, 0, 0, 0}, a2 = {0, 0, 0, 0}, a3 = {0, 0, 0, 0}, a4 = {0, 0, 0, 0};
  const float sc = 0.0622572819f;  // 1/sqrt(258)

  for (int c0 = 0; c0 < NPIX; c0 += 16) {
    for (int idx = tid; idx < 16 * 260; idx += TPB) {
      int m = idx / 260, d = idx - m * 260;
      float qv = 0.f, vv = 0.f;
      if (d < VF_) {
        size_t base = ((size_t)(b * NPIX + c0 + m)) * VF_ + d;
        qv = Qm[base];
        vv = Vm[base];
      }
      q_l[m][d] = qv;
      v_l[m][d] = vv;
    }
    __syncthreads();
    {
      float s = 0.f;
      const float* kr = k_l[r];
      const float* qr = q_l[dg];
#pragma unroll
      for (int f = 0; f < 65; ++f) {
        float4 ka = *(const float4*)(kr + (f << 2));
        float4 qa = *(const float4*)(qr + (f << 2));
        s += ka.x * qa.x + ka.y * qa.y + ka.z * qa.z + ka.w * qa.w;
      }
      s_l[r][dg] = s * sc;
    }
    __syncthreads();
    if (tid < 16) {
      float mold = mrow[tid];
      float mx = mold;
#pragma unroll
      for (int j = 0; j < 16; ++j) mx = fmaxf(mx, s_l[tid][j]);
      float alpha = __expf(mold - mx);
      float ls = lrow[tid] * alpha;
#pragma unroll
      for (int j = 0; j < 16; ++j) {
        float pj = __expf(s_l[tid][j] - mx);
        p_l[tid][j] = pj;
        ls += pj;
      }
      mrow[tid] = mx;
      lrow[tid] = ls;
      arow[tid] = alpha;
    }
    __syncthreads();
    {
      float alpha = arow[r];
      a0.x *= alpha; a0.y *= alpha; a0.z *= alpha; a0.w *= alpha;
      a1.x *= alpha; a1.y *= alpha; a1.z *= alpha; a1.w *= alpha;
      a2.x *= alpha; a2.y *= alpha; a2.z *= alpha; a2.w *= alpha;
      a3.x *= alpha; a3.y *= alpha; a3.z *= alpha; a3.w *= alpha;
      a4.x *= alpha; a4.y *= alpha;
      const float* pr = p_l[r];
#pragma unroll
      for (int m = 0; m < 16; ++m) {
        float pv = pr[m];
        const float* vrp = v_l[m] + (dg << 4);
        float4 v0 = *(const float4*)(vrp);
        float4 v1 = *(const float4*)(vrp + 4);
        float4 v2 = *(const float4*)(vrp + 8);
        float4 v3 = *(const float4*)(vrp + 12);
        a0.x += pv * v0.x; a0.y += pv * v0.y; a0.z += pv * v0.z; a0.w += pv * v0.w;
        a1.x += pv * v1.x; a1.y += pv * v1.y; a1.z += pv * v1.z; a1.w += pv * v1.w;
        a2.x += pv * v2.x; a2.y += pv * v2.y; a2.z += pv * v2.z; a2.w += pv * v2.w;
        a3.x += pv * v3.x; a3.y += pv * v3.y; a3.z += pv * v3.z; a3.w += pv * v3.w;
        if (dg == 15) {
          float4 v4 = *(const float4*)&v_l[m][256];
          a4.x += pv * v4.x;
          a4.y += pv * v4.y;
        }
      }
    }
    __syncthreads();
  }

  float inv = 1.f / lrow[r];
  const size_t ob = ((size_t)b * 558) << 10;
  const int d0 = dg << 4;
  const int nn = r0 + r;
#define ST(j, val) out[ob + ((size_t)(d0 + (j)) << 10) + nn] = (val) * inv;
  ST(0, a0.x) ST(1, a0.y) ST(2, a0.z) ST(3, a0.w)
  ST(4, a1.x) ST(5, a1.y) ST(6, a1.z) ST(7, a1.w)
  ST(8, a2.x) ST(9, a2.y) ST(10, a2.z) ST(11, a2.w)
  ST(12, a3.x) ST(13, a3.y) ST(14, a3.z) ST(15, a3.w)
#undef ST
  if (dg == 15) {
    out[ob + ((size_t)256 << 10) + nn] = a4.x * inv;
    out[ob + ((size_t)257 << 10) + nn] = a4.y * inv;
  }
}

// ---------------- launcher ----------------
extern "C" void kernel_launch(void* const* d_in, const int* in_sizes, int n_in,
                              void* d_out, int out_size, void* d_ws, size_t ws_size,
                              hipStream_t stream) {
  const float* spatial = (const float*)d_in[0];
  const float* video   = (const float*)d_in[1];
  const float* txt     = (const float*)d_in[2];
  const float* c1w = (const float*)d_in[3];
  const float* c1b = (const float*)d_in[4];
  const float* g1g = (const float*)d_in[5];
  const float* g1b = (const float*)d_in[6];
  const float* c2w = (const float*)d_in[7];
  const float* c2b = (const float*)d_in[8];
  const float* g2g = (const float*)d_in[9];
  const float* g2b = (const float*)d_in[10];
  const float* rw  = (const float*)d_in[11];
  const float* rb  = (const float*)d_in[12];
  const float* kw  = (const float*)d_in[13];
  const float* kb  = (const float*)d_in[14];
  const float* qw  = (const float*)d_in[15];
  const float* qb  = (const float*)d_in[16];
  const float* vw  = (const float*)d_in[17];
  const float* vb  = (const float*)d_in[18];
  const float* iw  = (const float*)d_in[19];
  const float* ib  = (const float*)d_in[20];
  float* out = (float*)d_out;
  float* ws = (float*)d_ws;

  // ws layout (floats), lifetime-aliased; total ~37.42M floats (~150 MB)
  float* x0   = ws + 0;         // 8,650,752   [concat -> conv1]
  float* vsr  = ws + 0;         // 9,830,400   [after conv1 done]
  float* kbuf = ws + 0;         // 8,454,144   [after txtattn done]
  float* y1   = ws + 10000000;  // 4,194,304
  float* qbuf = ws + 10000000;  // 8,454,144   [after conv2 done]
  float* y2   = ws + 19000000;  // 8,388,608
  float* vbuf = ws + 19000000;  // 8,454,144   [after vsoT built]
  float* vsoT = ws + 28000000;  // 8,454,144
  float* rwT  = ws + 37000000;  // 77,400
  float* kwT  = ws + 37100000;  // 66,564
  float* qwT  = ws + 37200000;  // 66,564
  float* vwT  = ws + 37300000;  // 66,564
  float* mod  = ws + 37400000;  // 8,256

  // weight transposes to k-major
  k_transpose<<<(300 * 258 + TPB - 1) / TPB, TPB, 0, stream>>>(rw, rwT, 300, 258);
  k_transpose<<<(258 * 258 + TPB - 1) / TPB, TPB, 0, stream>>>(kw, kwT, 258, 258);
  k_transpose<<<(258 * 258 + TPB - 1) / TPB, TPB, 0, stream>>>(qw, qwT, 258, 258);
  k_transpose<<<(258 * 258 + TPB - 1) / TPB, TPB, 0, stream>>>(vw, vwT, 258, 258);

  // concat inputs
  {
    int tot = NB * CIN * NPIX;
    k_concat<<<(tot + TPB - 1) / TPB, TPB, 0, stream>>>(video, spatial, x0, tot);
  }

  // conv1 + GN1 + relu
  k_conv3x3<<<dim3(8, C1 / 16, NB), TPB, 0, stream>>>(x0, c1w, c1b, y1, CIN, C1);
  k_gnrelu<<<dim3(32, NB), TPB, 0, stream>>>(y1, g1g, g1b, C1, 4);

  // conv2 + GN2 + relu
  k_conv3x3<<<dim3(8, C2 / 16, NB), TPB, 0, stream>>>(y1, c2w, c2b, y2, C1, C2);
  k_gnrelu<<<dim3(32, NB), TPB, 0, stream>>>(y2, g2g, g2b, C2, 8);

  // vsoT (c-major features + coords)
  {
    int tot = NB * VF_ * NPIX;
    k_build_vsoT<<<(tot + TPB - 1) / TPB, TPB, 0, stream>>>(y2, vsoT, tot);
  }

  // mod vector
  k_tmaxmod<<<NB, TPB, 0, stream>>>(txt, iw, ib, mod);

  // vsr = vso @ reduce_w^T + reduce_b   (M=1024, N=300, K=258)
  k_gemm_tn<<<dim3(5, 16, NB), TPB, 0, stream>>>(vsoT, (size_t)VF_ * NPIX, NPIX, rwT, DS_,
                                                 vsr, (size_t)NPIX * DS_, DS_,
                                                 NPIX, DS_, VF_, rb, nullptr, 0);

  // txt attention -> out channels [258, 558)
  k_txtattn<<<dim3(4, NB), TPB, 0, stream>>>(vsr, txt, out);

  // k, q, v projections (M=1024, N=258, K=258)
  k_gemm_tn<<<dim3(5, 16, NB), TPB, 0, stream>>>(vsoT, (size_t)VF_ * NPIX, NPIX, kwT, VF_,
                                                 kbuf, (size_t)NPIX * VF_, VF_,
                                                 NPIX, VF_, VF_, kb, mod, VF_);
  k_gemm_tn<<<dim3(5, 16, NB), TPB, 0, stream>>>(vsoT, (size_t)VF_ * NPIX, NPIX, qwT, VF_,
                                                 qbuf, (size_t)NPIX * VF_, VF_,
                                                 NPIX, VF_, VF_, qb, mod, VF_);
  k_gemm_tn<<<dim3(5, 16, NB), TPB, 0, stream>>>(vsoT, (size_t)VF_ * NPIX, NPIX, vwT, VF_,
                                                 vbuf, (size_t)NPIX * VF_, VF_,
                                                 NPIX, VF_, VF_, vb, nullptr, 0);

  // video self-attention -> out channels [0, 258)
  k_flash<<<dim3(64, NB), TPB, 0, stream>>>(kbuf, qbuf, vbuf, out);
}

// Round 3
// 1773.201 us; speedup vs baseline: 2.2340x; 2.2340x over previous
//
#include <hip/hip_runtime.h>
#include <cstddef>

#define TPB 256

typedef unsigned short ushort_t;
typedef __attribute__((ext_vector_type(8))) short s8v;
typedef __attribute__((ext_vector_type(4))) float f4v;

#define MFMA16(a, b, c) __builtin_amdgcn_mfma_f32_16x16x32_bf16((a), (b), (c), 0, 0, 0)

static const int NB   = 32;    // batch
static const int NPIX = 1024;  // 32x32
static const int CIN  = 264;
static const int C1   = 128;
static const int C2   = 256;
static const int VF_  = 258;
static const int DS_  = 300;
static const int LL   = 20;

__device__ __forceinline__ ushort_t f2b(float x) {
  unsigned u = __builtin_bit_cast(unsigned, x);
  u = (u + 0x7fffu + ((u >> 16) & 1u)) >> 16;
  return (ushort_t)u;
}

// ---------------- utility kernels ----------------

__global__ void k_concat(const float* __restrict__ video, const float* __restrict__ spatial,
                         float* __restrict__ x0, int total) {
  int i = blockIdx.x * TPB + threadIdx.x;
  if (i >= total) return;
  int n = i & 1023;
  int t = i >> 10;
  int c = t % CIN;
  int b = t / CIN;
  float v = (c < 256) ? video[(((size_t)b * 256 + c) << 10) + n]
                      : spatial[(((size_t)b * 8 + (c - 256)) << 10) + n];
  x0[i] = v;
}

__global__ void k_transpose(const float* __restrict__ in, float* __restrict__ out, int R, int C) {
  int i = blockIdx.x * TPB + threadIdx.x;
  if (i >= R * C) return;
  int r = i / C, c = i % C;
  out[(size_t)c * R + r] = in[i];
}

__global__ void k_build_vsoT(const float* __restrict__ y2, float* __restrict__ vsoT, int total) {
  int i = blockIdx.x * TPB + threadIdx.x;
  if (i >= total) return;
  int n = i & 1023;
  int t = i >> 10;
  int c = t % VF_;
  int b = t / VF_;
  float v;
  if (c < 256)      v = y2[(((size_t)b * 256 + c) << 10) + n];
  else if (c == 256) v = -1.f + (2.f / 31.f) * (float)(n & 31);
  else               v = -1.f + (2.f / 31.f) * (float)(n >> 5);
  vsoT[i] = v;
}

__global__ void k_tmaxmod(const float* __restrict__ txt, const float* __restrict__ inc_w,
                          const float* __restrict__ inc_b, float* __restrict__ mod) {
  int b = blockIdx.x;
  __shared__ float tm[DS_];
  for (int d = threadIdx.x; d < DS_; d += TPB) {
    const float* p = txt + ((size_t)b * DS_ + d) * LL;
    float m = p[0];
    for (int l = 1; l < LL; ++l) m = fmaxf(m, p[l]);
    tm[d] = m;
  }
  __syncthreads();
  for (int oc = threadIdx.x; oc < VF_; oc += TPB) {
    const float* wr = inc_w + (size_t)oc * DS_;
    float s = inc_b[oc];
    for (int d = 0; d < DS_; ++d) s += tm[d] * wr[d];
    mod[(size_t)b * VF_ + oc] = s;
  }
}

// ---------------- conv 3x3 (pad 1) ----------------
__global__ __launch_bounds__(TPB) void k_conv3x3(const float* __restrict__ in,
                                                 const float* __restrict__ w,
                                                 const float* __restrict__ bias,
                                                 float* __restrict__ out,
                                                 int Cin, int Cout) {
  const int b   = blockIdx.z;
  const int oc0 = blockIdx.y << 4;
  const int r0  = blockIdx.x << 2;
  const int tid = threadIdx.x;
  const int ocq  = tid >> 6;
  const int lane = tid & 63;
  const int col  = lane & 31;
  const int rowh = lane >> 5;

  __shared__ __align__(16) float in_t[8][6][34];
  __shared__ __align__(16) float w_t[72][17];

  float acc[4][2];
#pragma unroll
  for (int j = 0; j < 4; ++j) { acc[j][0] = 0.f; acc[j][1] = 0.f; }

  const int nchunks = Cin >> 3;
  for (int cc = 0; cc < nchunks; ++cc) {
    for (int idx = tid; idx < 8 * 6 * 34; idx += TPB) {
      int ic = idx / 204;
      int rem = idx - ic * 204;
      int rr = rem / 34;
      int cx = rem - rr * 34;
      int gy = r0 - 1 + rr;
      int gx = cx - 1;
      float v = 0.f;
      if ((unsigned)gy < 32u && (unsigned)gx < 32u)
        v = in[(((size_t)b * Cin + (cc << 3) + ic) << 10) + (gy << 5) + gx];
      in_t[ic][rr][cx] = v;
    }
    for (int idx = tid; idx < 16 * 72; idx += TPB) {
      int ocl = idx / 72;
      int kk = idx - ocl * 72;
      w_t[kk][ocl] = w[(size_t)(oc0 + ocl) * Cin * 9 + (size_t)cc * 72 + kk];
    }
    __syncthreads();

    for (int icl = 0; icl < 8; ++icl) {
#pragma unroll
      for (int ky = 0; ky < 3; ++ky) {
#pragma unroll
        for (int kx = 0; kx < 3; ++kx) {
          const int kk = icl * 9 + ky * 3 + kx;
          float i0 = in_t[icl][rowh * 2 + ky][col + kx];
          float i1 = in_t[icl][rowh * 2 + 1 + ky][col + kx];
#pragma unroll
          for (int j = 0; j < 4; ++j) {
            float wv = w_t[kk][ocq * 4 + j];
            acc[j][0] += wv * i0;
            acc[j][1] += wv * i1;
          }
        }
      }
    }
    __syncthreads();
  }

#pragma unroll
  for (int j = 0; j < 4; ++j) {
    int oc = oc0 + ocq * 4 + j;
    float bv = bias[oc];
#pragma unroll
    for (int rj = 0; rj < 2; ++rj) {
      int y = r0 + rowh * 2 + rj;
      out[(((size_t)b * Cout + oc) << 10) + (y << 5) + col] = acc[j][rj] + bv;
    }
  }
}

// ---------------- GroupNorm + ReLU, in place ----------------
__global__ __launch_bounds__(TPB) void k_gnrelu(float* __restrict__ x,
                                                const float* __restrict__ gamma,
                                                const float* __restrict__ beta,
                                                int C, int cpg) {
  const int g = blockIdx.x, b = blockIdx.y;
  const int M = cpg << 10;
  float* base = x + (((size_t)b * C + g * cpg) << 10);
  float s = 0.f, ss = 0.f;
  for (int i = threadIdx.x; i < M; i += TPB) {
    float v = base[i];
    s += v;
    ss += v * v;
  }
  __shared__ float rs[4], rss[4];
#pragma unroll
  for (int off = 32; off > 0; off >>= 1) {
    s += __shfl_down(s, off);
    ss += __shfl_down(ss, off);
  }
  if ((threadIdx.x & 63) == 0) { rs[threadIdx.x >> 6] = s; rss[threadIdx.x >> 6] = ss; }
  __syncthreads();
  if (threadIdx.x == 0) {
    float S = 0.f, SS = 0.f;
    for (int i = 0; i < 4; ++i) { S += rs[i]; SS += rss[i]; }
    float mean = S / (float)M;
    float var = SS / (float)M - mean * mean;
    rs[0] = mean;
    rss[0] = rsqrtf(var + 1e-5f);
  }
  __syncthreads();
  float mean = rs[0], rsig = rss[0];
  for (int i = threadIdx.x; i < M; i += TPB) {
    int c = g * cpg + (i >> 10);
    float v = (base[i] - mean) * rsig * gamma[c] + beta[c];
    base[i] = v > 0.f ? v : 0.f;
  }
}

// ---------------- generic TN GEMM, templated epilogue ----------------
// MODE 0: float out [m][N] (+bias)                       (vsr)
// MODE 1: bf16 out [m][288], (acc+bias)*mod[b][n], pad 0  (k, q)
// MODE 2: bf16 out [n][1024] transposed, pad rows 0       (v)
template <int MODE>
__global__ __launch_bounds__(TPB) void k_gemm_tn(const float* __restrict__ A, size_t strideA, int lda,
                                                 const float* __restrict__ Bm, int ldb,
                                                 void* __restrict__ Cout,
                                                 int M, int N, int K,
                                                 const float* __restrict__ bias,
                                                 const float* __restrict__ scale) {
  const int b = blockIdx.z;
  const float* Ab = A + (size_t)b * strideA;
  const int n0 = blockIdx.x << 6, m0 = blockIdx.y << 6;
  const int tid = threadIdx.x, tx = tid & 15, ty = tid >> 4;
  __shared__ __align__(16) float As[16][64];
  __shared__ __align__(16) float Bs[16][64];
  float acc[4][4];
#pragma unroll
  for (int i = 0; i < 4; ++i)
#pragma unroll
    for (int j = 0; j < 4; ++j) acc[i][j] = 0.f;

  for (int k0 = 0; k0 < K; k0 += 16) {
    for (int idx = tid; idx < 1024; idx += TPB) {
      int kk = idx >> 6, mm = idx & 63;
      bool kv = (k0 + kk) < K;
      As[kk][mm] = kv ? Ab[(size_t)(k0 + kk) * lda + m0 + mm] : 0.f;
      Bs[kk][mm] = (kv && (n0 + mm) < N) ? Bm[(size_t)(k0 + kk) * ldb + n0 + mm] : 0.f;
    }
    __syncthreads();
#pragma unroll
    for (int kk = 0; kk < 16; ++kk) {
      float4 a = *(const float4*)&As[kk][ty << 2];
      float4 bb = *(const float4*)&Bs[kk][tx << 2];
      float av[4] = {a.x, a.y, a.z, a.w};
      float bv[4] = {bb.x, bb.y, bb.z, bb.w};
#pragma unroll
      for (int i = 0; i < 4; ++i)
#pragma unroll
        for (int j = 0; j < 4; ++j) acc[i][j] += av[i] * bv[j];
    }
    __syncthreads();
  }

#pragma unroll
  for (int j = 0; j < 4; ++j) {
    int n = n0 + (tx << 2) + j;
    if (MODE == 0) {
      if (n >= N) continue;
      float* Cb = (float*)Cout + (size_t)b * M * N;
      float bv = bias[n];
#pragma unroll
      for (int i = 0; i < 4; ++i) {
        int m = m0 + (ty << 2) + i;
        Cb[(size_t)m * N + n] = acc[i][j] + bv;
      }
    } else if (MODE == 1) {
      if (n >= 288) continue;
      ushort_t* Cb = (ushort_t*)Cout + (size_t)b * 1024 * 288;
      bool real = n < VF_;
      float bv = real ? bias[n] : 0.f;
      float sc = real ? scale[(size_t)b * VF_ + n] : 0.f;
#pragma unroll
      for (int i = 0; i < 4; ++i) {
        int m = m0 + (ty << 2) + i;
        Cb[(size_t)m * 288 + n] = f2b(real ? (acc[i][j] + bv) * sc : 0.f);
      }
    } else {
      if (n >= 272) continue;
      ushort_t* Cb = (ushort_t*)Cout + (size_t)b * 272 * 1024;
      bool real = n < VF_;
      float bv = real ? bias[n] : 0.f;
#pragma unroll
      for (int i = 0; i < 4; ++i) {
        int m = m0 + (ty << 2) + i;
        Cb[((size_t)n << 10) + m] = f2b(real ? acc[i][j] + bv : 0.f);
      }
    }
  }
}

// ---------------- txt cross-attention ----------------
__global__ __launch_bounds__(TPB) void k_txtattn(const float* __restrict__ vsr,
                                                 const float* __restrict__ txt,
                                                 float* __restrict__ out) {
  const int b = blockIdx.y;
  const int p = blockIdx.x * TPB + threadIdx.x;
  __shared__ float tl[DS_ * LL];
  for (int i = threadIdx.x; i < DS_ * LL; i += TPB) tl[i] = txt[(size_t)b * DS_ * LL + i];
  __syncthreads();
  const float* vr = vsr + ((size_t)b * NPIX + p) * DS_;
  float lg[LL];
#pragma unroll
  for (int l = 0; l < LL; ++l) lg[l] = 0.f;
  for (int d = 0; d < DS_; ++d) {
    float v = vr[d];
    const float* tr = tl + d * LL;
#pragma unroll
    for (int l = 0; l < LL; ++l) lg[l] += v * tr[l];
  }
  const float sc = 0.057735026919f;
  float mx = lg[0] * sc;
#pragma unroll
  for (int l = 1; l < LL; ++l) mx = fmaxf(mx, lg[l] * sc);
  float sum = 0.f;
#pragma unroll
  for (int l = 0; l < LL; ++l) {
    lg[l] = __expf(lg[l] * sc - mx);
    sum += lg[l];
  }
  float inv = 1.f / sum;
#pragma unroll
  for (int l = 0; l < LL; ++l) lg[l] *= inv;
  float* ob = out + (((size_t)b * 558 + VF_) << 10) + p;
  for (int d = 0; d < DS_; ++d) {
    const float* tr = tl + d * LL;
    float s = 0.f;
#pragma unroll
    for (int l = 0; l < LL; ++l) s += lg[l] * tr[l];
    ob[(size_t)d << 10] = s;
  }
}

// ---------------- video self-attention: bf16 MFMA flash ----------------
// K,Q: bf16 [b][1024][288] (zero-padded d>=258). Vt: bf16 [b][272][1024].
// Block: 64 n-rows, 4 waves (16 rows each). Chunks of 32 m.
__global__ __launch_bounds__(256, 2) void k_flash_mfma(const ushort_t* __restrict__ Kb,
                                                       const ushort_t* __restrict__ Qb,
                                                       const ushort_t* __restrict__ Vtb,
                                                       float* __restrict__ out) {
  const int b = blockIdx.y;
  const int n0 = blockIdx.x << 6;
  const int tid = threadIdx.x;
  const int w = tid >> 6, lane = tid & 63;
  const int lhi = lane >> 4;   // 0..3
  const int llo = lane & 15;   // 0..15

  __shared__ ushort_t q_l[32][296];   // stride 296 -> 2-way banks
  __shared__ ushort_t vt_l[272][40];  // stride 40  -> 2-way banks
  __shared__ ushort_t p_l[64][40];

  // K fragments in registers: rows n0 + w*16 + llo, 9 k-steps of 32
  s8v kf[9];
  {
    const ushort_t* kp = Kb + ((size_t)(b * 1024 + n0 + w * 16 + llo)) * 288 + lhi * 8;
#pragma unroll
    for (int ks = 0; ks < 9; ++ks) kf[ks] = *(const s8v*)(kp + ks * 32);
  }

  f4v oacc[17];
#pragma unroll
  for (int i = 0; i < 17; ++i) oacc[i] = (f4v){0.f, 0.f, 0.f, 0.f};
  float mreg[4], lreg[4];
#pragma unroll
  for (int r = 0; r < 4; ++r) { mreg[r] = -1e30f; lreg[r] = 0.f; }

  const float sc = 0.0622572819f;  // 1/sqrt(258)
  const int src16 = ((llo >> 2) << 4) | (llo & 3);  // shfl source for row (llo)

  for (int mc = 0; mc < 32; ++mc) {
    const int m0 = mc << 5;
    __syncthreads();
    // stage Q tile [32][288] : 32 rows x 36 s8v chunks = 1152
    for (int u = tid; u < 1152; u += 256) {
      int row = u / 36, ch = u - row * 36;
      *(s8v*)&q_l[row][ch * 8] =
          *(const s8v*)(Qb + ((size_t)(b * 1024 + m0 + row)) * 288 + ch * 8);
    }
    // stage Vt tile [272][32]
    for (int r = tid; r < 272; r += 256) {
      const ushort_t* src = Vtb + ((size_t)(b * 272 + r) << 10) + m0;
      *(s8v*)&vt_l[r][0]  = *(const s8v*)(src);
      *(s8v*)&vt_l[r][8]  = *(const s8v*)(src + 8);
      *(s8v*)&vt_l[r][16] = *(const s8v*)(src + 16);
      *(s8v*)&vt_l[r][24] = *(const s8v*)(src + 24);
    }
    __syncthreads();

    // QK^T -> S ; lane holds S[n_local = lhi*4+r][m_local = llo (+16)]
    f4v sacc0 = {0.f, 0.f, 0.f, 0.f}, sacc1 = {0.f, 0.f, 0.f, 0.f};
#pragma unroll
    for (int ks = 0; ks < 9; ++ks) {
      s8v q0 = *(const s8v*)&q_l[llo][ks * 32 + lhi * 8];
      s8v q1 = *(const s8v*)&q_l[16 + llo][ks * 32 + lhi * 8];
      sacc0 = MFMA16(kf[ks], q0, sacc0);
      sacc1 = MFMA16(kf[ks], q1, sacc1);
    }

    // wave-parallel online softmax (rows = lhi*4 + r)
    float cmax[4], rsum[4], alpha[4];
#pragma unroll
    for (int r = 0; r < 4; ++r) cmax[r] = fmaxf(sacc0[r], sacc1[r]);
#pragma unroll
    for (int off = 1; off < 16; off <<= 1)
#pragma unroll
      for (int r = 0; r < 4; ++r) cmax[r] = fmaxf(cmax[r], __shfl_xor(cmax[r], off));
#pragma unroll
    for (int r = 0; r < 4; ++r) {
      float mn = fmaxf(mreg[r], cmax[r] * sc);
      alpha[r] = __expf(mreg[r] - mn);
      mreg[r] = mn;
    }
    const int prow = w * 16 + lhi * 4;
#pragma unroll
    for (int r = 0; r < 4; ++r) {
      float p0 = __expf(sacc0[r] * sc - mreg[r]);
      float p1 = __expf(sacc1[r] * sc - mreg[r]);
      rsum[r] = p0 + p1;
      p_l[prow + r][llo] = f2b(p0);
      p_l[prow + r][16 + llo] = f2b(p1);
    }
#pragma unroll
    for (int off = 1; off < 16; off <<= 1)
#pragma unroll
      for (int r = 0; r < 4; ++r) rsum[r] += __shfl_xor(rsum[r], off);
#pragma unroll
    for (int r = 0; r < 4; ++r) lreg[r] = lreg[r] * alpha[r] + rsum[r];

    // redistribute alpha to column(n) layout for the O accumulator
    float prep = (lane & 2) ? ((lane & 1) ? alpha[3] : alpha[2])
                            : ((lane & 1) ? alpha[1] : alpha[0]);
    float alphaN = __shfl(prep, src16, 64);

    asm volatile("s_waitcnt lgkmcnt(0)" ::: "memory");
    __builtin_amdgcn_sched_barrier(0);

    // PV (swapped operands): O^T[d][n] += Vt_tile * P
    s8v pf = *(const s8v*)&p_l[w * 16 + llo][lhi * 8];
#pragma unroll
    for (int dt = 0; dt < 17; ++dt) {
      s8v vf = *(const s8v*)&vt_l[dt * 16 + llo][lhi * 8];
      f4v o = oacc[dt];
      o[0] *= alphaN; o[1] *= alphaN; o[2] *= alphaN; o[3] *= alphaN;
      oacc[dt] = MFMA16(vf, pf, o);
    }
  }

  // epilogue: divide by l, store (coalesced over n)
  float prep = (lane & 2) ? ((lane & 1) ? lreg[3] : lreg[2])
                          : ((lane & 1) ? lreg[1] : lreg[0]);
  float linv = 1.f / __shfl(prep, src16, 64);
  const int n = n0 + w * 16 + llo;
#pragma unroll
  for (int dt = 0; dt < 17; ++dt) {
#pragma unroll
    for (int r = 0; r < 4; ++r) {
      int d = dt * 16 + lhi * 4 + r;
      if (d < VF_) out[((size_t)(b * 558 + d) << 10) + n] = oacc[dt][r] * linv;
    }
  }
}

// ---------------- launcher ----------------
extern "C" void kernel_launch(void* const* d_in, const int* in_sizes, int n_in,
                              void* d_out, int out_size, void* d_ws, size_t ws_size,
                              hipStream_t stream) {
  const float* spatial = (const float*)d_in[0];
  const float* video   = (const float*)d_in[1];
  const float* txt     = (const float*)d_in[2];
  const float* c1w = (const float*)d_in[3];
  const float* c1b = (const float*)d_in[4];
  const float* g1g = (const float*)d_in[5];
  const float* g1b = (const float*)d_in[6];
  const float* c2w = (const float*)d_in[7];
  const float* c2b = (const float*)d_in[8];
  const float* g2g = (const float*)d_in[9];
  const float* g2b = (const float*)d_in[10];
  const float* rw  = (const float*)d_in[11];
  const float* rb  = (const float*)d_in[12];
  const float* kw  = (const float*)d_in[13];
  const float* kb  = (const float*)d_in[14];
  const float* qw  = (const float*)d_in[15];
  const float* qb  = (const float*)d_in[16];
  const float* vw  = (const float*)d_in[17];
  const float* vb  = (const float*)d_in[18];
  const float* iw  = (const float*)d_in[19];
  const float* ib  = (const float*)d_in[20];
  float* out = (float*)d_out;
  float* ws = (float*)d_ws;

  // ws layout (float indices), lifetime-aliased
  float*    x0    = ws + 0;           // 8,650,752   [-> conv1]
  float*    vsr   = ws + 0;           // 9,830,400   [after conv1]
  float*    y1    = ws + 10000000;    // 4,194,304   [-> conv2]
  ushort_t* kb16  = (ushort_t*)(ws + 10000000);  // 9,437,184 us  [after conv2]
  ushort_t* vtb16 = (ushort_t*)(ws + 14800000);  // 8,912,896 us  [after vsoT built]
  float*    y2    = ws + 19000000;    // 8,388,608   [-> vsoT]
  ushort_t* qb16  = (ushort_t*)(ws + 19300000);  // 9,437,184 us  [after vsoT built]
  float*    vsoT  = ws + 28000000;    // 8,454,144
  float*    rwT   = ws + 36500000;    // 77,400
  float*    kwT   = ws + 36600000;    // 66,564
  float*    qwT   = ws + 36700000;    // 66,564
  float*    vwT   = ws + 36800000;    // 66,564
  float*    mod   = ws + 36900000;    // 8,256

  k_transpose<<<(300 * 258 + TPB - 1) / TPB, TPB, 0, stream>>>(rw, rwT, 300, 258);
  k_transpose<<<(258 * 258 + TPB - 1) / TPB, TPB, 0, stream>>>(kw, kwT, 258, 258);
  k_transpose<<<(258 * 258 + TPB - 1) / TPB, TPB, 0, stream>>>(qw, qwT, 258, 258);
  k_transpose<<<(258 * 258 + TPB - 1) / TPB, TPB, 0, stream>>>(vw, vwT, 258, 258);

  {
    int tot = NB * CIN * NPIX;
    k_concat<<<(tot + TPB - 1) / TPB, TPB, 0, stream>>>(video, spatial, x0, tot);
  }

  k_conv3x3<<<dim3(8, C1 / 16, NB), TPB, 0, stream>>>(x0, c1w, c1b, y1, CIN, C1);
  k_gnrelu<<<dim3(32, NB), TPB, 0, stream>>>(y1, g1g, g1b, C1, 4);

  k_conv3x3<<<dim3(8, C2 / 16, NB), TPB, 0, stream>>>(y1, c2w, c2b, y2, C1, C2);
  k_gnrelu<<<dim3(32, NB), TPB, 0, stream>>>(y2, g2g, g2b, C2, 8);

  {
    int tot = NB * VF_ * NPIX;
    k_build_vsoT<<<(tot + TPB - 1) / TPB, TPB, 0, stream>>>(y2, vsoT, tot);
  }

  k_tmaxmod<<<NB, TPB, 0, stream>>>(txt, iw, ib, mod);

  // vsr = vso @ reduce_w^T + reduce_b  (fp32)
  k_gemm_tn<0><<<dim3(5, 16, NB), TPB, 0, stream>>>(vsoT, (size_t)VF_ * NPIX, NPIX, rwT, DS_,
                                                    (void*)vsr, NPIX, DS_, VF_, rb, nullptr);

  // txt attention -> out channels [258, 558)
  k_txtattn<<<dim3(4, NB), TPB, 0, stream>>>(vsr, txt, out);

  // k, q (bf16 [m][288], *mod), v (bf16 transposed [272][1024])
  k_gemm_tn<1><<<dim3(5, 16, NB), TPB, 0, stream>>>(vsoT, (size_t)VF_ * NPIX, NPIX, kwT, VF_,
                                                    (void*)kb16, NPIX, VF_, VF_, kb, mod);
  k_gemm_tn<1><<<dim3(5, 16, NB), TPB, 0, stream>>>(vsoT, (size_t)VF_ * NPIX, NPIX, qwT, VF_,
                                                    (void*)qb16, NPIX, VF_, VF_, qb, mod);
  k_gemm_tn<2><<<dim3(5, 16, NB), TPB, 0, stream>>>(vsoT, (size_t)VF_ * NPIX, NPIX, vwT, VF_,
                                                    (void*)vtb16, NPIX, VF_, VF_, vb, nullptr);

  // video self-attention (bf16 MFMA flash) -> out channels [0, 258)
  k_flash_mfma<<<dim3(16, NB), 256, 0, stream>>>(kb16, qb16, vtb16, out);
}

// Round 4
// 824.121 us; speedup vs baseline: 4.8067x; 2.1516x over previous
//
#include <hip/hip_runtime.h>
#include <cstddef>

#define TPB 256

typedef unsigned short ushort_t;
typedef __attribute__((ext_vector_type(8))) short s8v;
typedef __attribute__((ext_vector_type(4))) float f4v;

#define MFMA16(a, b, c) __builtin_amdgcn_mfma_f32_16x16x32_bf16((a), (b), (c), 0, 0, 0)

static const int NB   = 32;    // batch
static const int NPIX = 1024;  // 32x32
static const int CIN  = 264;
static const int C1   = 128;
static const int C2   = 256;
static const int VF_  = 258;
static const int DS_  = 300;
static const int LL   = 20;

__device__ __forceinline__ ushort_t f2b(float x) {
  unsigned u = __builtin_bit_cast(unsigned, x);
  u = (u + 0x7fffu + ((u >> 16) & 1u)) >> 16;
  return (ushort_t)u;
}

// ---------------- small utility kernels ----------------

__global__ void k_transpose(const float* __restrict__ in, float* __restrict__ out, int R, int C) {
  int i = blockIdx.x * TPB + threadIdx.x;
  if (i >= R * C) return;
  int r = i / C, c = i % C;
  out[(size_t)c * R + r] = in[i];
}

// w[oc][ic][3][3] fp32 -> w_r[oc][tap][icpad] bf16 (pad ic with 0)
__global__ void k_wreorder(const float* __restrict__ w, ushort_t* __restrict__ wr,
                           int Cout, int Cin, int ICPAD) {
  int i = blockIdx.x * TPB + threadIdx.x;
  int total = Cout * 9 * ICPAD;
  if (i >= total) return;
  int ic = i % ICPAD;
  int t = (i / ICPAD) % 9;
  int oc = i / (ICPAD * 9);
  float v = (ic < Cin) ? w[((size_t)oc * Cin + ic) * 9 + t] : 0.f;
  wr[i] = f2b(v);
}

// concat(video,spatial) -> NHWC bf16 [b][1024][288], pad ch 264..287 = 0
__global__ __launch_bounds__(TPB) void k_cat_nhwc(const float* __restrict__ video,
                                                  const float* __restrict__ spatial,
                                                  ushort_t* __restrict__ dst) {
  const int pb = blockIdx.x;  // 16 blocks of 64 px
  const int b  = blockIdx.y;
  const int tid = threadIdx.x;
  __shared__ ushort_t lds[264][72];
  for (int u = tid; u < 264 * 64; u += TPB) {
    int c = u >> 6, px = u & 63;
    int p = (pb << 6) + px;
    float v = (c < 256) ? video[(((size_t)b * 256 + c) << 10) + p]
                        : spatial[(((size_t)b * 8 + (c - 256)) << 10) + p];
    lds[c][px] = f2b(v);
  }
  __syncthreads();
  for (int u = tid; u < 64 * 36; u += TPB) {
    int px = u / 36, ch = u - px * 36;
    s8v v;
#pragma unroll
    for (int j = 0; j < 8; ++j) {
      int ic = ch * 8 + j;
      v[j] = (ic < 264) ? (short)lds[ic][px] : (short)0;
    }
    *(s8v*)(dst + ((size_t)((b << 10) + (pb << 6) + px)) * 288 + ch * 8) = v;
  }
}

// c-major fp32 [b][128][1024] -> NHWC bf16 [b][1024][128]
__global__ __launch_bounds__(TPB) void k_to_nhwc128(const float* __restrict__ src,
                                                    ushort_t* __restrict__ dst) {
  const int pb = blockIdx.x;
  const int b  = blockIdx.y;
  const int tid = threadIdx.x;
  __shared__ ushort_t lds[128][72];
  for (int u = tid; u < 128 * 64; u += TPB) {
    int c = u >> 6, px = u & 63;
    int p = (pb << 6) + px;
    lds[c][px] = f2b(src[(((size_t)b * 128 + c) << 10) + p]);
  }
  __syncthreads();
  for (int u = tid; u < 64 * 16; u += TPB) {
    int px = u >> 4, ch = u & 15;
    s8v v;
#pragma unroll
    for (int j = 0; j < 8; ++j) v[j] = (short)lds[ch * 8 + j][px];
    *(s8v*)(dst + ((size_t)((b << 10) + (pb << 6) + px)) * 128 + ch * 8) = v;
  }
}

// coords + relu'd y2 -> vsoT [b][258][1024] fp32 c-major
__global__ void k_build_vsoT(const float* __restrict__ y2, float* __restrict__ vsoT, int total) {
  int i = blockIdx.x * TPB + threadIdx.x;
  if (i >= total) return;
  int n = i & 1023;
  int t = i >> 10;
  int c = t % VF_;
  int b = t / VF_;
  float v;
  if (c < 256)      v = y2[(((size_t)b * 256 + c) << 10) + n];
  else if (c == 256) v = -1.f + (2.f / 31.f) * (float)(n & 31);
  else               v = -1.f + (2.f / 31.f) * (float)(n >> 5);
  vsoT[i] = v;
}

__global__ void k_tmaxmod(const float* __restrict__ txt, const float* __restrict__ inc_w,
                          const float* __restrict__ inc_b, float* __restrict__ mod) {
  int b = blockIdx.x;
  __shared__ float tm[DS_];
  for (int d = threadIdx.x; d < DS_; d += TPB) {
    const float* p = txt + ((size_t)b * DS_ + d) * LL;
    float m = p[0];
    for (int l = 1; l < LL; ++l) m = fmaxf(m, p[l]);
    tm[d] = m;
  }
  __syncthreads();
  for (int oc = threadIdx.x; oc < VF_; oc += TPB) {
    const float* wr = inc_w + (size_t)oc * DS_;
    float s = inc_b[oc];
    for (int d = 0; d < DS_; ++d) s += tm[d] * wr[d];
    mod[(size_t)b * VF_ + oc] = s;
  }
}

// ---------------- conv 3x3 via bf16 MFMA implicit GEMM ----------------
// in_h: NHWC bf16 [b][1024][ICPAD]; wr: [oc][9][ICPAD] bf16; out: fp32 c-major.
// Block: 128 oc x 64 px (2 image rows). 4 waves, each 32 oc x 64 px.
// LDS: full-channel halo strip [ICG][4 rows][34 cols][8 ic], stride-padded.
template <int ICG>
__global__ __launch_bounds__(TPB) void k_conv_mfma(const ushort_t* __restrict__ in_h,
                                                   const ushort_t* __restrict__ wr,
                                                   const float* __restrict__ bias,
                                                   float* __restrict__ out, int Cout) {
  const int ICPAD = ICG * 8;
  const int ICGS = 4 * 34 * 8 + 16;  // 1104 elems: 552 dwords, %32==8 -> bank spread
  const int b   = blockIdx.z;
  const int ocb = blockIdx.y << 7;
  const int pxb = blockIdx.x;        // 64 px = image rows 2*pxb, 2*pxb+1
  const int tid = threadIdx.x;
  const int w = tid >> 6, lane = tid & 63;
  const int lhi = lane >> 4, llo = lane & 15;

  __shared__ ushort_t in_t[ICG * ICGS];

  // stage halo strip: rows gy = 2*pxb-1 .. 2*pxb+2, cols gx = -1..32
  for (int u = tid; u < ICG * 136; u += TPB) {
    int icg = u / 136;
    int rem = u - icg * 136;
    int row = rem / 34;
    int col = rem - row * 34;
    int gy = (pxb << 1) - 1 + row;
    int gx = col - 1;
    s8v v = (s8v){0, 0, 0, 0, 0, 0, 0, 0};
    if ((unsigned)gy < 32u && (unsigned)gx < 32u)
      v = *(const s8v*)(in_h + ((size_t)((b << 10) + (gy << 5) + gx)) * ICPAD + icg * 8);
    *(s8v*)&in_t[icg * ICGS + (row * 34 + col) * 8] = v;
  }
  __syncthreads();

  f4v acc[2][4];
#pragma unroll
  for (int i = 0; i < 2; ++i)
#pragma unroll
    for (int m = 0; m < 4; ++m) acc[i][m] = (f4v){0.f, 0.f, 0.f, 0.f};

  const ushort_t* wbase = wr + ((size_t)(ocb + w * 32 + llo) * 9) * ICPAD + lhi * 8;
  const size_t ocstep = (size_t)16 * 9 * ICPAD;

  for (int t = 0; t < 9; ++t) {
    const int ky = t / 3, kx = t - ky * 3;
#pragma unroll
    for (int s = 0; s < ICG / 4; ++s) {
      const ushort_t* wp = wbase + (size_t)t * ICPAD + s * 32;
      s8v a0 = *(const s8v*)(wp);
      s8v a1 = *(const s8v*)(wp + ocstep);
      const int icg = (s << 2) + lhi;
#pragma unroll
      for (int m = 0; m < 4; ++m) {
        const int row = (m >> 1) + ky;
        const int col = ((m & 1) << 4) + llo + kx;
        s8v bm = *(const s8v*)&in_t[icg * ICGS + (row * 34 + col) * 8];
        acc[0][m] = MFMA16(a0, bm, acc[0][m]);
        acc[1][m] = MFMA16(a1, bm, acc[1][m]);
      }
    }
  }

#pragma unroll
  for (int i = 0; i < 2; ++i) {
#pragma unroll
    for (int r = 0; r < 4; ++r) {
      const int oc = ocb + w * 32 + i * 16 + lhi * 4 + r;
      const float bv = bias[oc];
#pragma unroll
      for (int m = 0; m < 4; ++m) {
        const int px = (pxb << 6) + (m << 4) + llo;
        out[(((size_t)b * Cout + oc) << 10) + px] = acc[i][m][r] + bv;
      }
    }
  }
}

// ---------------- GroupNorm + ReLU, in place (c-major fp32) ----------------
__global__ __launch_bounds__(TPB) void k_gnrelu(float* __restrict__ x,
                                                const float* __restrict__ gamma,
                                                const float* __restrict__ beta,
                                                int C, int cpg) {
  const int g = blockIdx.x, b = blockIdx.y;
  const int M = cpg << 10;
  float* base = x + (((size_t)b * C + g * cpg) << 10);
  float s = 0.f, ss = 0.f;
  for (int i = threadIdx.x; i < M; i += TPB) {
    float v = base[i];
    s += v;
    ss += v * v;
  }
  __shared__ float rs[4], rss[4];
#pragma unroll
  for (int off = 32; off > 0; off >>= 1) {
    s += __shfl_down(s, off);
    ss += __shfl_down(ss, off);
  }
  if ((threadIdx.x & 63) == 0) { rs[threadIdx.x >> 6] = s; rss[threadIdx.x >> 6] = ss; }
  __syncthreads();
  if (threadIdx.x == 0) {
    float S = 0.f, SS = 0.f;
    for (int i = 0; i < 4; ++i) { S += rs[i]; SS += rss[i]; }
    float mean = S / (float)M;
    float var = SS / (float)M - mean * mean;
    rs[0] = mean;
    rss[0] = rsqrtf(var + 1e-5f);
  }
  __syncthreads();
  float mean = rs[0], rsig = rss[0];
  for (int i = threadIdx.x; i < M; i += TPB) {
    int c = g * cpg + (i >> 10);
    float v = (base[i] - mean) * rsig * gamma[c] + beta[c];
    base[i] = v > 0.f ? v : 0.f;
  }
}

// ---------------- generic TN GEMM (fp32), templated epilogue ----------------
// MODE 0: float out [m][N] (+bias)                        (vsr)
// MODE 1: bf16 out [m][288], (acc+bias)*mod[b][n], pad 0  (k, q)
// MODE 2: bf16 out [n][1024] transposed, pad rows 0       (v)
template <int MODE>
__global__ __launch_bounds__(TPB) void k_gemm_tn(const float* __restrict__ A, size_t strideA, int lda,
                                                 const float* __restrict__ Bm, int ldb,
                                                 void* __restrict__ Cout,
                                                 int M, int N, int K,
                                                 const float* __restrict__ bias,
                                                 const float* __restrict__ scale) {
  const int b = blockIdx.z;
  const float* Ab = A + (size_t)b * strideA;
  const int n0 = blockIdx.x << 6, m0 = blockIdx.y << 6;
  const int tid = threadIdx.x, tx = tid & 15, ty = tid >> 4;
  __shared__ __align__(16) float As[16][64];
  __shared__ __align__(16) float Bs[16][64];
  float acc[4][4];
#pragma unroll
  for (int i = 0; i < 4; ++i)
#pragma unroll
    for (int j = 0; j < 4; ++j) acc[i][j] = 0.f;

  for (int k0 = 0; k0 < K; k0 += 16) {
    for (int idx = tid; idx < 1024; idx += TPB) {
      int kk = idx >> 6, mm = idx & 63;
      bool kv = (k0 + kk) < K;
      As[kk][mm] = kv ? Ab[(size_t)(k0 + kk) * lda + m0 + mm] : 0.f;
      Bs[kk][mm] = (kv && (n0 + mm) < N) ? Bm[(size_t)(k0 + kk) * ldb + n0 + mm] : 0.f;
    }
    __syncthreads();
#pragma unroll
    for (int kk = 0; kk < 16; ++kk) {
      float4 a = *(const float4*)&As[kk][ty << 2];
      float4 bb = *(const float4*)&Bs[kk][tx << 2];
      float av[4] = {a.x, a.y, a.z, a.w};
      float bv[4] = {bb.x, bb.y, bb.z, bb.w};
#pragma unroll
      for (int i = 0; i < 4; ++i)
#pragma unroll
        for (int j = 0; j < 4; ++j) acc[i][j] += av[i] * bv[j];
    }
    __syncthreads();
  }

#pragma unroll
  for (int j = 0; j < 4; ++j) {
    int n = n0 + (tx << 2) + j;
    if (MODE == 0) {
      if (n >= N) continue;
      float* Cb = (float*)Cout + (size_t)b * M * N;
      float bv = bias[n];
#pragma unroll
      for (int i = 0; i < 4; ++i) {
        int m = m0 + (ty << 2) + i;
        Cb[(size_t)m * N + n] = acc[i][j] + bv;
      }
    } else if (MODE == 1) {
      if (n >= 288) continue;
      ushort_t* Cb = (ushort_t*)Cout + (size_t)b * 1024 * 288;
      bool real = n < VF_;
      float bv = real ? bias[n] : 0.f;
      float sc = real ? scale[(size_t)b * VF_ + n] : 0.f;
#pragma unroll
      for (int i = 0; i < 4; ++i) {
        int m = m0 + (ty << 2) + i;
        Cb[(size_t)m * 288 + n] = f2b(real ? (acc[i][j] + bv) * sc : 0.f);
      }
    } else {
      if (n >= 272) continue;
      ushort_t* Cb = (ushort_t*)Cout + (size_t)b * 272 * 1024;
      bool real = n < VF_;
      float bv = real ? bias[n] : 0.f;
#pragma unroll
      for (int i = 0; i < 4; ++i) {
        int m = m0 + (ty << 2) + i;
        Cb[((size_t)n << 10) + m] = f2b(real ? acc[i][j] + bv : 0.f);
      }
    }
  }
}

// ---------------- txt cross-attention ----------------
__global__ __launch_bounds__(TPB) void k_txtattn(const float* __restrict__ vsr,
                                                 const float* __restrict__ txt,
                                                 float* __restrict__ out) {
  const int b = blockIdx.y;
  const int p = blockIdx.x * TPB + threadIdx.x;
  __shared__ float tl[DS_ * LL];
  for (int i = threadIdx.x; i < DS_ * LL; i += TPB) tl[i] = txt[(size_t)b * DS_ * LL + i];
  __syncthreads();
  const float* vr = vsr + ((size_t)b * NPIX + p) * DS_;
  float lg[LL];
#pragma unroll
  for (int l = 0; l < LL; ++l) lg[l] = 0.f;
  for (int d = 0; d < DS_; ++d) {
    float v = vr[d];
    const float* tr = tl + d * LL;
#pragma unroll
    for (int l = 0; l < LL; ++l) lg[l] += v * tr[l];
  }
  const float sc = 0.057735026919f;
  float mx = lg[0] * sc;
#pragma unroll
  for (int l = 1; l < LL; ++l) mx = fmaxf(mx, lg[l] * sc);
  float sum = 0.f;
#pragma unroll
  for (int l = 0; l < LL; ++l) {
    lg[l] = __expf(lg[l] * sc - mx);
    sum += lg[l];
  }
  float inv = 1.f / sum;
#pragma unroll
  for (int l = 0; l < LL; ++l) lg[l] *= inv;
  float* ob = out + (((size_t)b * 558 + VF_) << 10) + p;
  for (int d = 0; d < DS_; ++d) {
    const float* tr = tl + d * LL;
    float s = 0.f;
#pragma unroll
    for (int l = 0; l < LL; ++l) s += lg[l] * tr[l];
    ob[(size_t)d << 10] = s;
  }
}

// ---------------- video self-attention: bf16 MFMA flash ----------------
__global__ __launch_bounds__(256, 2) void k_flash_mfma(const ushort_t* __restrict__ Kb,
                                                       const ushort_t* __restrict__ Qb,
                                                       const ushort_t* __restrict__ Vtb,
                                                       float* __restrict__ out) {
  const int b = blockIdx.y;
  const int n0 = blockIdx.x << 6;
  const int tid = threadIdx.x;
  const int w = tid >> 6, lane = tid & 63;
  const int lhi = lane >> 4;
  const int llo = lane & 15;

  __shared__ ushort_t q_l[32][296];
  __shared__ ushort_t vt_l[272][40];
  __shared__ ushort_t p_l[64][40];

  s8v kf[9];
  {
    const ushort_t* kp = Kb + ((size_t)(b * 1024 + n0 + w * 16 + llo)) * 288 + lhi * 8;
#pragma unroll
    for (int ks = 0; ks < 9; ++ks) kf[ks] = *(const s8v*)(kp + ks * 32);
  }

  f4v oacc[17];
#pragma unroll
  for (int i = 0; i < 17; ++i) oacc[i] = (f4v){0.f, 0.f, 0.f, 0.f};
  float mreg[4], lreg[4];
#pragma unroll
  for (int r = 0; r < 4; ++r) { mreg[r] = -1e30f; lreg[r] = 0.f; }

  const float sc = 0.0622572819f;
  const int src16 = ((llo >> 2) << 4) | (llo & 3);

  for (int mc = 0; mc < 32; ++mc) {
    const int m0 = mc << 5;
    __syncthreads();
    for (int u = tid; u < 1152; u += 256) {
      int row = u / 36, ch = u - row * 36;
      *(s8v*)&q_l[row][ch * 8] =
          *(const s8v*)(Qb + ((size_t)(b * 1024 + m0 + row)) * 288 + ch * 8);
    }
    for (int r = tid; r < 272; r += 256) {
      const ushort_t* src = Vtb + ((size_t)(b * 272 + r) << 10) + m0;
      *(s8v*)&vt_l[r][0]  = *(const s8v*)(src);
      *(s8v*)&vt_l[r][8]  = *(const s8v*)(src + 8);
      *(s8v*)&vt_l[r][16] = *(const s8v*)(src + 16);
      *(s8v*)&vt_l[r][24] = *(const s8v*)(src + 24);
    }
    __syncthreads();

    f4v sacc0 = {0.f, 0.f, 0.f, 0.f}, sacc1 = {0.f, 0.f, 0.f, 0.f};
#pragma unroll
    for (int ks = 0; ks < 9; ++ks) {
      s8v q0 = *(const s8v*)&q_l[llo][ks * 32 + lhi * 8];
      s8v q1 = *(const s8v*)&q_l[16 + llo][ks * 32 + lhi * 8];
      sacc0 = MFMA16(kf[ks], q0, sacc0);
      sacc1 = MFMA16(kf[ks], q1, sacc1);
    }

    float cmax[4], rsum[4], alpha[4];
#pragma unroll
    for (int r = 0; r < 4; ++r) cmax[r] = fmaxf(sacc0[r], sacc1[r]);
#pragma unroll
    for (int off = 1; off < 16; off <<= 1)
#pragma unroll
      for (int r = 0; r < 4; ++r) cmax[r] = fmaxf(cmax[r], __shfl_xor(cmax[r], off));
#pragma unroll
    for (int r = 0; r < 4; ++r) {
      float mn = fmaxf(mreg[r], cmax[r] * sc);
      alpha[r] = __expf(mreg[r] - mn);
      mreg[r] = mn;
    }
    const int prow = w * 16 + lhi * 4;
#pragma unroll
    for (int r = 0; r < 4; ++r) {
      float p0 = __expf(sacc0[r] * sc - mreg[r]);
      float p1 = __expf(sacc1[r] * sc - mreg[r]);
      rsum[r] = p0 + p1;
      p_l[prow + r][llo] = f2b(p0);
      p_l[prow + r][16 + llo] = f2b(p1);
    }
#pragma unroll
    for (int off = 1; off < 16; off <<= 1)
#pragma unroll
      for (int r = 0; r < 4; ++r) rsum[r] += __shfl_xor(rsum[r], off);
#pragma unroll
    for (int r = 0; r < 4; ++r) lreg[r] = lreg[r] * alpha[r] + rsum[r];

    float prep = (lane & 2) ? ((lane & 1) ? alpha[3] : alpha[2])
                            : ((lane & 1) ? alpha[1] : alpha[0]);
    float alphaN = __shfl(prep, src16, 64);

    asm volatile("s_waitcnt lgkmcnt(0)" ::: "memory");
    __builtin_amdgcn_sched_barrier(0);

    s8v pf = *(const s8v*)&p_l[w * 16 + llo][lhi * 8];
#pragma unroll
    for (int dt = 0; dt < 17; ++dt) {
      s8v vf = *(const s8v*)&vt_l[dt * 16 + llo][lhi * 8];
      f4v o = oacc[dt];
      o[0] *= alphaN; o[1] *= alphaN; o[2] *= alphaN; o[3] *= alphaN;
      oacc[dt] = MFMA16(vf, pf, o);
    }
  }

  float prep = (lane & 2) ? ((lane & 1) ? lreg[3] : lreg[2])
                          : ((lane & 1) ? lreg[1] : lreg[0]);
  float linv = 1.f / __shfl(prep, src16, 64);
  const int n = n0 + w * 16 + llo;
#pragma unroll
  for (int dt = 0; dt < 17; ++dt) {
#pragma unroll
    for (int r = 0; r < 4; ++r) {
      int d = dt * 16 + lhi * 4 + r;
      if (d < VF_) out[((size_t)(b * 558 + d) << 10) + n] = oacc[dt][r] * linv;
    }
  }
}

// ---------------- launcher ----------------
extern "C" void kernel_launch(void* const* d_in, const int* in_sizes, int n_in,
                              void* d_out, int out_size, void* d_ws, size_t ws_size,
                              hipStream_t stream) {
  const float* spatial = (const float*)d_in[0];
  const float* video   = (const float*)d_in[1];
  const float* txt     = (const float*)d_in[2];
  const float* c1w = (const float*)d_in[3];
  const float* c1b = (const float*)d_in[4];
  const float* g1g = (const float*)d_in[5];
  const float* g1b = (const float*)d_in[6];
  const float* c2w = (const float*)d_in[7];
  const float* c2b = (const float*)d_in[8];
  const float* g2g = (const float*)d_in[9];
  const float* g2b = (const float*)d_in[10];
  const float* rw  = (const float*)d_in[11];
  const float* rb  = (const float*)d_in[12];
  const float* kw  = (const float*)d_in[13];
  const float* kb  = (const float*)d_in[14];
  const float* qw  = (const float*)d_in[15];
  const float* qb  = (const float*)d_in[16];
  const float* vw  = (const float*)d_in[17];
  const float* vb  = (const float*)d_in[18];
  const float* iw  = (const float*)d_in[19];
  const float* ib  = (const float*)d_in[20];
  float* out = (float*)d_out;
  float* ws = (float*)d_ws;

  // ws layout (float offsets), lifetime-aliased; top ~34.61M floats (~138 MB)
  ushort_t* x0h   = (ushort_t*)(ws + 0);          // [0, 4.72M)  cat_nhwc -> conv1
  float*    vsr   = ws + 0;                       // [0, 9.83M)  after x1h dead
  float*    y1    = ws + 4750000;                 // [4.75M, 8.95M)
  ushort_t* x1h   = (ushort_t*)(ws + 9000000);    // [9.0M, 11.1M)
  float*    y2    = ws + 11200000;                // [11.2M, 19.59M)
  ushort_t* kb16  = (ushort_t*)(ws + 11200000);   // [11.2M, 15.92M) after vsoT built
  ushort_t* vtb16 = (ushort_t*)(ws + 16000000);   // [16.0M, 20.46M) after vsoT built
  float*    vsoT  = ws + 20500000;                // [20.5M, 28.96M)
  ushort_t* qb16  = (ushort_t*)(ws + 29000000);   // [29.0M, 33.72M)
  ushort_t* w1r   = (ushort_t*)(ws + 33800000);   // 331,776 us
  ushort_t* w2r   = (ushort_t*)(ws + 34000000);   // 294,912 us
  float*    rwT   = ws + 34200000;                // 77,400
  float*    kwT   = ws + 34300000;                // 66,564
  float*    qwT   = ws + 34400000;                // 66,564
  float*    vwT   = ws + 34500000;                // 66,564
  float*    mod   = ws + 34600000;                // 8,256

  // weight prep
  k_wreorder<<<(128 * 9 * 288 + TPB - 1) / TPB, TPB, 0, stream>>>(c1w, w1r, 128, 264, 288);
  k_wreorder<<<(256 * 9 * 128 + TPB - 1) / TPB, TPB, 0, stream>>>(c2w, w2r, 256, 128, 128);
  k_transpose<<<(300 * 258 + TPB - 1) / TPB, TPB, 0, stream>>>(rw, rwT, 300, 258);
  k_transpose<<<(258 * 258 + TPB - 1) / TPB, TPB, 0, stream>>>(kw, kwT, 258, 258);
  k_transpose<<<(258 * 258 + TPB - 1) / TPB, TPB, 0, stream>>>(qw, qwT, 258, 258);
  k_transpose<<<(258 * 258 + TPB - 1) / TPB, TPB, 0, stream>>>(vw, vwT, 258, 258);

  // concat -> NHWC bf16
  k_cat_nhwc<<<dim3(16, NB), TPB, 0, stream>>>(video, spatial, x0h);

  // conv1 (MFMA) + GN1 + relu -> NHWC bf16
  k_conv_mfma<36><<<dim3(16, 1, NB), TPB, 0, stream>>>(x0h, w1r, c1b, y1, C1);
  k_gnrelu<<<dim3(32, NB), TPB, 0, stream>>>(y1, g1g, g1b, C1, 4);
  k_to_nhwc128<<<dim3(16, NB), TPB, 0, stream>>>(y1, x1h);

  k_tmaxmod<<<NB, TPB, 0, stream>>>(txt, iw, ib, mod);

  // conv2 (MFMA) + GN2 + relu (c-major fp32)
  k_conv_mfma<16><<<dim3(16, 2, NB), TPB, 0, stream>>>(x1h, w2r, c2b, y2, C2);
  k_gnrelu<<<dim3(32, NB), TPB, 0, stream>>>(y2, g2g, g2b, C2, 8);

  // vsoT (c-major features + coords)
  {
    int tot = NB * VF_ * NPIX;
    k_build_vsoT<<<(tot + TPB - 1) / TPB, TPB, 0, stream>>>(y2, vsoT, tot);
  }

  // vsr = vso @ reduce_w^T + reduce_b  (fp32)
  k_gemm_tn<0><<<dim3(5, 16, NB), TPB, 0, stream>>>(vsoT, (size_t)VF_ * NPIX, NPIX, rwT, DS_,
                                                    (void*)vsr, NPIX, DS_, VF_, rb, nullptr);

  // txt attention -> out channels [258, 558)
  k_txtattn<<<dim3(4, NB), TPB, 0, stream>>>(vsr, txt, out);

  // k, q (bf16 [m][288], *mod), v (bf16 transposed [272][1024])
  k_gemm_tn<1><<<dim3(5, 16, NB), TPB, 0, stream>>>(vsoT, (size_t)VF_ * NPIX, NPIX, kwT, VF_,
                                                    (void*)kb16, NPIX, VF_, VF_, kb, mod);
  k_gemm_tn<1><<<dim3(5, 16, NB), TPB, 0, stream>>>(vsoT, (size_t)VF_ * NPIX, NPIX, qwT, VF_,
                                                    (void*)qb16, NPIX, VF_, VF_, qb, mod);
  k_gemm_tn<2><<<dim3(5, 16, NB), TPB, 0, stream>>>(vsoT, (size_t)VF_ * NPIX, NPIX, vwT, VF_,
                                                    (void*)vtb16, NPIX, VF_, VF_, vb, nullptr);

  // video self-attention (bf16 MFMA flash) -> out channels [0, 258)
  k_flash_mfma<<<dim3(16, NB), 256, 0, stream>>>(kb16, qb16, vtb16, out);
}

// Round 5
// 484.893 us; speedup vs baseline: 8.1695x; 1.6996x over previous
//
#include <hip/hip_runtime.h>
#include <cstddef>

#define TPB 256

typedef unsigned short ushort_t;
typedef __attribute__((ext_vector_type(8))) short s8v;
typedef __attribute__((ext_vector_type(4))) float f4v;

#define MFMA16(a, b, c) __builtin_amdgcn_mfma_f32_16x16x32_bf16((a), (b), (c), 0, 0, 0)

static const int NB   = 32;    // batch
static const int NPIX = 1024;  // 32x32
static const int CIN  = 264;
static const int C1   = 128;
static const int C2   = 256;
static const int VF_  = 258;
static const int DS_  = 300;
static const int LL   = 20;

__device__ __forceinline__ ushort_t f2b(float x) {
  unsigned u = __builtin_bit_cast(unsigned, x);
  u = (u + 0x7fffu + ((u >> 16) & 1u)) >> 16;
  return (ushort_t)u;
}

// ---------------- small utility kernels ----------------

// src [N][K=258] fp32 row-major -> dst [384][288] bf16, zero padded
__global__ void k_wprep(const float* __restrict__ src, ushort_t* __restrict__ dst, int N) {
  int i = blockIdx.x * TPB + threadIdx.x;
  if (i >= 384 * 288) return;
  int n = i / 288, k = i - n * 288;
  float v = (n < N && k < 258) ? src[(size_t)n * 258 + k] : 0.f;
  dst[i] = f2b(v);
}

// w[oc][ic][3][3] fp32 -> w_r[oc][tap][icpad] bf16 (pad ic with 0)
__global__ void k_wreorder(const float* __restrict__ w, ushort_t* __restrict__ wr,
                           int Cout, int Cin, int ICPAD) {
  int i = blockIdx.x * TPB + threadIdx.x;
  int total = Cout * 9 * ICPAD;
  if (i >= total) return;
  int ic = i % ICPAD;
  int t = (i / ICPAD) % 9;
  int oc = i / (ICPAD * 9);
  float v = (ic < Cin) ? w[((size_t)oc * Cin + ic) * 9 + t] : 0.f;
  wr[i] = f2b(v);
}

// concat(video,spatial) -> NHWC bf16 [b][1024][288], pad ch 264..287 = 0
__global__ __launch_bounds__(TPB) void k_cat_nhwc(const float* __restrict__ video,
                                                  const float* __restrict__ spatial,
                                                  ushort_t* __restrict__ dst) {
  const int pb = blockIdx.x;  // 16 blocks of 64 px
  const int b  = blockIdx.y;
  const int tid = threadIdx.x;
  __shared__ ushort_t lds[264][72];
  for (int u = tid; u < 264 * 64; u += TPB) {
    int c = u >> 6, px = u & 63;
    int p = (pb << 6) + px;
    float v = (c < 256) ? video[(((size_t)b * 256 + c) << 10) + p]
                        : spatial[(((size_t)b * 8 + (c - 256)) << 10) + p];
    lds[c][px] = f2b(v);
  }
  __syncthreads();
  for (int u = tid; u < 64 * 36; u += TPB) {
    int px = u / 36, ch = u - px * 36;
    s8v v;
#pragma unroll
    for (int j = 0; j < 8; ++j) {
      int ic = ch * 8 + j;
      v[j] = (ic < 264) ? (short)lds[ic][px] : (short)0;
    }
    *(s8v*)(dst + ((size_t)((b << 10) + (pb << 6) + px)) * 288 + ch * 8) = v;
  }
}

// c-major fp32 [b][128][1024] -> NHWC bf16 [b][1024][128]
__global__ __launch_bounds__(TPB) void k_to_nhwc128(const float* __restrict__ src,
                                                    ushort_t* __restrict__ dst) {
  const int pb = blockIdx.x;
  const int b  = blockIdx.y;
  const int tid = threadIdx.x;
  __shared__ ushort_t lds[128][72];
  for (int u = tid; u < 128 * 64; u += TPB) {
    int c = u >> 6, px = u & 63;
    int p = (pb << 6) + px;
    lds[c][px] = f2b(src[(((size_t)b * 128 + c) << 10) + p]);
  }
  __syncthreads();
  for (int u = tid; u < 64 * 16; u += TPB) {
    int px = u >> 4, ch = u & 15;
    s8v v;
#pragma unroll
    for (int j = 0; j < 8; ++j) v[j] = (short)lds[ch * 8 + j][px];
    *(s8v*)(dst + ((size_t)((b << 10) + (pb << 6) + px)) * 128 + ch * 8) = v;
  }
}

// gn2'd y2 (c-major fp32 [b][256][1024]) + coords -> vso_h bf16 [b][1024][288]
__global__ __launch_bounds__(TPB) void k_build_vsoh(const float* __restrict__ y2,
                                                    ushort_t* __restrict__ dst) {
  const int pb = blockIdx.x;
  const int b  = blockIdx.y;
  const int tid = threadIdx.x;
  __shared__ ushort_t lds[256][72];
  for (int u = tid; u < 256 * 64; u += TPB) {
    int c = u >> 6, px = u & 63;
    int p = (pb << 6) + px;
    lds[c][px] = f2b(y2[(((size_t)b * 256 + c) << 10) + p]);
  }
  __syncthreads();
  for (int u = tid; u < 64 * 36; u += TPB) {
    int px = u / 36, ch = u - px * 36;
    int p = (pb << 6) + px;
    s8v v;
#pragma unroll
    for (int j = 0; j < 8; ++j) {
      int cg = ch * 8 + j;
      float fv;
      if (cg < 256)      { v[j] = (short)lds[cg][px]; continue; }
      else if (cg == 256) fv = -1.f + (2.f / 31.f) * (float)(p & 31);
      else if (cg == 257) fv = -1.f + (2.f / 31.f) * (float)(p >> 5);
      else                fv = 0.f;
      v[j] = (short)f2b(fv);
    }
    *(s8v*)(dst + ((size_t)((b << 10) + p)) * 288 + ch * 8) = v;
  }
}

__global__ void k_tmaxmod(const float* __restrict__ txt, const float* __restrict__ inc_w,
                          const float* __restrict__ inc_b, float* __restrict__ mod) {
  int b = blockIdx.x;
  __shared__ float tm[DS_];
  for (int d = threadIdx.x; d < DS_; d += TPB) {
    const float* p = txt + ((size_t)b * DS_ + d) * LL;
    float m = p[0];
    for (int l = 1; l < LL; ++l) m = fmaxf(m, p[l]);
    tm[d] = m;
  }
  __syncthreads();
  for (int oc = threadIdx.x; oc < VF_; oc += TPB) {
    const float* wr = inc_w + (size_t)oc * DS_;
    float s = inc_b[oc];
    for (int d = 0; d < DS_; ++d) s += tm[d] * wr[d];
    mod[(size_t)b * VF_ + oc] = s;
  }
}

// ---------------- conv 3x3 via bf16 MFMA implicit GEMM ----------------
template <int ICG>
__global__ __launch_bounds__(TPB) void k_conv_mfma(const ushort_t* __restrict__ in_h,
                                                   const ushort_t* __restrict__ wr,
                                                   const float* __restrict__ bias,
                                                   float* __restrict__ out, int Cout) {
  const int ICPAD = ICG * 8;
  const int ICGS = 4 * 34 * 8 + 16;
  const int b   = blockIdx.z;
  const int ocb = blockIdx.y << 7;
  const int pxb = blockIdx.x;
  const int tid = threadIdx.x;
  const int w = tid >> 6, lane = tid & 63;
  const int lhi = lane >> 4, llo = lane & 15;

  __shared__ ushort_t in_t[ICG * ICGS];

  for (int u = tid; u < ICG * 136; u += TPB) {
    int icg = u / 136;
    int rem = u - icg * 136;
    int row = rem / 34;
    int col = rem - row * 34;
    int gy = (pxb << 1) - 1 + row;
    int gx = col - 1;
    s8v v = (s8v){0, 0, 0, 0, 0, 0, 0, 0};
    if ((unsigned)gy < 32u && (unsigned)gx < 32u)
      v = *(const s8v*)(in_h + ((size_t)((b << 10) + (gy << 5) + gx)) * ICPAD + icg * 8);
    *(s8v*)&in_t[icg * ICGS + (row * 34 + col) * 8] = v;
  }
  __syncthreads();

  f4v acc[2][4];
#pragma unroll
  for (int i = 0; i < 2; ++i)
#pragma unroll
    for (int m = 0; m < 4; ++m) acc[i][m] = (f4v){0.f, 0.f, 0.f, 0.f};

  const ushort_t* wbase = wr + ((size_t)(ocb + w * 32 + llo) * 9) * ICPAD + lhi * 8;
  const size_t ocstep = (size_t)16 * 9 * ICPAD;

  for (int t = 0; t < 9; ++t) {
    const int ky = t / 3, kx = t - ky * 3;
#pragma unroll
    for (int s = 0; s < ICG / 4; ++s) {
      const ushort_t* wp = wbase + (size_t)t * ICPAD + s * 32;
      s8v a0 = *(const s8v*)(wp);
      s8v a1 = *(const s8v*)(wp + ocstep);
      const int icg = (s << 2) + lhi;
#pragma unroll
      for (int m = 0; m < 4; ++m) {
        const int row = (m >> 1) + ky;
        const int col = ((m & 1) << 4) + llo + kx;
        s8v bm = *(const s8v*)&in_t[icg * ICGS + (row * 34 + col) * 8];
        acc[0][m] = MFMA16(a0, bm, acc[0][m]);
        acc[1][m] = MFMA16(a1, bm, acc[1][m]);
      }
    }
  }

#pragma unroll
  for (int i = 0; i < 2; ++i) {
#pragma unroll
    for (int r = 0; r < 4; ++r) {
      const int oc = ocb + w * 32 + i * 16 + lhi * 4 + r;
      const float bv = bias[oc];
#pragma unroll
      for (int m = 0; m < 4; ++m) {
        const int px = (pxb << 6) + (m << 4) + llo;
        out[(((size_t)b * Cout + oc) << 10) + px] = acc[i][m][r] + bv;
      }
    }
  }
}

// ---------------- GroupNorm + ReLU, in place (c-major fp32) ----------------
__global__ __launch_bounds__(TPB) void k_gnrelu(float* __restrict__ x,
                                                const float* __restrict__ gamma,
                                                const float* __restrict__ beta,
                                                int C, int cpg) {
  const int g = blockIdx.x, b = blockIdx.y;
  const int M = cpg << 10;
  float* base = x + (((size_t)b * C + g * cpg) << 10);
  float s = 0.f, ss = 0.f;
  for (int i = threadIdx.x; i < M; i += TPB) {
    float v = base[i];
    s += v;
    ss += v * v;
  }
  __shared__ float rs[4], rss[4];
#pragma unroll
  for (int off = 32; off > 0; off >>= 1) {
    s += __shfl_down(s, off);
    ss += __shfl_down(ss, off);
  }
  if ((threadIdx.x & 63) == 0) { rs[threadIdx.x >> 6] = s; rss[threadIdx.x >> 6] = ss; }
  __syncthreads();
  if (threadIdx.x == 0) {
    float S = 0.f, SS = 0.f;
    for (int i = 0; i < 4; ++i) { S += rs[i]; SS += rss[i]; }
    float mean = S / (float)M;
    float var = SS / (float)M - mean * mean;
    rs[0] = mean;
    rss[0] = rsqrtf(var + 1e-5f);
  }
  __syncthreads();
  float mean = rs[0], rsig = rss[0];
  for (int i = threadIdx.x; i < M; i += TPB) {
    int c = g * cpg + (i >> 10);
    float v = (base[i] - mean) * rsig * gamma[c] + beta[c];
    base[i] = v > 0.f ? v : 0.f;
  }
}

// ---------------- bf16 MFMA GEMM: out = vso_h @ W^T (+bias [, *mod]) ----------------
// A: [b][1024][288] bf16; Bw: [384][288] bf16 zero-padded.
// MODE 0: fp32 out [b][1024][300]          (vsr)
// MODE 1: bf16 out [b][1024][288], *mod    (k, q)
// MODE 2: bf16 out [b][272][1024] (swapped operands -> transposed store)  (v)
template <int MODE>
__global__ __launch_bounds__(TPB) void k_gemm_mfma(const ushort_t* __restrict__ A,
                                                   const ushort_t* __restrict__ Bw,
                                                   void* __restrict__ Cout,
                                                   const float* __restrict__ bias,
                                                   const float* __restrict__ mod) {
  const int b = blockIdx.z;
  const int n0 = blockIdx.x << 7;
  const int m0 = blockIdx.y << 7;
  const int tid = threadIdx.x;
  const int w = tid >> 6, lane = tid & 63;
  const int wr = w >> 1, wc = w & 1;
  const int lhi = lane >> 4, llo = lane & 15;

  __shared__ ushort_t A_l[128][40];
  __shared__ ushort_t B_l[128][40];

  f4v acc[4][4];
#pragma unroll
  for (int i = 0; i < 4; ++i)
#pragma unroll
    for (int j = 0; j < 4; ++j) acc[i][j] = (f4v){0.f, 0.f, 0.f, 0.f};

  const ushort_t* Ab = A + (((size_t)b << 10)) * 288;

  for (int k0 = 0; k0 < 288; k0 += 32) {
    for (int u = tid; u < 512; u += TPB) {
      int row = u >> 2, seg = u & 3;
      *(s8v*)&A_l[row][seg * 8] = *(const s8v*)(Ab + (size_t)(m0 + row) * 288 + k0 + seg * 8);
      *(s8v*)&B_l[row][seg * 8] = *(const s8v*)(Bw + (size_t)(n0 + row) * 288 + k0 + seg * 8);
    }
    __syncthreads();
    s8v am[4], bn[4];
#pragma unroll
    for (int i = 0; i < 4; ++i) am[i] = *(const s8v*)&A_l[wr * 64 + i * 16 + llo][lhi * 8];
#pragma unroll
    for (int j = 0; j < 4; ++j) bn[j] = *(const s8v*)&B_l[wc * 64 + j * 16 + llo][lhi * 8];
#pragma unroll
    for (int i = 0; i < 4; ++i)
#pragma unroll
      for (int j = 0; j < 4; ++j) {
        if (MODE == 2) acc[i][j] = MFMA16(bn[j], am[i], acc[i][j]);
        else           acc[i][j] = MFMA16(am[i], bn[j], acc[i][j]);
      }
    __syncthreads();
  }

  if (MODE == 0) {
    float* Cf = (float*)Cout + (size_t)b * 1024 * 300;
#pragma unroll
    for (int j = 0; j < 4; ++j) {
      int n = n0 + wc * 64 + j * 16 + llo;
      if (n >= 300) continue;
      float bv = bias[n];
#pragma unroll
      for (int i = 0; i < 4; ++i)
#pragma unroll
        for (int r = 0; r < 4; ++r) {
          int m = m0 + wr * 64 + i * 16 + lhi * 4 + r;
          Cf[(size_t)m * 300 + n] = acc[i][j][r] + bv;
        }
    }
  } else if (MODE == 1) {
    ushort_t* Cb = (ushort_t*)Cout + (size_t)b * 1024 * 288;
#pragma unroll
    for (int j = 0; j < 4; ++j) {
      int n = n0 + wc * 64 + j * 16 + llo;
      if (n >= 288) continue;
      bool real = n < VF_;
      float bv = real ? bias[n] : 0.f;
      float sm = real ? mod[(size_t)b * VF_ + n] : 0.f;
#pragma unroll
      for (int i = 0; i < 4; ++i)
#pragma unroll
        for (int r = 0; r < 4; ++r) {
          int m = m0 + wr * 64 + i * 16 + lhi * 4 + r;
          Cb[(size_t)m * 288 + n] = f2b(real ? (acc[i][j][r] + bv) * sm : 0.f);
        }
    }
  } else {
    ushort_t* Cb = (ushort_t*)Cout + (size_t)b * 272 * 1024;
#pragma unroll
    for (int j = 0; j < 4; ++j)
#pragma unroll
      for (int r = 0; r < 4; ++r) {
        int n = n0 + wc * 64 + j * 16 + lhi * 4 + r;
        if (n >= 272) continue;
        bool real = n < VF_;
        float bv = real ? bias[n] : 0.f;
#pragma unroll
        for (int i = 0; i < 4; ++i) {
          int m = m0 + wr * 64 + i * 16 + llo;
          Cb[((size_t)n << 10) + m] = f2b(real ? acc[i][j][r] + bv : 0.f);
        }
      }
  }
}

// ---------------- txt cross-attention ----------------
__global__ __launch_bounds__(TPB) void k_txtattn(const float* __restrict__ vsr,
                                                 const float* __restrict__ txt,
                                                 float* __restrict__ out) {
  const int b = blockIdx.y;
  const int p = blockIdx.x * TPB + threadIdx.x;
  __shared__ float tl[DS_ * LL];
  for (int i = threadIdx.x; i < DS_ * LL; i += TPB) tl[i] = txt[(size_t)b * DS_ * LL + i];
  __syncthreads();
  const float* vr = vsr + ((size_t)b * NPIX + p) * DS_;
  float lg[LL];
#pragma unroll
  for (int l = 0; l < LL; ++l) lg[l] = 0.f;
  for (int d = 0; d < DS_; ++d) {
    float v = vr[d];
    const float* tr = tl + d * LL;
#pragma unroll
    for (int l = 0; l < LL; ++l) lg[l] += v * tr[l];
  }
  const float sc = 0.057735026919f;
  float mx = lg[0] * sc;
#pragma unroll
  for (int l = 1; l < LL; ++l) mx = fmaxf(mx, lg[l] * sc);
  float sum = 0.f;
#pragma unroll
  for (int l = 0; l < LL; ++l) {
    lg[l] = __expf(lg[l] * sc - mx);
    sum += lg[l];
  }
  float inv = 1.f / sum;
#pragma unroll
  for (int l = 0; l < LL; ++l) lg[l] *= inv;
  float* ob = out + (((size_t)b * 558 + VF_) << 10) + p;
  for (int d = 0; d < DS_; ++d) {
    const float* tr = tl + d * LL;
    float s = 0.f;
#pragma unroll
    for (int l = 0; l < LL; ++l) s += lg[l] * tr[l];
    ob[(size_t)d << 10] = s;
  }
}

// ---------------- video self-attention: bf16 MFMA flash ----------------
__global__ __launch_bounds__(256, 2) void k_flash_mfma(const ushort_t* __restrict__ Kb,
                                                       const ushort_t* __restrict__ Qb,
                                                       const ushort_t* __restrict__ Vtb,
                                                       float* __restrict__ out) {
  const int b = blockIdx.y;
  const int n0 = blockIdx.x << 6;
  const int tid = threadIdx.x;
  const int w = tid >> 6, lane = tid & 63;
  const int lhi = lane >> 4;
  const int llo = lane & 15;

  __shared__ ushort_t q_l[32][296];
  __shared__ ushort_t vt_l[272][40];
  __shared__ ushort_t p_l[64][40];

  s8v kf[9];
  {
    const ushort_t* kp = Kb + ((size_t)(b * 1024 + n0 + w * 16 + llo)) * 288 + lhi * 8;
#pragma unroll
    for (int ks = 0; ks < 9; ++ks) kf[ks] = *(const s8v*)(kp + ks * 32);
  }

  f4v oacc[17];
#pragma unroll
  for (int i = 0; i < 17; ++i) oacc[i] = (f4v){0.f, 0.f, 0.f, 0.f};
  float mreg[4], lreg[4];
#pragma unroll
  for (int r = 0; r < 4; ++r) { mreg[r] = -1e30f; lreg[r] = 0.f; }

  const float sc = 0.0622572819f;
  const int src16 = ((llo >> 2) << 4) | (llo & 3);

  for (int mc = 0; mc < 32; ++mc) {
    const int m0 = mc << 5;
    __syncthreads();
    for (int u = tid; u < 1152; u += 256) {
      int row = u / 36, ch = u - row * 36;
      *(s8v*)&q_l[row][ch * 8] =
          *(const s8v*)(Qb + ((size_t)(b * 1024 + m0 + row)) * 288 + ch * 8);
    }
    for (int r = tid; r < 272; r += 256) {
      const ushort_t* src = Vtb + ((size_t)(b * 272 + r) << 10) + m0;
      *(s8v*)&vt_l[r][0]  = *(const s8v*)(src);
      *(s8v*)&vt_l[r][8]  = *(const s8v*)(src + 8);
      *(s8v*)&vt_l[r][16] = *(const s8v*)(src + 16);
      *(s8v*)&vt_l[r][24] = *(const s8v*)(src + 24);
    }
    __syncthreads();

    f4v sacc0 = {0.f, 0.f, 0.f, 0.f}, sacc1 = {0.f, 0.f, 0.f, 0.f};
#pragma unroll
    for (int ks = 0; ks < 9; ++ks) {
      s8v q0 = *(const s8v*)&q_l[llo][ks * 32 + lhi * 8];
      s8v q1 = *(const s8v*)&q_l[16 + llo][ks * 32 + lhi * 8];
      sacc0 = MFMA16(kf[ks], q0, sacc0);
      sacc1 = MFMA16(kf[ks], q1, sacc1);
    }

    float cmax[4], rsum[4], alpha[4];
#pragma unroll
    for (int r = 0; r < 4; ++r) cmax[r] = fmaxf(sacc0[r], sacc1[r]);
#pragma unroll
    for (int off = 1; off < 16; off <<= 1)
#pragma unroll
      for (int r = 0; r < 4; ++r) cmax[r] = fmaxf(cmax[r], __shfl_xor(cmax[r], off));
#pragma unroll
    for (int r = 0; r < 4; ++r) {
      float mn = fmaxf(mreg[r], cmax[r] * sc);
      alpha[r] = __expf(mreg[r] - mn);
      mreg[r] = mn;
    }
    const int prow = w * 16 + lhi * 4;
#pragma unroll
    for (int r = 0; r < 4; ++r) {
      float p0 = __expf(sacc0[r] * sc - mreg[r]);
      float p1 = __expf(sacc1[r] * sc - mreg[r]);
      rsum[r] = p0 + p1;
      p_l[prow + r][llo] = f2b(p0);
      p_l[prow + r][16 + llo] = f2b(p1);
    }
#pragma unroll
    for (int off = 1; off < 16; off <<= 1)
#pragma unroll
      for (int r = 0; r < 4; ++r) rsum[r] += __shfl_xor(rsum[r], off);
#pragma unroll
    for (int r = 0; r < 4; ++r) lreg[r] = lreg[r] * alpha[r] + rsum[r];

    float prep = (lane & 2) ? ((lane & 1) ? alpha[3] : alpha[2])
                            : ((lane & 1) ? alpha[1] : alpha[0]);
    float alphaN = __shfl(prep, src16, 64);

    asm volatile("s_waitcnt lgkmcnt(0)" ::: "memory");
    __builtin_amdgcn_sched_barrier(0);

    s8v pf = *(const s8v*)&p_l[w * 16 + llo][lhi * 8];
#pragma unroll
    for (int dt = 0; dt < 17; ++dt) {
      s8v vf = *(const s8v*)&vt_l[dt * 16 + llo][lhi * 8];
      f4v o = oacc[dt];
      o[0] *= alphaN; o[1] *= alphaN; o[2] *= alphaN; o[3] *= alphaN;
      oacc[dt] = MFMA16(vf, pf, o);
    }
  }

  float prep = (lane & 2) ? ((lane & 1) ? lreg[3] : lreg[2])
                          : ((lane & 1) ? lreg[1] : lreg[0]);
  float linv = 1.f / __shfl(prep, src16, 64);
  const int n = n0 + w * 16 + llo;
#pragma unroll
  for (int dt = 0; dt < 17; ++dt) {
#pragma unroll
    for (int r = 0; r < 4; ++r) {
      int d = dt * 16 + lhi * 4 + r;
      if (d < VF_) out[((size_t)(b * 558 + d) << 10) + n] = oacc[dt][r] * linv;
    }
  }
}

// ---------------- launcher ----------------
extern "C" void kernel_launch(void* const* d_in, const int* in_sizes, int n_in,
                              void* d_out, int out_size, void* d_ws, size_t ws_size,
                              hipStream_t stream) {
  const float* spatial = (const float*)d_in[0];
  const float* video   = (const float*)d_in[1];
  const float* txt     = (const float*)d_in[2];
  const float* c1w = (const float*)d_in[3];
  const float* c1b = (const float*)d_in[4];
  const float* g1g = (const float*)d_in[5];
  const float* g1b = (const float*)d_in[6];
  const float* c2w = (const float*)d_in[7];
  const float* c2b = (const float*)d_in[8];
  const float* g2g = (const float*)d_in[9];
  const float* g2b = (const float*)d_in[10];
  const float* rw  = (const float*)d_in[11];
  const float* rb  = (const float*)d_in[12];
  const float* kw  = (const float*)d_in[13];
  const float* kb  = (const float*)d_in[14];
  const float* qw  = (const float*)d_in[15];
  const float* qb  = (const float*)d_in[16];
  const float* vw  = (const float*)d_in[17];
  const float* vb  = (const float*)d_in[18];
  const float* iw  = (const float*)d_in[19];
  const float* ib  = (const float*)d_in[20];
  float* out = (float*)d_out;
  float* ws = (float*)d_ws;

  // ws layout (float offsets), lifetime-aliased; top ~29.71M floats (~119 MB)
  ushort_t* x0h   = (ushort_t*)(ws + 0);          // [0, 4.72M) fl        -> conv1
  float*    vsr   = ws + 0;                       // [0, 9.83M)           after x1h dead
  float*    y1    = ws + 5000000;                 // [5.0M, 9.2M)
  ushort_t* x1h   = (ushort_t*)(ws + 9300000);    // [9.3M, 11.4M)
  ushort_t* kb16  = (ushort_t*)(ws + 10000000);   // [10.0M, 14.72M)      after y2 dead
  float*    y2    = ws + 11500000;                // [11.5M, 19.9M)
  ushort_t* qb16  = (ushort_t*)(ws + 14800000);   // [14.8M, 19.52M)      after y2 dead
  ushort_t* vsoh  = (ushort_t*)(ws + 20000000);   // [20.0M, 24.72M)
  ushort_t* vtb16 = (ushort_t*)(ws + 24800000);   // [24.8M, 29.26M)
  ushort_t* rwp   = (ushort_t*)(ws + 29300000);   // 110,592 us
  ushort_t* kwp   = (ushort_t*)(ws + 29360000);   // 110,592 us
  ushort_t* qwp   = (ushort_t*)(ws + 29420000);   // 110,592 us
  ushort_t* vwp   = (ushort_t*)(ws + 29480000);   // 110,592 us
  ushort_t* w1r   = (ushort_t*)(ws + 29540000);   // 331,776 us
  ushort_t* w2r   = (ushort_t*)(ws + 29710000);   // 294,912 us
  float*    mod   = ws + 29860000;                // 8,256

  // weight prep
  k_wreorder<<<(128 * 9 * 288 + TPB - 1) / TPB, TPB, 0, stream>>>(c1w, w1r, 128, 264, 288);
  k_wreorder<<<(256 * 9 * 128 + TPB - 1) / TPB, TPB, 0, stream>>>(c2w, w2r, 256, 128, 128);
  {
    int tot = 384 * 288;
    k_wprep<<<(tot + TPB - 1) / TPB, TPB, 0, stream>>>(rw, rwp, 300);
    k_wprep<<<(tot + TPB - 1) / TPB, TPB, 0, stream>>>(kw, kwp, 258);
    k_wprep<<<(tot + TPB - 1) / TPB, TPB, 0, stream>>>(qw, qwp, 258);
    k_wprep<<<(tot + TPB - 1) / TPB, TPB, 0, stream>>>(vw, vwp, 258);
  }

  // concat -> NHWC bf16
  k_cat_nhwc<<<dim3(16, NB), TPB, 0, stream>>>(video, spatial, x0h);

  // conv1 (MFMA) + GN1 + relu -> NHWC bf16
  k_conv_mfma<36><<<dim3(16, 1, NB), TPB, 0, stream>>>(x0h, w1r, c1b, y1, C1);
  k_gnrelu<<<dim3(32, NB), TPB, 0, stream>>>(y1, g1g, g1b, C1, 4);
  k_to_nhwc128<<<dim3(16, NB), TPB, 0, stream>>>(y1, x1h);

  k_tmaxmod<<<NB, TPB, 0, stream>>>(txt, iw, ib, mod);

  // conv2 (MFMA) + GN2 + relu (c-major fp32)
  k_conv_mfma<16><<<dim3(16, 2, NB), TPB, 0, stream>>>(x1h, w2r, c2b, y2, C2);
  k_gnrelu<<<dim3(32, NB), TPB, 0, stream>>>(y2, g2g, g2b, C2, 8);

  // vso_h bf16 NHWC (+coords)
  k_build_vsoh<<<dim3(16, NB), TPB, 0, stream>>>(y2, vsoh);

  // vsr = vso @ reduce_w^T + reduce_b (MFMA, fp32 out)
  k_gemm_mfma<0><<<dim3(3, 8, NB), TPB, 0, stream>>>(vsoh, rwp, (void*)vsr, rb, nullptr);

  // txt attention -> out channels [258, 558)
  k_txtattn<<<dim3(4, NB), TPB, 0, stream>>>(vsr, txt, out);

  // k, q (bf16 [m][288], *mod), v (bf16 transposed [272][1024])
  k_gemm_mfma<1><<<dim3(3, 8, NB), TPB, 0, stream>>>(vsoh, kwp, (void*)kb16, kb, mod);
  k_gemm_mfma<1><<<dim3(3, 8, NB), TPB, 0, stream>>>(vsoh, qwp, (void*)qb16, qb, mod);
  k_gemm_mfma<2><<<dim3(3, 8, NB), TPB, 0, stream>>>(vsoh, vwp, (void*)vtb16, vb, nullptr);

  // video self-attention (bf16 MFMA flash) -> out channels [0, 258)
  k_flash_mfma<<<dim3(16, NB), 256, 0, stream>>>(kb16, qb16, vtb16, out);
}

// Round 6
// 451.800 us; speedup vs baseline: 8.7679x; 1.0732x over previous
//
#include <hip/hip_runtime.h>
#include <cstddef>

#define TPB 256

typedef unsigned short ushort_t;
typedef __attribute__((ext_vector_type(8))) short s8v;
typedef __attribute__((ext_vector_type(4))) float f4v;

#define MFMA16(a, b, c) __builtin_amdgcn_mfma_f32_16x16x32_bf16((a), (b), (c), 0, 0, 0)

static const int NB   = 32;    // batch
static const int NPIX = 1024;  // 32x32
static const int CIN  = 264;
static const int C1   = 128;
static const int C2   = 256;
static const int VF_  = 258;
static const int DS_  = 300;
static const int LL   = 20;

__device__ __forceinline__ ushort_t f2b(float x) {
  unsigned u = __builtin_bit_cast(unsigned, x);
  u = (u + 0x7fffu + ((u >> 16) & 1u)) >> 16;
  return (ushort_t)u;
}

// ---------------- small utility kernels ----------------

// src [N][K=258] fp32 row-major -> dst [384][288] bf16, zero padded
__global__ void k_wprep(const float* __restrict__ src, ushort_t* __restrict__ dst, int N) {
  int i = blockIdx.x * TPB + threadIdx.x;
  if (i >= 384 * 288) return;
  int n = i / 288, k = i - n * 288;
  float v = (n < N && k < 258) ? src[(size_t)n * 258 + k] : 0.f;
  dst[i] = f2b(v);
}

// w[oc][ic][3][3] fp32 -> w_r[oc][tap][icpad] bf16 (pad ic with 0)
__global__ void k_wreorder(const float* __restrict__ w, ushort_t* __restrict__ wr,
                           int Cout, int Cin, int ICPAD) {
  int i = blockIdx.x * TPB + threadIdx.x;
  int total = Cout * 9 * ICPAD;
  if (i >= total) return;
  int ic = i % ICPAD;
  int t = (i / ICPAD) % 9;
  int oc = i / (ICPAD * 9);
  float v = (ic < Cin) ? w[((size_t)oc * Cin + ic) * 9 + t] : 0.f;
  wr[i] = f2b(v);
}

// concat(video,spatial) -> NHWC bf16 [b][1024][288], pad ch 264..287 = 0
__global__ __launch_bounds__(TPB) void k_cat_nhwc(const float* __restrict__ video,
                                                  const float* __restrict__ spatial,
                                                  ushort_t* __restrict__ dst) {
  const int pb = blockIdx.x;  // 16 blocks of 64 px
  const int b  = blockIdx.y;
  const int tid = threadIdx.x;
  __shared__ ushort_t lds[264][72];
  for (int u = tid; u < 264 * 64; u += TPB) {
    int c = u >> 6, px = u & 63;
    int p = (pb << 6) + px;
    float v = (c < 256) ? video[(((size_t)b * 256 + c) << 10) + p]
                        : spatial[(((size_t)b * 8 + (c - 256)) << 10) + p];
    lds[c][px] = f2b(v);
  }
  __syncthreads();
  for (int u = tid; u < 64 * 36; u += TPB) {
    int px = u / 36, ch = u - px * 36;
    s8v v;
#pragma unroll
    for (int j = 0; j < 8; ++j) {
      int ic = ch * 8 + j;
      v[j] = (ic < 264) ? (short)lds[ic][px] : (short)0;
    }
    *(s8v*)(dst + ((size_t)((b << 10) + (pb << 6) + px)) * 288 + ch * 8) = v;
  }
}

// c-major fp32 [b][128][1024] -> NHWC bf16 [b][1024][128]
__global__ __launch_bounds__(TPB) void k_to_nhwc128(const float* __restrict__ src,
                                                    ushort_t* __restrict__ dst) {
  const int pb = blockIdx.x;
  const int b  = blockIdx.y;
  const int tid = threadIdx.x;
  __shared__ ushort_t lds[128][72];
  for (int u = tid; u < 128 * 64; u += TPB) {
    int c = u >> 6, px = u & 63;
    int p = (pb << 6) + px;
    lds[c][px] = f2b(src[(((size_t)b * 128 + c) << 10) + p]);
  }
  __syncthreads();
  for (int u = tid; u < 64 * 16; u += TPB) {
    int px = u >> 4, ch = u & 15;
    s8v v;
#pragma unroll
    for (int j = 0; j < 8; ++j) v[j] = (short)lds[ch * 8 + j][px];
    *(s8v*)(dst + ((size_t)((b << 10) + (pb << 6) + px)) * 128 + ch * 8) = v;
  }
}

// gn2'd y2 (c-major fp32 [b][256][1024]) + coords -> vso_h bf16 [b][1024][288]
__global__ __launch_bounds__(TPB) void k_build_vsoh(const float* __restrict__ y2,
                                                    ushort_t* __restrict__ dst) {
  const int pb = blockIdx.x;
  const int b  = blockIdx.y;
  const int tid = threadIdx.x;
  __shared__ ushort_t lds[256][72];
  for (int u = tid; u < 256 * 64; u += TPB) {
    int c = u >> 6, px = u & 63;
    int p = (pb << 6) + px;
    lds[c][px] = f2b(y2[(((size_t)b * 256 + c) << 10) + p]);
  }
  __syncthreads();
  for (int u = tid; u < 64 * 36; u += TPB) {
    int px = u / 36, ch = u - px * 36;
    int p = (pb << 6) + px;
    s8v v;
#pragma unroll
    for (int j = 0; j < 8; ++j) {
      int cg = ch * 8 + j;
      float fv;
      if (cg < 256)      { v[j] = (short)lds[cg][px]; continue; }
      else if (cg == 256) fv = -1.f + (2.f / 31.f) * (float)(p & 31);
      else if (cg == 257) fv = -1.f + (2.f / 31.f) * (float)(p >> 5);
      else                fv = 0.f;
      v[j] = (short)f2b(fv);
    }
    *(s8v*)(dst + ((size_t)((b << 10) + p)) * 288 + ch * 8) = v;
  }
}

__global__ void k_tmaxmod(const float* __restrict__ txt, const float* __restrict__ inc_w,
                          const float* __restrict__ inc_b, float* __restrict__ mod) {
  int b = blockIdx.x;
  __shared__ float tm[DS_];
  for (int d = threadIdx.x; d < DS_; d += TPB) {
    const float* p = txt + ((size_t)b * DS_ + d) * LL;
    float m = p[0];
    for (int l = 1; l < LL; ++l) m = fmaxf(m, p[l]);
    tm[d] = m;
  }
  __syncthreads();
  for (int oc = threadIdx.x; oc < VF_; oc += TPB) {
    const float* wr = inc_w + (size_t)oc * DS_;
    float s = inc_b[oc];
    for (int d = 0; d < DS_; ++d) s += tm[d] * wr[d];
    mod[(size_t)b * VF_ + oc] = s;
  }
}

// ---------------- conv 3x3 via bf16 MFMA implicit GEMM ----------------
template <int ICG>
__global__ __launch_bounds__(TPB) void k_conv_mfma(const ushort_t* __restrict__ in_h,
                                                   const ushort_t* __restrict__ wr,
                                                   const float* __restrict__ bias,
                                                   float* __restrict__ out, int Cout) {
  const int ICPAD = ICG * 8;
  const int ICGS = 4 * 34 * 8 + 16;
  const int b   = blockIdx.z;
  const int ocb = blockIdx.y << 7;
  const int pxb = blockIdx.x;
  const int tid = threadIdx.x;
  const int w = tid >> 6, lane = tid & 63;
  const int lhi = lane >> 4, llo = lane & 15;

  __shared__ ushort_t in_t[ICG * ICGS];

  for (int u = tid; u < ICG * 136; u += TPB) {
    int icg = u / 136;
    int rem = u - icg * 136;
    int row = rem / 34;
    int col = rem - row * 34;
    int gy = (pxb << 1) - 1 + row;
    int gx = col - 1;
    s8v v = (s8v){0, 0, 0, 0, 0, 0, 0, 0};
    if ((unsigned)gy < 32u && (unsigned)gx < 32u)
      v = *(const s8v*)(in_h + ((size_t)((b << 10) + (gy << 5) + gx)) * ICPAD + icg * 8);
    *(s8v*)&in_t[icg * ICGS + (row * 34 + col) * 8] = v;
  }
  __syncthreads();

  f4v acc[2][4];
#pragma unroll
  for (int i = 0; i < 2; ++i)
#pragma unroll
    for (int m = 0; m < 4; ++m) acc[i][m] = (f4v){0.f, 0.f, 0.f, 0.f};

  const ushort_t* wbase = wr + ((size_t)(ocb + w * 32 + llo) * 9) * ICPAD + lhi * 8;
  const size_t ocstep = (size_t)16 * 9 * ICPAD;

  for (int t = 0; t < 9; ++t) {
    const int ky = t / 3, kx = t - ky * 3;
#pragma unroll
    for (int s = 0; s < ICG / 4; ++s) {
      const ushort_t* wp = wbase + (size_t)t * ICPAD + s * 32;
      s8v a0 = *(const s8v*)(wp);
      s8v a1 = *(const s8v*)(wp + ocstep);
      const int icg = (s << 2) + lhi;
#pragma unroll
      for (int m = 0; m < 4; ++m) {
        const int row = (m >> 1) + ky;
        const int col = ((m & 1) << 4) + llo + kx;
        s8v bm = *(const s8v*)&in_t[icg * ICGS + (row * 34 + col) * 8];
        acc[0][m] = MFMA16(a0, bm, acc[0][m]);
        acc[1][m] = MFMA16(a1, bm, acc[1][m]);
      }
    }
  }

#pragma unroll
  for (int i = 0; i < 2; ++i) {
#pragma unroll
    for (int r = 0; r < 4; ++r) {
      const int oc = ocb + w * 32 + i * 16 + lhi * 4 + r;
      const float bv = bias[oc];
#pragma unroll
      for (int m = 0; m < 4; ++m) {
        const int px = (pxb << 6) + (m << 4) + llo;
        out[(((size_t)b * Cout + oc) << 10) + px] = acc[i][m][r] + bv;
      }
    }
  }
}

// ---------------- GroupNorm + ReLU, in place (c-major fp32) ----------------
__global__ __launch_bounds__(TPB) void k_gnrelu(float* __restrict__ x,
                                                const float* __restrict__ gamma,
                                                const float* __restrict__ beta,
                                                int C, int cpg) {
  const int g = blockIdx.x, b = blockIdx.y;
  const int M = cpg << 10;
  float* base = x + (((size_t)b * C + g * cpg) << 10);
  float s = 0.f, ss = 0.f;
  for (int i = threadIdx.x; i < M; i += TPB) {
    float v = base[i];
    s += v;
    ss += v * v;
  }
  __shared__ float rs[4], rss[4];
#pragma unroll
  for (int off = 32; off > 0; off >>= 1) {
    s += __shfl_down(s, off);
    ss += __shfl_down(ss, off);
  }
  if ((threadIdx.x & 63) == 0) { rs[threadIdx.x >> 6] = s; rss[threadIdx.x >> 6] = ss; }
  __syncthreads();
  if (threadIdx.x == 0) {
    float S = 0.f, SS = 0.f;
    for (int i = 0; i < 4; ++i) { S += rs[i]; SS += rss[i]; }
    float mean = S / (float)M;
    float var = SS / (float)M - mean * mean;
    rs[0] = mean;
    rss[0] = rsqrtf(var + 1e-5f);
  }
  __syncthreads();
  float mean = rs[0], rsig = rss[0];
  for (int i = threadIdx.x; i < M; i += TPB) {
    int c = g * cpg + (i >> 10);
    float v = (base[i] - mean) * rsig * gamma[c] + beta[c];
    base[i] = v > 0.f ? v : 0.f;
  }
}

// ---------------- bf16 MFMA GEMM: out = vso_h @ W^T (+bias [, *mod]) ----------------
// A: [b][1024][288] bf16; Bw: [384][288] bf16 zero-padded.
// MODE 0: fp32 out [b][1024][300]          (vsr)
// MODE 1: bf16 out [b][1024][288], *mod    (k, q)
// MODE 2: bf16 out chunk-blocked Vt [b][32][272][32]  (v)
template <int MODE>
__global__ __launch_bounds__(TPB) void k_gemm_mfma(const ushort_t* __restrict__ A,
                                                   const ushort_t* __restrict__ Bw,
                                                   void* __restrict__ Cout,
                                                   const float* __restrict__ bias,
                                                   const float* __restrict__ mod) {
  const int b = blockIdx.z;
  const int n0 = blockIdx.x << 7;
  const int m0 = blockIdx.y << 7;
  const int tid = threadIdx.x;
  const int w = tid >> 6, lane = tid & 63;
  const int wr = w >> 1, wc = w & 1;
  const int lhi = lane >> 4, llo = lane & 15;

  __shared__ ushort_t A_l[128][40];
  __shared__ ushort_t B_l[128][40];

  f4v acc[4][4];
#pragma unroll
  for (int i = 0; i < 4; ++i)
#pragma unroll
    for (int j = 0; j < 4; ++j) acc[i][j] = (f4v){0.f, 0.f, 0.f, 0.f};

  const ushort_t* Ab = A + (((size_t)b << 10)) * 288;

  for (int k0 = 0; k0 < 288; k0 += 32) {
    for (int u = tid; u < 512; u += TPB) {
      int row = u >> 2, seg = u & 3;
      *(s8v*)&A_l[row][seg * 8] = *(const s8v*)(Ab + (size_t)(m0 + row) * 288 + k0 + seg * 8);
      *(s8v*)&B_l[row][seg * 8] = *(const s8v*)(Bw + (size_t)(n0 + row) * 288 + k0 + seg * 8);
    }
    __syncthreads();
    s8v am[4], bn[4];
#pragma unroll
    for (int i = 0; i < 4; ++i) am[i] = *(const s8v*)&A_l[wr * 64 + i * 16 + llo][lhi * 8];
#pragma unroll
    for (int j = 0; j < 4; ++j) bn[j] = *(const s8v*)&B_l[wc * 64 + j * 16 + llo][lhi * 8];
#pragma unroll
    for (int i = 0; i < 4; ++i)
#pragma unroll
      for (int j = 0; j < 4; ++j) {
        if (MODE == 2) acc[i][j] = MFMA16(bn[j], am[i], acc[i][j]);
        else           acc[i][j] = MFMA16(am[i], bn[j], acc[i][j]);
      }
    __syncthreads();
  }

  if (MODE == 0) {
    float* Cf = (float*)Cout + (size_t)b * 1024 * 300;
#pragma unroll
    for (int j = 0; j < 4; ++j) {
      int n = n0 + wc * 64 + j * 16 + llo;
      if (n >= 300) continue;
      float bv = bias[n];
#pragma unroll
      for (int i = 0; i < 4; ++i)
#pragma unroll
        for (int r = 0; r < 4; ++r) {
          int m = m0 + wr * 64 + i * 16 + lhi * 4 + r;
          Cf[(size_t)m * 300 + n] = acc[i][j][r] + bv;
        }
    }
  } else if (MODE == 1) {
    ushort_t* Cb = (ushort_t*)Cout + (size_t)b * 1024 * 288;
#pragma unroll
    for (int j = 0; j < 4; ++j) {
      int n = n0 + wc * 64 + j * 16 + llo;
      if (n >= 288) continue;
      bool real = n < VF_;
      float bv = real ? bias[n] : 0.f;
      float sm = real ? mod[(size_t)b * VF_ + n] : 0.f;
#pragma unroll
      for (int i = 0; i < 4; ++i)
#pragma unroll
        for (int r = 0; r < 4; ++r) {
          int m = m0 + wr * 64 + i * 16 + lhi * 4 + r;
          Cb[(size_t)m * 288 + n] = f2b(real ? (acc[i][j][r] + bv) * sm : 0.f);
        }
    }
  } else {
    // chunk-blocked transposed store: Vt_blk[b][m>>5][n][m&31]
    ushort_t* Cb = (ushort_t*)Cout + (size_t)b * 32 * 272 * 32;
#pragma unroll
    for (int j = 0; j < 4; ++j)
#pragma unroll
      for (int r = 0; r < 4; ++r) {
        int n = n0 + wc * 64 + j * 16 + lhi * 4 + r;
        if (n >= 272) continue;
        bool real = n < VF_;
        float bv = real ? bias[n] : 0.f;
#pragma unroll
        for (int i = 0; i < 4; ++i) {
          int m = m0 + wr * 64 + i * 16 + llo;
          int mc = m >> 5, mlo = m & 31;
          Cb[(((size_t)mc * 272 + n) << 5) + mlo] = f2b(real ? acc[i][j][r] + bv : 0.f);
        }
      }
  }
}

// ---------------- txt cross-attention ----------------
__global__ __launch_bounds__(TPB) void k_txtattn(const float* __restrict__ vsr,
                                                 const float* __restrict__ txt,
                                                 float* __restrict__ out) {
  const int b = blockIdx.y;
  const int p = blockIdx.x * TPB + threadIdx.x;
  __shared__ float tl[DS_ * LL];
  for (int i = threadIdx.x; i < DS_ * LL; i += TPB) tl[i] = txt[(size_t)b * DS_ * LL + i];
  __syncthreads();
  const float* vr = vsr + ((size_t)b * NPIX + p) * DS_;
  float lg[LL];
#pragma unroll
  for (int l = 0; l < LL; ++l) lg[l] = 0.f;
  for (int d = 0; d < DS_; d += 4) {
    float4 vv = *(const float4*)(vr + d);
    const float* tr = tl + d * LL;
#pragma unroll
    for (int l = 0; l < LL; ++l)
      lg[l] += vv.x * tr[l] + vv.y * tr[l + 20] + vv.z * tr[l + 40] + vv.w * tr[l + 60];
  }
  const float sc = 0.057735026919f;
  float mx = lg[0] * sc;
#pragma unroll
  for (int l = 1; l < LL; ++l) mx = fmaxf(mx, lg[l] * sc);
  float sum = 0.f;
#pragma unroll
  for (int l = 0; l < LL; ++l) {
    lg[l] = __expf(lg[l] * sc - mx);
    sum += lg[l];
  }
  float inv = 1.f / sum;
#pragma unroll
  for (int l = 0; l < LL; ++l) lg[l] *= inv;
  float* ob = out + (((size_t)b * 558 + VF_) << 10) + p;
  for (int d = 0; d < DS_; ++d) {
    const float* tr = tl + d * LL;
    float s = 0.f;
#pragma unroll
    for (int l = 0; l < LL; ++l) s += lg[l] * tr[l];
    ob[(size_t)d << 10] = s;
  }
}

// ---------------- video self-attention: bf16 MFMA flash (T14 dbuf + blocked Vt) ----------------
// K,Q: bf16 [b][1024][288]. Vt_blk: bf16 [b][32][272][32].
__global__ __launch_bounds__(256, 2) void k_flash_mfma(const ushort_t* __restrict__ Kb,
                                                       const ushort_t* __restrict__ Qb,
                                                       const ushort_t* __restrict__ Vtb,
                                                       float* __restrict__ out) {
  // XCD-aware swizzle: all 16 n-blocks of a batch on one XCD
  const int wg = blockIdx.x;           // 0..511
  const int xcd = wg & 7, s = wg >> 3; // s 0..63
  const int b = xcd * 4 + (s >> 4);
  const int n0 = (s & 15) << 6;
  const int tid = threadIdx.x;
  const int w = tid >> 6, lane = tid & 63;
  const int lhi = lane >> 4;
  const int llo = lane & 15;

  __shared__ ushort_t q_l[32][296];   // stride 296 (148 dw) -> 2-way
  __shared__ ushort_t vt_l[272][36];  // stride 36 (18 dw)  -> 2-way
  __shared__ ushort_t p_l[64][36];

  s8v kf[9];
  {
    const ushort_t* kp = Kb + ((size_t)(b * 1024 + n0 + w * 16 + llo)) * 288 + lhi * 8;
#pragma unroll
    for (int ks = 0; ks < 9; ++ks) kf[ks] = *(const s8v*)(kp + ks * 32);
  }

  const ushort_t* Qbase = Qb + (((size_t)b << 10)) * 288;
  const ushort_t* Vbase = Vtb + (size_t)b * 32 * 272 * 32;

  s8v qs[5], vs[5];
  // stage issue: chunk mc -> regs
  auto ISSUE = [&](int mc) {
#pragma unroll
    for (int i = 0; i < 5; ++i) {
      int u = tid + (i << 8);
      if (u < 1152) qs[i] = *(const s8v*)(Qbase + (size_t)((mc << 5) + u / 36) * 288 + (u % 36) * 8);
      if (u < 1088) vs[i] = *(const s8v*)(Vbase + (size_t)mc * 8704 + (u << 3));
    }
  };
  // regs -> LDS
  auto WRITE = [&]() {
#pragma unroll
    for (int i = 0; i < 5; ++i) {
      int u = tid + (i << 8);
      if (u < 1152) *(s8v*)&q_l[u / 36][(u % 36) * 8] = qs[i];
      if (u < 1088) *(s8v*)&vt_l[u >> 2][(u & 3) * 8] = vs[i];
    }
  };

  f4v oacc[17];
#pragma unroll
  for (int i = 0; i < 17; ++i) oacc[i] = (f4v){0.f, 0.f, 0.f, 0.f};
  float mreg[4], lreg[4];
#pragma unroll
  for (int r = 0; r < 4; ++r) { mreg[r] = -1e30f; lreg[r] = 0.f; }

  const float sc = 0.0622572819f;  // 1/sqrt(258)
  const int src16 = ((llo >> 2) << 4) | (llo & 3);

  // prologue
  ISSUE(0);
  WRITE();
  __syncthreads();
  ISSUE(1);

  for (int mc = 0; mc < 32; ++mc) {
    // QK^T on LDS chunk mc
    f4v sacc0 = {0.f, 0.f, 0.f, 0.f}, sacc1 = {0.f, 0.f, 0.f, 0.f};
#pragma unroll
    for (int ks = 0; ks < 9; ++ks) {
      s8v q0 = *(const s8v*)&q_l[llo][ks * 32 + lhi * 8];
      s8v q1 = *(const s8v*)&q_l[16 + llo][ks * 32 + lhi * 8];
      sacc0 = MFMA16(kf[ks], q0, sacc0);
      sacc1 = MFMA16(kf[ks], q1, sacc1);
    }

    // wave-parallel online softmax
    float cmax[4], rsum[4], alpha[4];
#pragma unroll
    for (int r = 0; r < 4; ++r) cmax[r] = fmaxf(sacc0[r], sacc1[r]);
#pragma unroll
    for (int off = 1; off < 16; off <<= 1)
#pragma unroll
      for (int r = 0; r < 4; ++r) cmax[r] = fmaxf(cmax[r], __shfl_xor(cmax[r], off));
#pragma unroll
    for (int r = 0; r < 4; ++r) {
      float mn = fmaxf(mreg[r], cmax[r] * sc);
      alpha[r] = __expf(mreg[r] - mn);
      mreg[r] = mn;
    }
    const int prow = w * 16 + lhi * 4;
#pragma unroll
    for (int r = 0; r < 4; ++r) {
      float p0 = __expf(sacc0[r] * sc - mreg[r]);
      float p1 = __expf(sacc1[r] * sc - mreg[r]);
      rsum[r] = p0 + p1;
      p_l[prow + r][llo] = f2b(p0);
      p_l[prow + r][16 + llo] = f2b(p1);
    }
#pragma unroll
    for (int off = 1; off < 16; off <<= 1)
#pragma unroll
      for (int r = 0; r < 4; ++r) rsum[r] += __shfl_xor(rsum[r], off);
#pragma unroll
    for (int r = 0; r < 4; ++r) lreg[r] = lreg[r] * alpha[r] + rsum[r];

    float prep = (lane & 2) ? ((lane & 1) ? alpha[3] : alpha[2])
                            : ((lane & 1) ? alpha[1] : alpha[0]);
    float alphaN = __shfl(prep, src16, 64);

    asm volatile("s_waitcnt lgkmcnt(0)" ::: "memory");
    __builtin_amdgcn_sched_barrier(0);

    // PV (swapped operands): O^T[d][n] += Vt_tile * P
    s8v pf = *(const s8v*)&p_l[w * 16 + llo][lhi * 8];
#pragma unroll
    for (int dt = 0; dt < 17; ++dt) {
      s8v vf = *(const s8v*)&vt_l[dt * 16 + llo][lhi * 8];
      f4v o = oacc[dt];
      o[0] *= alphaN; o[1] *= alphaN; o[2] *= alphaN; o[3] *= alphaN;
      oacc[dt] = MFMA16(vf, pf, o);
    }

    __syncthreads();  // all waves done reading chunk mc from LDS
    if (mc < 31) {
      WRITE();        // chunk mc+1 -> LDS (waits on its vmcnt via reg deps)
      __syncthreads();
      if (mc < 30) ISSUE(mc + 2);
    }
  }

  // epilogue
  float prep = (lane & 2) ? ((lane & 1) ? lreg[3] : lreg[2])
                          : ((lane & 1) ? lreg[1] : lreg[0]);
  float linv = 1.f / __shfl(prep, src16, 64);
  const int n = n0 + w * 16 + llo;
#pragma unroll
  for (int dt = 0; dt < 17; ++dt) {
#pragma unroll
    for (int r = 0; r < 4; ++r) {
      int d = dt * 16 + lhi * 4 + r;
      if (d < VF_) out[((size_t)(b * 558 + d) << 10) + n] = oacc[dt][r] * linv;
    }
  }
}

// ---------------- launcher ----------------
extern "C" void kernel_launch(void* const* d_in, const int* in_sizes, int n_in,
                              void* d_out, int out_size, void* d_ws, size_t ws_size,
                              hipStream_t stream) {
  const float* spatial = (const float*)d_in[0];
  const float* video   = (const float*)d_in[1];
  const float* txt     = (const float*)d_in[2];
  const float* c1w = (const float*)d_in[3];
  const float* c1b = (const float*)d_in[4];
  const float* g1g = (const float*)d_in[5];
  const float* g1b = (const float*)d_in[6];
  const float* c2w = (const float*)d_in[7];
  const float* c2b = (const float*)d_in[8];
  const float* g2g = (const float*)d_in[9];
  const float* g2b = (const float*)d_in[10];
  const float* rw  = (const float*)d_in[11];
  const float* rb  = (const float*)d_in[12];
  const float* kw  = (const float*)d_in[13];
  const float* kb  = (const float*)d_in[14];
  const float* qw  = (const float*)d_in[15];
  const float* qb  = (const float*)d_in[16];
  const float* vw  = (const float*)d_in[17];
  const float* vb  = (const float*)d_in[18];
  const float* iw  = (const float*)d_in[19];
  const float* ib  = (const float*)d_in[20];
  float* out = (float*)d_out;
  float* ws = (float*)d_ws;

  // ws layout (float offsets), lifetime-aliased
  ushort_t* x0h   = (ushort_t*)(ws + 0);          // [0, 4.72M) -> conv1
  float*    vsr   = ws + 0;                       // [0, 9.83M)  after x1h dead
  float*    y1    = ws + 5000000;                 // [5.0M, 9.2M)
  ushort_t* x1h   = (ushort_t*)(ws + 9300000);    // [9.3M, 11.4M)
  ushort_t* kb16  = (ushort_t*)(ws + 10000000);   // [10.0M, 14.72M)  after y2 dead
  float*    y2    = ws + 11500000;                // [11.5M, 19.9M)
  ushort_t* qb16  = (ushort_t*)(ws + 14800000);   // [14.8M, 19.52M)  after y2 dead
  ushort_t* vsoh  = (ushort_t*)(ws + 20000000);   // [20.0M, 24.72M)
  ushort_t* vtb16 = (ushort_t*)(ws + 24800000);   // [24.8M, 29.26M)
  ushort_t* rwp   = (ushort_t*)(ws + 29300000);
  ushort_t* kwp   = (ushort_t*)(ws + 29360000);
  ushort_t* qwp   = (ushort_t*)(ws + 29420000);
  ushort_t* vwp   = (ushort_t*)(ws + 29480000);
  ushort_t* w1r   = (ushort_t*)(ws + 29540000);
  ushort_t* w2r   = (ushort_t*)(ws + 29710000);
  float*    mod   = ws + 29860000;

  // weight prep
  k_wreorder<<<(128 * 9 * 288 + TPB - 1) / TPB, TPB, 0, stream>>>(c1w, w1r, 128, 264, 288);
  k_wreorder<<<(256 * 9 * 128 + TPB - 1) / TPB, TPB, 0, stream>>>(c2w, w2r, 256, 128, 128);
  {
    int tot = 384 * 288;
    k_wprep<<<(tot + TPB - 1) / TPB, TPB, 0, stream>>>(rw, rwp, 300);
    k_wprep<<<(tot + TPB - 1) / TPB, TPB, 0, stream>>>(kw, kwp, 258);
    k_wprep<<<(tot + TPB - 1) / TPB, TPB, 0, stream>>>(qw, qwp, 258);
    k_wprep<<<(tot + TPB - 1) / TPB, TPB, 0, stream>>>(vw, vwp, 258);
  }

  // concat -> NHWC bf16
  k_cat_nhwc<<<dim3(16, NB), TPB, 0, stream>>>(video, spatial, x0h);

  // conv1 (MFMA) + GN1 + relu -> NHWC bf16
  k_conv_mfma<36><<<dim3(16, 1, NB), TPB, 0, stream>>>(x0h, w1r, c1b, y1, C1);
  k_gnrelu<<<dim3(32, NB), TPB, 0, stream>>>(y1, g1g, g1b, C1, 4);
  k_to_nhwc128<<<dim3(16, NB), TPB, 0, stream>>>(y1, x1h);

  k_tmaxmod<<<NB, TPB, 0, stream>>>(txt, iw, ib, mod);

  // conv2 (MFMA) + GN2 + relu (c-major fp32)
  k_conv_mfma<16><<<dim3(16, 2, NB), TPB, 0, stream>>>(x1h, w2r, c2b, y2, C2);
  k_gnrelu<<<dim3(32, NB), TPB, 0, stream>>>(y2, g2g, g2b, C2, 8);

  // vso_h bf16 NHWC (+coords)
  k_build_vsoh<<<dim3(16, NB), TPB, 0, stream>>>(y2, vsoh);

  // vsr = vso @ reduce_w^T + reduce_b (MFMA, fp32 out)
  k_gemm_mfma<0><<<dim3(3, 8, NB), TPB, 0, stream>>>(vsoh, rwp, (void*)vsr, rb, nullptr);

  // txt attention -> out channels [258, 558)
  k_txtattn<<<dim3(4, NB), TPB, 0, stream>>>(vsr, txt, out);

  // k, q (bf16 [m][288], *mod), v (bf16 chunk-blocked Vt)
  k_gemm_mfma<1><<<dim3(3, 8, NB), TPB, 0, stream>>>(vsoh, kwp, (void*)kb16, kb, mod);
  k_gemm_mfma<1><<<dim3(3, 8, NB), TPB, 0, stream>>>(vsoh, qwp, (void*)qb16, qb, mod);
  k_gemm_mfma<2><<<dim3(3, 8, NB), TPB, 0, stream>>>(vsoh, vwp, (void*)vtb16, vb, nullptr);

  // video self-attention (bf16 MFMA flash) -> out channels [0, 258)
  k_flash_mfma<<<dim3(512), 256, 0, stream>>>(kb16, qb16, vtb16, out);
}

// Round 7
// 451.684 us; speedup vs baseline: 8.7701x; 1.0003x over previous
//
#include <hip/hip_runtime.h>
#include <cstddef>

#define TPB 256

typedef unsigned short ushort_t;
typedef __attribute__((ext_vector_type(8))) short s8v;
typedef __attribute__((ext_vector_type(4))) float f4v;

#define MFMA16(a, b, c) __builtin_amdgcn_mfma_f32_16x16x32_bf16((a), (b), (c), 0, 0, 0)

static const int NB   = 32;    // batch
static const int NPIX = 1024;  // 32x32
static const int CIN  = 264;
static const int C1   = 128;
static const int C2   = 256;
static const int VF_  = 258;
static const int DS_  = 300;
static const int LL   = 20;

__device__ __forceinline__ ushort_t f2b(float x) {
  unsigned u = __builtin_bit_cast(unsigned, x);
  u = (u + 0x7fffu + ((u >> 16) & 1u)) >> 16;
  return (ushort_t)u;
}

// ---------------- small utility kernels ----------------

// src [N][K=258] fp32 row-major -> dst [384][288] bf16, zero padded
__global__ void k_wprep(const float* __restrict__ src, ushort_t* __restrict__ dst, int N) {
  int i = blockIdx.x * TPB + threadIdx.x;
  if (i >= 384 * 288) return;
  int n = i / 288, k = i - n * 288;
  float v = (n < N && k < 258) ? src[(size_t)n * 258 + k] : 0.f;
  dst[i] = f2b(v);
}

// w[oc][ic][3][3] fp32 -> w_r[t][s][oc][32] bf16 (ic = s*32+j, zero pad)
__global__ void k_wreorder2(const float* __restrict__ w, ushort_t* __restrict__ wr,
                            int Cout, int Cin, int NS) {
  int i = blockIdx.x * TPB + threadIdx.x;
  int total = 9 * NS * Cout * 32;
  if (i >= total) return;
  int j = i & 31;
  int oc = (i >> 5) % Cout;
  int ts = (i >> 5) / Cout;
  int s = ts % NS, t = ts / NS;
  int ic = s * 32 + j;
  float v = (ic < Cin) ? w[((size_t)oc * Cin + ic) * 9 + t] : 0.f;
  wr[i] = f2b(v);
}

// concat(video,spatial) -> NHWC bf16 [b][1024][288], pad ch 264..287 = 0
__global__ __launch_bounds__(TPB) void k_cat_nhwc(const float* __restrict__ video,
                                                  const float* __restrict__ spatial,
                                                  ushort_t* __restrict__ dst) {
  const int pb = blockIdx.x;  // 16 blocks of 64 px
  const int b  = blockIdx.y;
  const int tid = threadIdx.x;
  __shared__ ushort_t lds[264][72];
  for (int u = tid; u < 264 * 64; u += TPB) {
    int c = u >> 6, px = u & 63;
    int p = (pb << 6) + px;
    float v = (c < 256) ? video[(((size_t)b * 256 + c) << 10) + p]
                        : spatial[(((size_t)b * 8 + (c - 256)) << 10) + p];
    lds[c][px] = f2b(v);
  }
  __syncthreads();
  for (int u = tid; u < 64 * 36; u += TPB) {
    int px = u / 36, ch = u - px * 36;
    s8v v;
#pragma unroll
    for (int j = 0; j < 8; ++j) {
      int ic = ch * 8 + j;
      v[j] = (ic < 264) ? (short)lds[ic][px] : (short)0;
    }
    *(s8v*)(dst + ((size_t)((b << 10) + (pb << 6) + px)) * 288 + ch * 8) = v;
  }
}

// c-major fp32 [b][128][1024] -> NHWC bf16 [b][1024][128]
__global__ __launch_bounds__(TPB) void k_to_nhwc128(const float* __restrict__ src,
                                                    ushort_t* __restrict__ dst) {
  const int pb = blockIdx.x;
  const int b  = blockIdx.y;
  const int tid = threadIdx.x;
  __shared__ ushort_t lds[128][72];
  for (int u = tid; u < 128 * 64; u += TPB) {
    int c = u >> 6, px = u & 63;
    int p = (pb << 6) + px;
    lds[c][px] = f2b(src[(((size_t)b * 128 + c) << 10) + p]);
  }
  __syncthreads();
  for (int u = tid; u < 64 * 16; u += TPB) {
    int px = u >> 4, ch = u & 15;
    s8v v;
#pragma unroll
    for (int j = 0; j < 8; ++j) v[j] = (short)lds[ch * 8 + j][px];
    *(s8v*)(dst + ((size_t)((b << 10) + (pb << 6) + px)) * 128 + ch * 8) = v;
  }
}

// gn2'd y2 (c-major fp32 [b][256][1024]) + coords -> vso_h bf16 [b][1024][288]
__global__ __launch_bounds__(TPB) void k_build_vsoh(const float* __restrict__ y2,
                                                    ushort_t* __restrict__ dst) {
  const int pb = blockIdx.x;
  const int b  = blockIdx.y;
  const int tid = threadIdx.x;
  __shared__ ushort_t lds[256][72];
  for (int u = tid; u < 256 * 64; u += TPB) {
    int c = u >> 6, px = u & 63;
    int p = (pb << 6) + px;
    lds[c][px] = f2b(y2[(((size_t)b * 256 + c) << 10) + p]);
  }
  __syncthreads();
  for (int u = tid; u < 64 * 36; u += TPB) {
    int px = u / 36, ch = u - px * 36;
    int p = (pb << 6) + px;
    s8v v;
#pragma unroll
    for (int j = 0; j < 8; ++j) {
      int cg = ch * 8 + j;
      float fv;
      if (cg < 256)      { v[j] = (short)lds[cg][px]; continue; }
      else if (cg == 256) fv = -1.f + (2.f / 31.f) * (float)(p & 31);
      else if (cg == 257) fv = -1.f + (2.f / 31.f) * (float)(p >> 5);
      else                fv = 0.f;
      v[j] = (short)f2b(fv);
    }
    *(s8v*)(dst + ((size_t)((b << 10) + p)) * 288 + ch * 8) = v;
  }
}

__global__ void k_tmaxmod(const float* __restrict__ txt, const float* __restrict__ inc_w,
                          const float* __restrict__ inc_b, float* __restrict__ mod) {
  int b = blockIdx.x;
  __shared__ float tm[DS_];
  for (int d = threadIdx.x; d < DS_; d += TPB) {
    const float* p = txt + ((size_t)b * DS_ + d) * LL;
    float m = p[0];
    for (int l = 1; l < LL; ++l) m = fmaxf(m, p[l]);
    tm[d] = m;
  }
  __syncthreads();
  for (int oc = threadIdx.x; oc < VF_; oc += TPB) {
    const float* wr = inc_w + (size_t)oc * DS_;
    float s = inc_b[oc];
    for (int d = 0; d < DS_; ++d) s += tm[d] * wr[d];
    mod[(size_t)b * VF_ + oc] = s;
  }
}

// ---------------- conv 3x3 via bf16 MFMA implicit GEMM ----------------
// in_h: NHWC bf16 [b][1024][ICPAD]; wr: [t][s][Cout][32] bf16; out: fp32 c-major.
// Staging: linear coalesced copy of 4 image rows; x-halo cols always zero.
template <int ICG>
__global__ __launch_bounds__(TPB) void k_conv_mfma(const ushort_t* __restrict__ in_h,
                                                   const ushort_t* __restrict__ wr,
                                                   const float* __restrict__ bias,
                                                   float* __restrict__ out, int Cout) {
  const int ICPAD = ICG * 8;
  const int NS = ICG / 4;
  const int ICGS = 4 * 34 * 8 + 24;  // 1112 elems = 556 dw; 556%32=12 -> spread
  const int b   = blockIdx.z;
  const int ocb = blockIdx.y << 7;
  const int pxb = blockIdx.x;
  const int tid = threadIdx.x;
  const int w = tid >> 6, lane = tid & 63;
  const int lhi = lane >> 4, llo = lane & 15;

  __shared__ ushort_t in_t[ICG * ICGS];

  // zero x-halo columns (col 0 and 33, every icg, every row)
  for (int u = tid; u < ICG * 8; u += TPB) {
    int icg = u >> 3, rem = u & 7, row = rem >> 1, col = (rem & 1) ? 33 : 0;
    *(s8v*)&in_t[icg * ICGS + (row * 34 + col) * 8] = (s8v){0, 0, 0, 0, 0, 0, 0, 0};
  }
  // rows: linear coalesced copy (or zero when out of image)
  for (int r = 0; r < 4; ++r) {
    int gy = (pxb << 1) - 1 + r;
    if ((unsigned)gy < 32u) {
      const ushort_t* src = in_h + ((size_t)((b << 10) + (gy << 5))) * ICPAD;
      for (int u = tid; u < 32 * ICG; u += TPB) {
        int px = u / ICG, icg = u - px * ICG;
        *(s8v*)&in_t[icg * ICGS + (r * 34 + px + 1) * 8] = *(const s8v*)(src + u * 8);
      }
    } else {
      for (int u = tid; u < 32 * ICG; u += TPB) {
        int px = u / ICG, icg = u - px * ICG;
        *(s8v*)&in_t[icg * ICGS + (r * 34 + px + 1) * 8] = (s8v){0, 0, 0, 0, 0, 0, 0, 0};
      }
    }
  }
  __syncthreads();

  f4v acc[2][4];
#pragma unroll
  for (int i = 0; i < 2; ++i)
#pragma unroll
    for (int m = 0; m < 4; ++m) acc[i][m] = (f4v){0.f, 0.f, 0.f, 0.f};

  for (int t = 0; t < 9; ++t) {
    const int ky = t / 3, kx = t - ky * 3;
#pragma unroll
    for (int s = 0; s < NS; ++s) {
      const ushort_t* wp = wr + (((size_t)(t * NS + s) * Cout + ocb + w * 32 + llo) << 5) + lhi * 8;
      s8v a0 = *(const s8v*)(wp);
      s8v a1 = *(const s8v*)(wp + (16 << 5));
      const int icg = (s << 2) + lhi;
#pragma unroll
      for (int m = 0; m < 4; ++m) {
        const int row = (m >> 1) + ky;
        const int col = ((m & 1) << 4) + llo + kx;
        s8v bm = *(const s8v*)&in_t[icg * ICGS + (row * 34 + col) * 8];
        acc[0][m] = MFMA16(a0, bm, acc[0][m]);
        acc[1][m] = MFMA16(a1, bm, acc[1][m]);
      }
    }
  }

#pragma unroll
  for (int i = 0; i < 2; ++i) {
#pragma unroll
    for (int r = 0; r < 4; ++r) {
      const int oc = ocb + w * 32 + i * 16 + lhi * 4 + r;
      const float bv = bias[oc];
#pragma unroll
      for (int m = 0; m < 4; ++m) {
        const int px = (pxb << 6) + (m << 4) + llo;
        out[(((size_t)b * Cout + oc) << 10) + px] = acc[i][m][r] + bv;
      }
    }
  }
}

// ---------------- GroupNorm + ReLU, in place (c-major fp32) ----------------
__global__ __launch_bounds__(TPB) void k_gnrelu(float* __restrict__ x,
                                                const float* __restrict__ gamma,
                                                const float* __restrict__ beta,
                                                int C, int cpg) {
  const int g = blockIdx.x, b = blockIdx.y;
  const int M = cpg << 10;
  float* base = x + (((size_t)b * C + g * cpg) << 10);
  float s = 0.f, ss = 0.f;
  for (int i = threadIdx.x; i < M; i += TPB) {
    float v = base[i];
    s += v;
    ss += v * v;
  }
  __shared__ float rs[4], rss[4];
#pragma unroll
  for (int off = 32; off > 0; off >>= 1) {
    s += __shfl_down(s, off);
    ss += __shfl_down(ss, off);
  }
  if ((threadIdx.x & 63) == 0) { rs[threadIdx.x >> 6] = s; rss[threadIdx.x >> 6] = ss; }
  __syncthreads();
  if (threadIdx.x == 0) {
    float S = 0.f, SS = 0.f;
    for (int i = 0; i < 4; ++i) { S += rs[i]; SS += rss[i]; }
    float mean = S / (float)M;
    float var = SS / (float)M - mean * mean;
    rs[0] = mean;
    rss[0] = rsqrtf(var + 1e-5f);
  }
  __syncthreads();
  float mean = rs[0], rsig = rss[0];
  for (int i = threadIdx.x; i < M; i += TPB) {
    int c = g * cpg + (i >> 10);
    float v = (base[i] - mean) * rsig * gamma[c] + beta[c];
    base[i] = v > 0.f ? v : 0.f;
  }
}

// ---------------- bf16 MFMA GEMM: out = vso_h @ W^T (+bias [, *mod]) ----------------
template <int MODE>
__global__ __launch_bounds__(TPB) void k_gemm_mfma(const ushort_t* __restrict__ A,
                                                   const ushort_t* __restrict__ Bw,
                                                   void* __restrict__ Cout,
                                                   const float* __restrict__ bias,
                                                   const float* __restrict__ mod) {
  const int b = blockIdx.z;
  const int n0 = blockIdx.x << 7;
  const int m0 = blockIdx.y << 7;
  const int tid = threadIdx.x;
  const int w = tid >> 6, lane = tid & 63;
  const int wr = w >> 1, wc = w & 1;
  const int lhi = lane >> 4, llo = lane & 15;

  __shared__ ushort_t A_l[128][40];
  __shared__ ushort_t B_l[128][40];

  f4v acc[4][4];
#pragma unroll
  for (int i = 0; i < 4; ++i)
#pragma unroll
    for (int j = 0; j < 4; ++j) acc[i][j] = (f4v){0.f, 0.f, 0.f, 0.f};

  const ushort_t* Ab = A + (((size_t)b << 10)) * 288;

  for (int k0 = 0; k0 < 288; k0 += 32) {
    for (int u = tid; u < 512; u += TPB) {
      int row = u >> 2, seg = u & 3;
      *(s8v*)&A_l[row][seg * 8] = *(const s8v*)(Ab + (size_t)(m0 + row) * 288 + k0 + seg * 8);
      *(s8v*)&B_l[row][seg * 8] = *(const s8v*)(Bw + (size_t)(n0 + row) * 288 + k0 + seg * 8);
    }
    __syncthreads();
    s8v am[4], bn[4];
#pragma unroll
    for (int i = 0; i < 4; ++i) am[i] = *(const s8v*)&A_l[wr * 64 + i * 16 + llo][lhi * 8];
#pragma unroll
    for (int j = 0; j < 4; ++j) bn[j] = *(const s8v*)&B_l[wc * 64 + j * 16 + llo][lhi * 8];
#pragma unroll
    for (int i = 0; i < 4; ++i)
#pragma unroll
      for (int j = 0; j < 4; ++j) {
        if (MODE == 2) acc[i][j] = MFMA16(bn[j], am[i], acc[i][j]);
        else           acc[i][j] = MFMA16(am[i], bn[j], acc[i][j]);
      }
    __syncthreads();
  }

  if (MODE == 0) {
    float* Cf = (float*)Cout + (size_t)b * 1024 * 300;
#pragma unroll
    for (int j = 0; j < 4; ++j) {
      int n = n0 + wc * 64 + j * 16 + llo;
      if (n >= 300) continue;
      float bv = bias[n];
#pragma unroll
      for (int i = 0; i < 4; ++i)
#pragma unroll
        for (int r = 0; r < 4; ++r) {
          int m = m0 + wr * 64 + i * 16 + lhi * 4 + r;
          Cf[(size_t)m * 300 + n] = acc[i][j][r] + bv;
        }
    }
  } else if (MODE == 1) {
    ushort_t* Cb = (ushort_t*)Cout + (size_t)b * 1024 * 288;
#pragma unroll
    for (int j = 0; j < 4; ++j) {
      int n = n0 + wc * 64 + j * 16 + llo;
      if (n >= 288) continue;
      bool real = n < VF_;
      float bv = real ? bias[n] : 0.f;
      float sm = real ? mod[(size_t)b * VF_ + n] : 0.f;
#pragma unroll
      for (int i = 0; i < 4; ++i)
#pragma unroll
        for (int r = 0; r < 4; ++r) {
          int m = m0 + wr * 64 + i * 16 + lhi * 4 + r;
          Cb[(size_t)m * 288 + n] = f2b(real ? (acc[i][j][r] + bv) * sm : 0.f);
        }
    }
  } else {
    // chunk-blocked transposed store: Vt_blk[b][m>>5][n][m&31]
    ushort_t* Cb = (ushort_t*)Cout + (size_t)b * 32 * 272 * 32;
#pragma unroll
    for (int j = 0; j < 4; ++j)
#pragma unroll
      for (int r = 0; r < 4; ++r) {
        int n = n0 + wc * 64 + j * 16 + lhi * 4 + r;
        if (n >= 272) continue;
        bool real = n < VF_;
        float bv = real ? bias[n] : 0.f;
#pragma unroll
        for (int i = 0; i < 4; ++i) {
          int m = m0 + wr * 64 + i * 16 + llo;
          int mc = m >> 5, mlo = m & 31;
          Cb[(((size_t)mc * 272 + n) << 5) + mlo] = f2b(real ? acc[i][j][r] + bv : 0.f);
        }
      }
  }
}

// ---------------- txt cross-attention ----------------
__global__ __launch_bounds__(TPB) void k_txtattn(const float* __restrict__ vsr,
                                                 const float* __restrict__ txt,
                                                 float* __restrict__ out) {
  const int b = blockIdx.y;
  const int p = blockIdx.x * TPB + threadIdx.x;
  __shared__ float tl[DS_ * LL];
  for (int i = threadIdx.x; i < DS_ * LL; i += TPB) tl[i] = txt[(size_t)b * DS_ * LL + i];
  __syncthreads();
  const float* vr = vsr + ((size_t)b * NPIX + p) * DS_;
  float lg[LL];
#pragma unroll
  for (int l = 0; l < LL; ++l) lg[l] = 0.f;
  for (int d = 0; d < DS_; d += 4) {
    float4 vv = *(const float4*)(vr + d);
    const float* tr = tl + d * LL;
#pragma unroll
    for (int l = 0; l < LL; ++l)
      lg[l] += vv.x * tr[l] + vv.y * tr[l + 20] + vv.z * tr[l + 40] + vv.w * tr[l + 60];
  }
  const float sc = 0.057735026919f;
  float mx = lg[0] * sc;
#pragma unroll
  for (int l = 1; l < LL; ++l) mx = fmaxf(mx, lg[l] * sc);
  float sum = 0.f;
#pragma unroll
  for (int l = 0; l < LL; ++l) {
    lg[l] = __expf(lg[l] * sc - mx);
    sum += lg[l];
  }
  float inv = 1.f / sum;
#pragma unroll
  for (int l = 0; l < LL; ++l) lg[l] *= inv;
  float* ob = out + (((size_t)b * 558 + VF_) << 10) + p;
  for (int d = 0; d < DS_; ++d) {
    const float* tr = tl + d * LL;
    float s = 0.f;
#pragma unroll
    for (int l = 0; l < LL; ++l) s += lg[l] * tr[l];
    ob[(size_t)d << 10] = s;
  }
}

// ---------------- video self-attention: bf16 MFMA flash ----------------
// K,Q: bf16 [b][1024][288]. Vt_blk: bf16 [b][32][272][32].
__global__ __launch_bounds__(256, 2) void k_flash_mfma(const ushort_t* __restrict__ Kb,
                                                       const ushort_t* __restrict__ Qb,
                                                       const ushort_t* __restrict__ Vtb,
                                                       float* __restrict__ out) {
  const int wg = blockIdx.x;           // 0..511
  const int xcd = wg & 7, s = wg >> 3;
  const int b = xcd * 4 + (s >> 4);
  const int n0 = (s & 15) << 6;
  const int tid = threadIdx.x;
  const int w = tid >> 6, lane = tid & 63;
  const int lhi = lane >> 4;
  const int llo = lane & 15;

  __shared__ ushort_t q_l[32][296];
  __shared__ ushort_t vt_l[272][36];
  __shared__ ushort_t p_l[64][36];

  s8v kf[9];
  {
    const ushort_t* kp = Kb + ((size_t)(b * 1024 + n0 + w * 16 + llo)) * 288 + lhi * 8;
#pragma unroll
    for (int ks = 0; ks < 9; ++ks) kf[ks] = *(const s8v*)(kp + ks * 32);
  }

  const ushort_t* Qbase = Qb + (((size_t)b << 10)) * 288;
  const ushort_t* Vbase = Vtb + (size_t)b * 32 * 272 * 32;

  // precomputed staging pointers (advance by constant stride per chunk)
  const ushort_t* qp[5];
  const ushort_t* vp[5];
  ushort_t* qlp[5];
  ushort_t* vlp[5];
#pragma unroll
  for (int i = 0; i < 5; ++i) {
    int u = tid + (i << 8);
    int qr = u / 36, qc = u - qr * 36;
    qp[i] = Qbase + (size_t)qr * 288 + qc * 8;
    qlp[i] = (ushort_t*)q_l + qr * 296 + qc * 8;
    vp[i] = Vbase + (u << 3);
    vlp[i] = (ushort_t*)vt_l + (u >> 2) * 36 + (u & 3) * 8;
  }

  s8v qs[5], vs[5];
  auto ISSUE = [&]() {
#pragma unroll
    for (int i = 0; i < 5; ++i) {
      if (i < 4 || tid < 128) { qs[i] = *(const s8v*)qp[i]; qp[i] += 32 * 288; }
      if (i < 4 || tid < 64)  { vs[i] = *(const s8v*)vp[i]; vp[i] += 8704; }
    }
  };
  auto WRITE = [&]() {
#pragma unroll
    for (int i = 0; i < 5; ++i) {
      if (i < 4 || tid < 128) *(s8v*)qlp[i] = qs[i];
      if (i < 4 || tid < 64)  *(s8v*)vlp[i] = vs[i];
    }
  };

  f4v oacc[17];
#pragma unroll
  for (int i = 0; i < 17; ++i) oacc[i] = (f4v){0.f, 0.f, 0.f, 0.f};
  float mreg[4], lreg[4];
#pragma unroll
  for (int r = 0; r < 4; ++r) { mreg[r] = -1e30f; lreg[r] = 0.f; }

  const float sc = 0.0622572819f;  // 1/sqrt(258)
  const int src16 = ((llo >> 2) << 4) | (llo & 3);

  ISSUE();
  WRITE();
  __syncthreads();
  ISSUE();

  for (int mc = 0; mc < 32; ++mc) {
    // QK^T on LDS chunk mc
    f4v sacc0 = {0.f, 0.f, 0.f, 0.f}, sacc1 = {0.f, 0.f, 0.f, 0.f};
#pragma unroll
    for (int ks = 0; ks < 9; ++ks) {
      s8v q0 = *(const s8v*)&q_l[llo][ks * 32 + lhi * 8];
      s8v q1 = *(const s8v*)&q_l[16 + llo][ks * 32 + lhi * 8];
      sacc0 = MFMA16(kf[ks], q0, sacc0);
      sacc1 = MFMA16(kf[ks], q1, sacc1);
    }

    // chunk max (reduced over 16 llo lanes)
    float cmax[4];
#pragma unroll
    for (int r = 0; r < 4; ++r) cmax[r] = fmaxf(sacc0[r], sacc1[r]);
#pragma unroll
    for (int off = 1; off < 16; off <<= 1)
#pragma unroll
      for (int r = 0; r < 4; ++r) cmax[r] = fmaxf(cmax[r], __shfl_xor(cmax[r], off));

    // T13 defer-max: only rescale when some row max grew past threshold
    bool need = false;
#pragma unroll
    for (int r = 0; r < 4; ++r) need |= (cmax[r] * sc > mreg[r] + 8.f);
    if (__any(need)) {
      float alpha[4];
#pragma unroll
      for (int r = 0; r < 4; ++r) {
        float mn = fmaxf(mreg[r], cmax[r] * sc);
        alpha[r] = __expf(mreg[r] - mn);
        mreg[r] = mn;
        lreg[r] *= alpha[r];
      }
      float prep = (lane & 2) ? ((lane & 1) ? alpha[3] : alpha[2])
                              : ((lane & 1) ? alpha[1] : alpha[0]);
      float alphaN = __shfl(prep, src16, 64);
#pragma unroll
      for (int dt = 0; dt < 17; ++dt) {
        oacc[dt][0] *= alphaN; oacc[dt][1] *= alphaN;
        oacc[dt][2] *= alphaN; oacc[dt][3] *= alphaN;
      }
    }

    float rsum[4];
    const int prow = w * 16 + lhi * 4;
#pragma unroll
    for (int r = 0; r < 4; ++r) {
      float p0 = __expf(sacc0[r] * sc - mreg[r]);
      float p1 = __expf(sacc1[r] * sc - mreg[r]);
      rsum[r] = p0 + p1;
      p_l[prow + r][llo] = f2b(p0);
      p_l[prow + r][16 + llo] = f2b(p1);
    }
#pragma unroll
    for (int off = 1; off < 16; off <<= 1)
#pragma unroll
      for (int r = 0; r < 4; ++r) rsum[r] += __shfl_xor(rsum[r], off);
#pragma unroll
    for (int r = 0; r < 4; ++r) lreg[r] += rsum[r];

    asm volatile("s_waitcnt lgkmcnt(0)" ::: "memory");
    __builtin_amdgcn_sched_barrier(0);

    // PV (swapped operands): O^T[d][n] += Vt_tile * P
    s8v pf = *(const s8v*)&p_l[w * 16 + llo][lhi * 8];
#pragma unroll
    for (int dt = 0; dt < 17; ++dt) {
      s8v vf = *(const s8v*)&vt_l[dt * 16 + llo][lhi * 8];
      oacc[dt] = MFMA16(vf, pf, oacc[dt]);
    }

    __syncthreads();
    if (mc < 31) {
      WRITE();
      __syncthreads();
      if (mc < 30) ISSUE();
    }
  }

  // epilogue
  float prep = (lane & 2) ? ((lane & 1) ? lreg[3] : lreg[2])
                          : ((lane & 1) ? lreg[1] : lreg[0]);
  float linv = 1.f / __shfl(prep, src16, 64);
  const int n = n0 + w * 16 + llo;
#pragma unroll
  for (int dt = 0; dt < 17; ++dt) {
#pragma unroll
    for (int r = 0; r < 4; ++r) {
      int d = dt * 16 + lhi * 4 + r;
      if (d < VF_) out[((size_t)(b * 558 + d) << 10) + n] = oacc[dt][r] * linv;
    }
  }
}

// ---------------- launcher ----------------
extern "C" void kernel_launch(void* const* d_in, const int* in_sizes, int n_in,
                              void* d_out, int out_size, void* d_ws, size_t ws_size,
                              hipStream_t stream) {
  const float* spatial = (const float*)d_in[0];
  const float* video   = (const float*)d_in[1];
  const float* txt     = (const float*)d_in[2];
  const float* c1w = (const float*)d_in[3];
  const float* c1b = (const float*)d_in[4];
  const float* g1g = (const float*)d_in[5];
  const float* g1b = (const float*)d_in[6];
  const float* c2w = (const float*)d_in[7];
  const float* c2b = (const float*)d_in[8];
  const float* g2g = (const float*)d_in[9];
  const float* g2b = (const float*)d_in[10];
  const float* rw  = (const float*)d_in[11];
  const float* rb  = (const float*)d_in[12];
  const float* kw  = (const float*)d_in[13];
  const float* kb  = (const float*)d_in[14];
  const float* qw  = (const float*)d_in[15];
  const float* qb  = (const float*)d_in[16];
  const float* vw  = (const float*)d_in[17];
  const float* vb  = (const float*)d_in[18];
  const float* iw  = (const float*)d_in[19];
  const float* ib  = (const float*)d_in[20];
  float* out = (float*)d_out;
  float* ws = (float*)d_ws;

  // ws layout (float offsets), lifetime-aliased
  ushort_t* x0h   = (ushort_t*)(ws + 0);          // [0, 4.72M) -> conv1
  float*    vsr   = ws + 0;                       // [0, 9.83M)  after x1h dead
  float*    y1    = ws + 5000000;                 // [5.0M, 9.2M)
  ushort_t* x1h   = (ushort_t*)(ws + 9300000);    // [9.3M, 11.4M)
  ushort_t* kb16  = (ushort_t*)(ws + 10000000);   // [10.0M, 14.72M)  after y2 dead
  float*    y2    = ws + 11500000;                // [11.5M, 19.9M)
  ushort_t* qb16  = (ushort_t*)(ws + 14800000);   // [14.8M, 19.52M)  after y2 dead
  ushort_t* vsoh  = (ushort_t*)(ws + 20000000);   // [20.0M, 24.72M)
  ushort_t* vtb16 = (ushort_t*)(ws + 24800000);   // [24.8M, 29.26M)
  ushort_t* rwp   = (ushort_t*)(ws + 29300000);
  ushort_t* kwp   = (ushort_t*)(ws + 29360000);
  ushort_t* qwp   = (ushort_t*)(ws + 29420000);
  ushort_t* vwp   = (ushort_t*)(ws + 29480000);
  ushort_t* w1r   = (ushort_t*)(ws + 29540000);
  ushort_t* w2r   = (ushort_t*)(ws + 29710000);
  float*    mod   = ws + 29860000;

  // weight prep
  k_wreorder2<<<(9 * 9 * 128 * 32 + TPB - 1) / TPB, TPB, 0, stream>>>(c1w, w1r, 128, 264, 9);
  k_wreorder2<<<(9 * 4 * 256 * 32 + TPB - 1) / TPB, TPB, 0, stream>>>(c2w, w2r, 256, 128, 4);
  {
    int tot = 384 * 288;
    k_wprep<<<(tot + TPB - 1) / TPB, TPB, 0, stream>>>(rw, rwp, 300);
    k_wprep<<<(tot + TPB - 1) / TPB, TPB, 0, stream>>>(kw, kwp, 258);
    k_wprep<<<(tot + TPB - 1) / TPB, TPB, 0, stream>>>(qw, qwp, 258);
    k_wprep<<<(tot + TPB - 1) / TPB, TPB, 0, stream>>>(vw, vwp, 258);
  }

  // concat -> NHWC bf16
  k_cat_nhwc<<<dim3(16, NB), TPB, 0, stream>>>(video, spatial, x0h);

  // conv1 (MFMA) + GN1 + relu -> NHWC bf16
  k_conv_mfma<36><<<dim3(16, 1, NB), TPB, 0, stream>>>(x0h, w1r, c1b, y1, C1);
  k_gnrelu<<<dim3(32, NB), TPB, 0, stream>>>(y1, g1g, g1b, C1, 4);
  k_to_nhwc128<<<dim3(16, NB), TPB, 0, stream>>>(y1, x1h);

  k_tmaxmod<<<NB, TPB, 0, stream>>>(txt, iw, ib, mod);

  // conv2 (MFMA) + GN2 + relu (c-major fp32)
  k_conv_mfma<16><<<dim3(16, 2, NB), TPB, 0, stream>>>(x1h, w2r, c2b, y2, C2);
  k_gnrelu<<<dim3(32, NB), TPB, 0, stream>>>(y2, g2g, g2b, C2, 8);

  // vso_h bf16 NHWC (+coords)
  k_build_vsoh<<<dim3(16, NB), TPB, 0, stream>>>(y2, vsoh);

  // vsr = vso @ reduce_w^T + reduce_b (MFMA, fp32 out)
  k_gemm_mfma<0><<<dim3(3, 8, NB), TPB, 0, stream>>>(vsoh, rwp, (void*)vsr, rb, nullptr);

  // txt attention -> out channels [258, 558)
  k_txtattn<<<dim3(4, NB), TPB, 0, stream>>>(vsr, txt, out);

  // k, q (bf16 [m][288], *mod), v (bf16 chunk-blocked Vt)
  k_gemm_mfma<1><<<dim3(3, 8, NB), TPB, 0, stream>>>(vsoh, kwp, (void*)kb16, kb, mod);
  k_gemm_mfma<1><<<dim3(3, 8, NB), TPB, 0, stream>>>(vsoh, qwp, (void*)qb16, qb, mod);
  k_gemm_mfma<2><<<dim3(3, 8, NB), TPB, 0, stream>>>(vsoh, vwp, (void*)vtb16, vb, nullptr);

  // video self-attention (bf16 MFMA flash) -> out channels [0, 258)
  k_flash_mfma<<<dim3(512), 256, 0, stream>>>(kb16, qb16, vtb16, out);
}

// Round 8
// 403.515 us; speedup vs baseline: 9.8171x; 1.1194x over previous
//
#include <hip/hip_runtime.h>
#include <cstddef>

#define TPB 256

typedef unsigned short ushort_t;
typedef __attribute__((ext_vector_type(8))) short s8v;
typedef __attribute__((ext_vector_type(4))) float f4v;

#define MFMA16(a, b, c) __builtin_amdgcn_mfma_f32_16x16x32_bf16((a), (b), (c), 0, 0, 0)

static const int NB   = 32;    // batch
static const int NPIX = 1024;  // 32x32
static const int CIN  = 264;
static const int C1   = 128;
static const int C2   = 256;
static const int VF_  = 258;
static const int DS_  = 300;
static const int LL   = 20;

__device__ __forceinline__ ushort_t f2b(float x) {
  unsigned u = __builtin_bit_cast(unsigned, x);
  u = (u + 0x7fffu + ((u >> 16) & 1u)) >> 16;
  return (ushort_t)u;
}

// ---------------- fused prep kernel ----------------
// block ranges:
//  [0,1296)      wreorder2 conv1 (Cout=128, Cin=264, NS=9)
//  [1296,2448)   wreorder2 conv2 (Cout=256, Cin=128, NS=4)
//  [2448,2880)   wprep rw (N=300)
//  [2880,3312)   wprep kw (N=258)
//  [3312,3744)   wprep qw (N=258)
//  [3744,4176)   wprep vw (N=258)
//  [4176,4208)   tmaxmod (b = bid)
//  [4208,4720)   cat_nhwc (t = bid: pb = t%16, b = t/16)
__global__ __launch_bounds__(TPB) void k_prep(
    const float* __restrict__ c1w, const float* __restrict__ c2w,
    const float* __restrict__ rw, const float* __restrict__ kw,
    const float* __restrict__ qw, const float* __restrict__ vw,
    const float* __restrict__ txt, const float* __restrict__ iw,
    const float* __restrict__ ib,
    const float* __restrict__ video, const float* __restrict__ spatial,
    ushort_t* __restrict__ w1r, ushort_t* __restrict__ w2r,
    ushort_t* __restrict__ rwp, ushort_t* __restrict__ kwp,
    ushort_t* __restrict__ qwp, ushort_t* __restrict__ vwp,
    float* __restrict__ mod, ushort_t* __restrict__ x0h) {
  int bid = blockIdx.x;
  const int tid = threadIdx.x;

  if (bid < 1296) {  // wreorder2 conv1
    int i = bid * TPB + tid;
    if (i < 9 * 9 * 128 * 32) {
      int j = i & 31;
      int oc = (i >> 5) % 128;
      int ts = (i >> 5) / 128;
      int s = ts % 9, t = ts / 9;
      int ic = s * 32 + j;
      float v = (ic < 264) ? c1w[((size_t)oc * 264 + ic) * 9 + t] : 0.f;
      w1r[i] = f2b(v);
    }
    return;
  }
  bid -= 1296;
  if (bid < 1152) {  // wreorder2 conv2
    int i = bid * TPB + tid;
    if (i < 9 * 4 * 256 * 32) {
      int j = i & 31;
      int oc = (i >> 5) % 256;
      int ts = (i >> 5) / 256;
      int s = ts % 4, t = ts / 4;
      int ic = s * 32 + j;
      float v = (ic < 128) ? c2w[((size_t)oc * 128 + ic) * 9 + t] : 0.f;
      w2r[i] = f2b(v);
    }
    return;
  }
  bid -= 1152;
  if (bid < 4 * 432) {  // wprep x4
    int which = bid / 432;
    int i = (bid - which * 432) * TPB + tid;
    if (i < 384 * 288) {
      int n = i / 288, k = i - n * 288;
      const float* src = (which == 0) ? rw : (which == 1) ? kw : (which == 2) ? qw : vw;
      int N = (which == 0) ? 300 : 258;
      float v = (n < N && k < 258) ? src[(size_t)n * 258 + k] : 0.f;
      ushort_t* dst = (which == 0) ? rwp : (which == 1) ? kwp : (which == 2) ? qwp : vwp;
      dst[i] = f2b(v);
    }
    return;
  }
  bid -= 4 * 432;
  if (bid < 32) {  // tmaxmod, b = bid
    int b = bid;
    __shared__ float tm[DS_];
    for (int d = tid; d < DS_; d += TPB) {
      const float* p = txt + ((size_t)b * DS_ + d) * LL;
      float m = p[0];
      for (int l = 1; l < LL; ++l) m = fmaxf(m, p[l]);
      tm[d] = m;
    }
    __syncthreads();
    for (int oc = tid; oc < VF_; oc += TPB) {
      const float* wr = iw + (size_t)oc * DS_;
      float s = ib[oc];
      for (int d = 0; d < DS_; ++d) s += tm[d] * wr[d];
      mod[(size_t)b * VF_ + oc] = s;
    }
    return;
  }
  bid -= 32;
  {  // cat_nhwc
    const int pb = bid & 15;
    const int b = bid >> 4;
    __shared__ ushort_t lds[264][72];
    for (int u = tid; u < 264 * 64; u += TPB) {
      int c = u >> 6, px = u & 63;
      int p = (pb << 6) + px;
      float v = (c < 256) ? video[(((size_t)b * 256 + c) << 10) + p]
                          : spatial[(((size_t)b * 8 + (c - 256)) << 10) + p];
      lds[c][px] = f2b(v);
    }
    __syncthreads();
    for (int u = tid; u < 64 * 36; u += TPB) {
      int px = u / 36, ch = u - px * 36;
      s8v v;
#pragma unroll
      for (int j = 0; j < 8; ++j) {
        int ic = ch * 8 + j;
        v[j] = (ic < 264) ? (short)lds[ic][px] : (short)0;
      }
      *(s8v*)(x0h + ((size_t)((b << 10) + (pb << 6) + px)) * 288 + ch * 8) = v;
    }
  }
}

// ---------------- conv 3x3 via bf16 MFMA implicit GEMM (+GN stats) ----------------
// in_h: NHWC bf16 [b][1024][ICPAD]; wr: [t][s][Cout][32] bf16; out: fp32 c-major.
// stats[((b*Cout+oc)*16+pxb)*2 + {0,1}] = (sum, sumsq) over the block's 64 px.
template <int ICG>
__global__ __launch_bounds__(TPB) void k_conv_mfma(const ushort_t* __restrict__ in_h,
                                                   const ushort_t* __restrict__ wr,
                                                   const float* __restrict__ bias,
                                                   float* __restrict__ out,
                                                   float* __restrict__ stats, int Cout) {
  const int ICPAD = ICG * 8;
  const int NS = ICG / 4;
  const int ICGS = 4 * 34 * 8 + 24;  // 1112 elems = 556 dw; 556%32=12 -> spread
  const int b   = blockIdx.z;
  const int ocb = blockIdx.y << 7;
  const int pxb = blockIdx.x;
  const int tid = threadIdx.x;
  const int w = tid >> 6, lane = tid & 63;
  const int lhi = lane >> 4, llo = lane & 15;

  __shared__ ushort_t in_t[ICG * ICGS];

  // zero x-halo columns (col 0 and 33, every icg, every row)
  for (int u = tid; u < ICG * 8; u += TPB) {
    int icg = u >> 3, rem = u & 7, row = rem >> 1, col = (rem & 1) ? 33 : 0;
    *(s8v*)&in_t[icg * ICGS + (row * 34 + col) * 8] = (s8v){0, 0, 0, 0, 0, 0, 0, 0};
  }
  // rows: linear coalesced copy (or zero when out of image)
  for (int r = 0; r < 4; ++r) {
    int gy = (pxb << 1) - 1 + r;
    if ((unsigned)gy < 32u) {
      const ushort_t* src = in_h + ((size_t)((b << 10) + (gy << 5))) * ICPAD;
      for (int u = tid; u < 32 * ICG; u += TPB) {
        int px = u / ICG, icg = u - px * ICG;
        *(s8v*)&in_t[icg * ICGS + (r * 34 + px + 1) * 8] = *(const s8v*)(src + u * 8);
      }
    } else {
      for (int u = tid; u < 32 * ICG; u += TPB) {
        int px = u / ICG, icg = u - px * ICG;
        *(s8v*)&in_t[icg * ICGS + (r * 34 + px + 1) * 8] = (s8v){0, 0, 0, 0, 0, 0, 0, 0};
      }
    }
  }
  __syncthreads();

  f4v acc[2][4];
#pragma unroll
  for (int i = 0; i < 2; ++i)
#pragma unroll
    for (int m = 0; m < 4; ++m) acc[i][m] = (f4v){0.f, 0.f, 0.f, 0.f};

  for (int t = 0; t < 9; ++t) {
    const int ky = t / 3, kx = t - ky * 3;
#pragma unroll
    for (int s = 0; s < NS; ++s) {
      const ushort_t* wp = wr + (((size_t)(t * NS + s) * Cout + ocb + w * 32 + llo) << 5) + lhi * 8;
      s8v a0 = *(const s8v*)(wp);
      s8v a1 = *(const s8v*)(wp + (16 << 5));
      const int icg = (s << 2) + lhi;
#pragma unroll
      for (int m = 0; m < 4; ++m) {
        const int row = (m >> 1) + ky;
        const int col = ((m & 1) << 4) + llo + kx;
        s8v bm = *(const s8v*)&in_t[icg * ICGS + (row * 34 + col) * 8];
        acc[0][m] = MFMA16(a0, bm, acc[0][m]);
        acc[1][m] = MFMA16(a1, bm, acc[1][m]);
      }
    }
  }

#pragma unroll
  for (int i = 0; i < 2; ++i) {
#pragma unroll
    for (int r = 0; r < 4; ++r) {
      const int oc = ocb + w * 32 + i * 16 + lhi * 4 + r;
      const float bv = bias[oc];
      float sm = 0.f, sq = 0.f;
#pragma unroll
      for (int m = 0; m < 4; ++m) {
        const int px = (pxb << 6) + (m << 4) + llo;
        float v = acc[i][m][r] + bv;
        out[(((size_t)b * Cout + oc) << 10) + px] = v;
        sm += v;
        sq += v * v;
      }
#pragma unroll
      for (int off = 1; off < 16; off <<= 1) {
        sm += __shfl_xor(sm, off);
        sq += __shfl_xor(sq, off);
      }
      if (llo == 0) {
        size_t sidx = ((((size_t)b * Cout + oc) << 4) + pxb) << 1;
        stats[sidx] = sm;
        stats[sidx + 1] = sq;
      }
    }
  }
}

// ---------------- GN finalize: partials -> per-channel scale/shift ----------------
__global__ __launch_bounds__(64) void k_gnfin(const float* __restrict__ stats,
                                              const float* __restrict__ gamma,
                                              const float* __restrict__ beta,
                                              float* __restrict__ scale,
                                              float* __restrict__ shift,
                                              int C, int cpg) {
  const int g = blockIdx.x, b = blockIdx.y;
  const int n = cpg << 4;
  float s = 0.f, q = 0.f;
  for (int i = threadIdx.x; i < n; i += 64) {
    int c = g * cpg + (i >> 4), pxb = i & 15;
    size_t idx = ((((size_t)b * C + c) << 4) + pxb) << 1;
    s += stats[idx];
    q += stats[idx + 1];
  }
#pragma unroll
  for (int off = 32; off > 0; off >>= 1) {
    s += __shfl_xor(s, off);
    q += __shfl_xor(q, off);
  }
  const float M = (float)(cpg << 10);
  float mean = s / M;
  float rsig = rsqrtf(q / M - mean * mean + 1e-5f);
  if ((int)threadIdx.x < cpg) {
    int c = g * cpg + threadIdx.x;
    float sc = rsig * gamma[c];
    scale[(size_t)b * C + c] = sc;
    shift[(size_t)b * C + c] = beta[c] - mean * sc;
  }
}

// ---------------- c-major fp32 -> NHWC bf16 with fused GN+ReLU ----------------
__global__ __launch_bounds__(TPB) void k_to_nhwc128(const float* __restrict__ src,
                                                    const float* __restrict__ scale,
                                                    const float* __restrict__ shift,
                                                    ushort_t* __restrict__ dst) {
  const int pb = blockIdx.x;
  const int b  = blockIdx.y;
  const int tid = threadIdx.x;
  __shared__ ushort_t lds[128][72];
  for (int u = tid; u < 128 * 64; u += TPB) {
    int c = u >> 6, px = u & 63;
    int p = (pb << 6) + px;
    float v = src[(((size_t)b * 128 + c) << 10) + p];
    v = fmaxf(v * scale[(size_t)b * 128 + c] + shift[(size_t)b * 128 + c], 0.f);
    lds[c][px] = f2b(v);
  }
  __syncthreads();
  for (int u = tid; u < 64 * 16; u += TPB) {
    int px = u >> 4, ch = u & 15;
    s8v v;
#pragma unroll
    for (int j = 0; j < 8; ++j) v[j] = (short)lds[ch * 8 + j][px];
    *(s8v*)(dst + ((size_t)((b << 10) + (pb << 6) + px)) * 128 + ch * 8) = v;
  }
}

// y2 (c-major fp32, raw conv) + fused GN+ReLU + coords -> vso_h bf16 [b][1024][288]
__global__ __launch_bounds__(TPB) void k_build_vsoh(const float* __restrict__ y2,
                                                    const float* __restrict__ scale,
                                                    const float* __restrict__ shift,
                                                    ushort_t* __restrict__ dst) {
  const int pb = blockIdx.x;
  const int b  = blockIdx.y;
  const int tid = threadIdx.x;
  __shared__ ushort_t lds[256][72];
  for (int u = tid; u < 256 * 64; u += TPB) {
    int c = u >> 6, px = u & 63;
    int p = (pb << 6) + px;
    float v = y2[(((size_t)b * 256 + c) << 10) + p];
    v = fmaxf(v * scale[(size_t)b * 256 + c] + shift[(size_t)b * 256 + c], 0.f);
    lds[c][px] = f2b(v);
  }
  __syncthreads();
  for (int u = tid; u < 64 * 36; u += TPB) {
    int px = u / 36, ch = u - px * 36;
    int p = (pb << 6) + px;
    s8v v;
#pragma unroll
    for (int j = 0; j < 8; ++j) {
      int cg = ch * 8 + j;
      float fv;
      if (cg < 256)      { v[j] = (short)lds[cg][px]; continue; }
      else if (cg == 256) fv = -1.f + (2.f / 31.f) * (float)(p & 31);
      else if (cg == 257) fv = -1.f + (2.f / 31.f) * (float)(p >> 5);
      else                fv = 0.f;
      v[j] = (short)f2b(fv);
    }
    *(s8v*)(dst + ((size_t)((b << 10) + p)) * 288 + ch * 8) = v;
  }
}

// ---------------- bf16 MFMA GEMM: out = vso_h @ W^T (+bias [, *mod]) ----------------
template <int MODE>
__global__ __launch_bounds__(TPB) void k_gemm_mfma(const ushort_t* __restrict__ A,
                                                   const ushort_t* __restrict__ Bw,
                                                   void* __restrict__ Cout,
                                                   const float* __restrict__ bias,
                                                   const float* __restrict__ mod) {
  const int b = blockIdx.z;
  const int n0 = blockIdx.x << 7;
  const int m0 = blockIdx.y << 7;
  const int tid = threadIdx.x;
  const int w = tid >> 6, lane = tid & 63;
  const int wr = w >> 1, wc = w & 1;
  const int lhi = lane >> 4, llo = lane & 15;

  __shared__ ushort_t A_l[128][40];
  __shared__ ushort_t B_l[128][40];

  f4v acc[4][4];
#pragma unroll
  for (int i = 0; i < 4; ++i)
#pragma unroll
    for (int j = 0; j < 4; ++j) acc[i][j] = (f4v){0.f, 0.f, 0.f, 0.f};

  const ushort_t* Ab = A + (((size_t)b << 10)) * 288;

  for (int k0 = 0; k0 < 288; k0 += 32) {
    for (int u = tid; u < 512; u += TPB) {
      int row = u >> 2, seg = u & 3;
      *(s8v*)&A_l[row][seg * 8] = *(const s8v*)(Ab + (size_t)(m0 + row) * 288 + k0 + seg * 8);
      *(s8v*)&B_l[row][seg * 8] = *(const s8v*)(Bw + (size_t)(n0 + row) * 288 + k0 + seg * 8);
    }
    __syncthreads();
    s8v am[4], bn[4];
#pragma unroll
    for (int i = 0; i < 4; ++i) am[i] = *(const s8v*)&A_l[wr * 64 + i * 16 + llo][lhi * 8];
#pragma unroll
    for (int j = 0; j < 4; ++j) bn[j] = *(const s8v*)&B_l[wc * 64 + j * 16 + llo][lhi * 8];
#pragma unroll
    for (int i = 0; i < 4; ++i)
#pragma unroll
      for (int j = 0; j < 4; ++j) {
        if (MODE == 2) acc[i][j] = MFMA16(bn[j], am[i], acc[i][j]);
        else           acc[i][j] = MFMA16(am[i], bn[j], acc[i][j]);
      }
    __syncthreads();
  }

  if (MODE == 0) {
    float* Cf = (float*)Cout + (size_t)b * 1024 * 300;
#pragma unroll
    for (int j = 0; j < 4; ++j) {
      int n = n0 + wc * 64 + j * 16 + llo;
      if (n >= 300) continue;
      float bv = bias[n];
#pragma unroll
      for (int i = 0; i < 4; ++i)
#pragma unroll
        for (int r = 0; r < 4; ++r) {
          int m = m0 + wr * 64 + i * 16 + lhi * 4 + r;
          Cf[(size_t)m * 300 + n] = acc[i][j][r] + bv;
        }
    }
  } else if (MODE == 1) {
    ushort_t* Cb = (ushort_t*)Cout + (size_t)b * 1024 * 288;
#pragma unroll
    for (int j = 0; j < 4; ++j) {
      int n = n0 + wc * 64 + j * 16 + llo;
      if (n >= 288) continue;
      bool real = n < VF_;
      float bv = real ? bias[n] : 0.f;
      float sm = real ? mod[(size_t)b * VF_ + n] : 0.f;
#pragma unroll
      for (int i = 0; i < 4; ++i)
#pragma unroll
        for (int r = 0; r < 4; ++r) {
          int m = m0 + wr * 64 + i * 16 + lhi * 4 + r;
          Cb[(size_t)m * 288 + n] = f2b(real ? (acc[i][j][r] + bv) * sm : 0.f);
        }
    }
  } else {
    // chunk-blocked transposed store: Vt_blk[b][m>>5][n][m&31]
    ushort_t* Cb = (ushort_t*)Cout + (size_t)b * 32 * 272 * 32;
#pragma unroll
    for (int j = 0; j < 4; ++j)
#pragma unroll
      for (int r = 0; r < 4; ++r) {
        int n = n0 + wc * 64 + j * 16 + lhi * 4 + r;
        if (n >= 272) continue;
        bool real = n < VF_;
        float bv = real ? bias[n] : 0.f;
#pragma unroll
        for (int i = 0; i < 4; ++i) {
          int m = m0 + wr * 64 + i * 16 + llo;
          int mc = m >> 5, mlo = m & 31;
          Cb[(((size_t)mc * 272 + n) << 5) + mlo] = f2b(real ? acc[i][j][r] + bv : 0.f);
        }
      }
  }
}

// ---------------- txt cross-attention ----------------
__global__ __launch_bounds__(TPB) void k_txtattn(const float* __restrict__ vsr,
                                                 const float* __restrict__ txt,
                                                 float* __restrict__ out) {
  const int b = blockIdx.y;
  const int p = blockIdx.x * TPB + threadIdx.x;
  __shared__ float tl[DS_ * LL];
  for (int i = threadIdx.x; i < DS_ * LL; i += TPB) tl[i] = txt[(size_t)b * DS_ * LL + i];
  __syncthreads();
  const float* vr = vsr + ((size_t)b * NPIX + p) * DS_;
  float lg[LL];
#pragma unroll
  for (int l = 0; l < LL; ++l) lg[l] = 0.f;
  for (int d = 0; d < DS_; d += 4) {
    float4 vv = *(const float4*)(vr + d);
    const float* tr = tl + d * LL;
#pragma unroll
    for (int l = 0; l < LL; ++l)
      lg[l] += vv.x * tr[l] + vv.y * tr[l + 20] + vv.z * tr[l + 40] + vv.w * tr[l + 60];
  }
  const float sc = 0.057735026919f;
  float mx = lg[0] * sc;
#pragma unroll
  for (int l = 1; l < LL; ++l) mx = fmaxf(mx, lg[l] * sc);
  float sum = 0.f;
#pragma unroll
  for (int l = 0; l < LL; ++l) {
    lg[l] = __expf(lg[l] * sc - mx);
    sum += lg[l];
  }
  float inv = 1.f / sum;
#pragma unroll
  for (int l = 0; l < LL; ++l) lg[l] *= inv;
  float* ob = out + (((size_t)b * 558 + VF_) << 10) + p;
  for (int d = 0; d < DS_; ++d) {
    const float* tr = tl + d * LL;
    float s = 0.f;
#pragma unroll
    for (int l = 0; l < LL; ++l) s += lg[l] * tr[l];
    ob[(size_t)d << 10] = s;
  }
}

// ---------------- video self-attention: bf16 MFMA flash (R6 version) ----------------
// K,Q: bf16 [b][1024][288]. Vt_blk: bf16 [b][32][272][32].
__global__ __launch_bounds__(256, 2) void k_flash_mfma(const ushort_t* __restrict__ Kb,
                                                       const ushort_t* __restrict__ Qb,
                                                       const ushort_t* __restrict__ Vtb,
                                                       float* __restrict__ out) {
  // XCD-aware swizzle: all 16 n-blocks of a batch on one XCD
  const int wg = blockIdx.x;           // 0..511
  const int xcd = wg & 7, s = wg >> 3; // s 0..63
  const int b = xcd * 4 + (s >> 4);
  const int n0 = (s & 15) << 6;
  const int tid = threadIdx.x;
  const int w = tid >> 6, lane = tid & 63;
  const int lhi = lane >> 4;
  const int llo = lane & 15;

  __shared__ ushort_t q_l[32][296];   // stride 296 (148 dw) -> 2-way
  __shared__ ushort_t vt_l[272][36];  // stride 36 (18 dw)  -> 2-way
  __shared__ ushort_t p_l[64][36];

  s8v kf[9];
  {
    const ushort_t* kp = Kb + ((size_t)(b * 1024 + n0 + w * 16 + llo)) * 288 + lhi * 8;
#pragma unroll
    for (int ks = 0; ks < 9; ++ks) kf[ks] = *(const s8v*)(kp + ks * 32);
  }

  const ushort_t* Qbase = Qb + (((size_t)b << 10)) * 288;
  const ushort_t* Vbase = Vtb + (size_t)b * 32 * 272 * 32;

  s8v qs[5], vs[5];
  // stage issue: chunk mc -> regs
  auto ISSUE = [&](int mc) {
#pragma unroll
    for (int i = 0; i < 5; ++i) {
      int u = tid + (i << 8);
      if (u < 1152) qs[i] = *(const s8v*)(Qbase + (size_t)((mc << 5) + u / 36) * 288 + (u % 36) * 8);
      if (u < 1088) vs[i] = *(const s8v*)(Vbase + (size_t)mc * 8704 + (u << 3));
    }
  };
  // regs -> LDS
  auto WRITE = [&]() {
#pragma unroll
    for (int i = 0; i < 5; ++i) {
      int u = tid + (i << 8);
      if (u < 1152) *(s8v*)&q_l[u / 36][(u % 36) * 8] = qs[i];
      if (u < 1088) *(s8v*)&vt_l[u >> 2][(u & 3) * 8] = vs[i];
    }
  };

  f4v oacc[17];
#pragma unroll
  for (int i = 0; i < 17; ++i) oacc[i] = (f4v){0.f, 0.f, 0.f, 0.f};
  float mreg[4], lreg[4];
#pragma unroll
  for (int r = 0; r < 4; ++r) { mreg[r] = -1e30f; lreg[r] = 0.f; }

  const float sc = 0.0622572819f;  // 1/sqrt(258)
  const int src16 = ((llo >> 2) << 4) | (llo & 3);

  // prologue
  ISSUE(0);
  WRITE();
  __syncthreads();
  ISSUE(1);

  for (int mc = 0; mc < 32; ++mc) {
    // QK^T on LDS chunk mc
    f4v sacc0 = {0.f, 0.f, 0.f, 0.f}, sacc1 = {0.f, 0.f, 0.f, 0.f};
#pragma unroll
    for (int ks = 0; ks < 9; ++ks) {
      s8v q0 = *(const s8v*)&q_l[llo][ks * 32 + lhi * 8];
      s8v q1 = *(const s8v*)&q_l[16 + llo][ks * 32 + lhi * 8];
      sacc0 = MFMA16(kf[ks], q0, sacc0);
      sacc1 = MFMA16(kf[ks], q1, sacc1);
    }

    // wave-parallel online softmax
    float cmax[4], rsum[4], alpha[4];
#pragma unroll
    for (int r = 0; r < 4; ++r) cmax[r] = fmaxf(sacc0[r], sacc1[r]);
#pragma unroll
    for (int off = 1; off < 16; off <<= 1)
#pragma unroll
      for (int r = 0; r < 4; ++r) cmax[r] = fmaxf(cmax[r], __shfl_xor(cmax[r], off));
#pragma unroll
    for (int r = 0; r < 4; ++r) {
      float mn = fmaxf(mreg[r], cmax[r] * sc);
      alpha[r] = __expf(mreg[r] - mn);
      mreg[r] = mn;
    }
    const int prow = w * 16 + lhi * 4;
#pragma unroll
    for (int r = 0; r < 4; ++r) {
      float p0 = __expf(sacc0[r] * sc - mreg[r]);
      float p1 = __expf(sacc1[r] * sc - mreg[r]);
      rsum[r] = p0 + p1;
      p_l[prow + r][llo] = f2b(p0);
      p_l[prow + r][16 + llo] = f2b(p1);
    }
#pragma unroll
    for (int off = 1; off < 16; off <<= 1)
#pragma unroll
      for (int r = 0; r < 4; ++r) rsum[r] += __shfl_xor(rsum[r], off);
#pragma unroll
    for (int r = 0; r < 4; ++r) lreg[r] = lreg[r] * alpha[r] + rsum[r];

    float prep = (lane & 2) ? ((lane & 1) ? alpha[3] : alpha[2])
                            : ((lane & 1) ? alpha[1] : alpha[0]);
    float alphaN = __shfl(prep, src16, 64);

    asm volatile("s_waitcnt lgkmcnt(0)" ::: "memory");
    __builtin_amdgcn_sched_barrier(0);

    // PV (swapped operands): O^T[d][n] += Vt_tile * P
    s8v pf = *(const s8v*)&p_l[w * 16 + llo][lhi * 8];
#pragma unroll
    for (int dt = 0; dt < 17; ++dt) {
      s8v vf = *(const s8v*)&vt_l[dt * 16 + llo][lhi * 8];
      f4v o = oacc[dt];
      o[0] *= alphaN; o[1] *= alphaN; o[2] *= alphaN; o[3] *= alphaN;
      oacc[dt] = MFMA16(vf, pf, o);
    }

    __syncthreads();  // all waves done reading chunk mc from LDS
    if (mc < 31) {
      WRITE();        // chunk mc+1 -> LDS
      __syncthreads();
      if (mc < 30) ISSUE(mc + 2);
    }
  }

  // epilogue
  float prep = (lane & 2) ? ((lane & 1) ? lreg[3] : lreg[2])
                          : ((lane & 1) ? lreg[1] : lreg[0]);
  float linv = 1.f / __shfl(prep, src16, 64);
  const int n = n0 + w * 16 + llo;
#pragma unroll
  for (int dt = 0; dt < 17; ++dt) {
#pragma unroll
    for (int r = 0; r < 4; ++r) {
      int d = dt * 16 + lhi * 4 + r;
      if (d < VF_) out[((size_t)(b * 558 + d) << 10) + n] = oacc[dt][r] * linv;
    }
  }
}

// ---------------- launcher ----------------
extern "C" void kernel_launch(void* const* d_in, const int* in_sizes, int n_in,
                              void* d_out, int out_size, void* d_ws, size_t ws_size,
                              hipStream_t stream) {
  const float* spatial = (const float*)d_in[0];
  const float* video   = (const float*)d_in[1];
  const float* txt     = (const float*)d_in[2];
  const float* c1w = (const float*)d_in[3];
  const float* c1b = (const float*)d_in[4];
  const float* g1g = (const float*)d_in[5];
  const float* g1b = (const float*)d_in[6];
  const float* c2w = (const float*)d_in[7];
  const float* c2b = (const float*)d_in[8];
  const float* g2g = (const float*)d_in[9];
  const float* g2b = (const float*)d_in[10];
  const float* rw  = (const float*)d_in[11];
  const float* rb  = (const float*)d_in[12];
  const float* kw  = (const float*)d_in[13];
  const float* kb  = (const float*)d_in[14];
  const float* qw  = (const float*)d_in[15];
  const float* qb  = (const float*)d_in[16];
  const float* vw  = (const float*)d_in[17];
  const float* vb  = (const float*)d_in[18];
  const float* iw  = (const float*)d_in[19];
  const float* ib  = (const float*)d_in[20];
  float* out = (float*)d_out;
  float* ws = (float*)d_ws;

  // ws layout (float offsets), lifetime-aliased
  ushort_t* x0h    = (ushort_t*)(ws + 0);          // [0, 4.72M) -> conv1
  float*    vsr    = ws + 0;                       // [0, 9.83M)  after x1h dead
  float*    y1     = ws + 5000000;                 // [5.0M, 9.2M)
  ushort_t* x1h    = (ushort_t*)(ws + 9300000);    // [9.3M, 11.4M)
  ushort_t* kb16   = (ushort_t*)(ws + 10000000);   // [10.0M, 14.72M)  after x1h dead
  float*    y2     = ws + 11500000;                // [11.5M, 19.9M)
  ushort_t* qb16   = (ushort_t*)(ws + 14800000);   // [14.8M, 19.52M)  after y2 dead
  ushort_t* vsoh   = (ushort_t*)(ws + 20000000);   // [20.0M, 24.72M)
  ushort_t* vtb16  = (ushort_t*)(ws + 24800000);   // [24.8M, 29.26M)
  ushort_t* rwp    = (ushort_t*)(ws + 29300000);
  ushort_t* kwp    = (ushort_t*)(ws + 29360000);
  ushort_t* qwp    = (ushort_t*)(ws + 29420000);
  ushort_t* vwp    = (ushort_t*)(ws + 29480000);
  ushort_t* w1r    = (ushort_t*)(ws + 29540000);
  ushort_t* w2r    = (ushort_t*)(ws + 29710000);
  float*    mod    = ws + 29860000;                // 8,256
  float*    stats1 = ws + 29900000;                // 131,072
  float*    stats2 = ws + 30100000;                // 262,144
  float*    scale1 = ws + 30400000;                // 4,096
  float*    shift1 = ws + 30410000;                // 4,096
  float*    scale2 = ws + 30420000;                // 8,192
  float*    shift2 = ws + 30430000;                // 8,192

  // all prep (weights, mod, concat) in one dispatch
  k_prep<<<dim3(4720), TPB, 0, stream>>>(c1w, c2w, rw, kw, qw, vw, txt, iw, ib,
                                         video, spatial,
                                         w1r, w2r, rwp, kwp, qwp, vwp, mod, x0h);

  // conv1 (MFMA + GN stats) -> y1 fp32 c-major; finalize; transpose+GN+relu -> x1h
  k_conv_mfma<36><<<dim3(16, 1, NB), TPB, 0, stream>>>(x0h, w1r, c1b, y1, stats1, C1);
  k_gnfin<<<dim3(32, NB), 64, 0, stream>>>(stats1, g1g, g1b, scale1, shift1, C1, 4);
  k_to_nhwc128<<<dim3(16, NB), TPB, 0, stream>>>(y1, scale1, shift1, x1h);

  // conv2 (MFMA + GN stats) -> y2; finalize; vsoh (GN+relu+coords)
  k_conv_mfma<16><<<dim3(16, 2, NB), TPB, 0, stream>>>(x1h, w2r, c2b, y2, stats2, C2);
  k_gnfin<<<dim3(32, NB), 64, 0, stream>>>(stats2, g2g, g2b, scale2, shift2, C2, 8);
  k_build_vsoh<<<dim3(16, NB), TPB, 0, stream>>>(y2, scale2, shift2, vsoh);

  // vsr = vso @ reduce_w^T + reduce_b (MFMA, fp32 out)
  k_gemm_mfma<0><<<dim3(3, 8, NB), TPB, 0, stream>>>(vsoh, rwp, (void*)vsr, rb, nullptr);

  // txt attention -> out channels [258, 558)
  k_txtattn<<<dim3(4, NB), TPB, 0, stream>>>(vsr, txt, out);

  // k, q (bf16 [m][288], *mod), v (bf16 chunk-blocked Vt)
  k_gemm_mfma<1><<<dim3(3, 8, NB), TPB, 0, stream>>>(vsoh, kwp, (void*)kb16, kb, mod);
  k_gemm_mfma<1><<<dim3(3, 8, NB), TPB, 0, stream>>>(vsoh, qwp, (void*)qb16, qb, mod);
  k_gemm_mfma<2><<<dim3(3, 8, NB), TPB, 0, stream>>>(vsoh, vwp, (void*)vtb16, vb, nullptr);

  // video self-attention (bf16 MFMA flash) -> out channels [0, 258)
  k_flash_mfma<<<dim3(512), 256, 0, stream>>>(kb16, qb16, vtb16, out);
}

// Round 9
// 369.509 us; speedup vs baseline: 10.7205x; 1.0920x over previous
//
#include <hip/hip_runtime.h>
#include <cstddef>

#define TPB 256

typedef unsigned short ushort_t;
typedef __attribute__((ext_vector_type(8))) short s8v;
typedef __attribute__((ext_vector_type(4))) float f4v;
typedef __attribute__((ext_vector_type(4))) unsigned u4v;

#define MFMA16(a, b, c) __builtin_amdgcn_mfma_f32_16x16x32_bf16((a), (b), (c), 0, 0, 0)

static const int NB   = 32;    // batch
static const int NPIX = 1024;  // 32x32
static const int CIN  = 264;
static const int C1   = 128;
static const int C2   = 256;
static const int VF_  = 258;
static const int DS_  = 300;
static const int LL   = 20;

__device__ __forceinline__ ushort_t f2b(float x) {
  unsigned u = __builtin_bit_cast(unsigned, x);
  u = (u + 0x7fffu + ((u >> 16) & 1u)) >> 16;
  return (ushort_t)u;
}

// ---------------- fused prep kernel ----------------
__global__ __launch_bounds__(TPB) void k_prep(
    const float* __restrict__ c1w, const float* __restrict__ c2w,
    const float* __restrict__ rw, const float* __restrict__ kw,
    const float* __restrict__ qw, const float* __restrict__ vw,
    const float* __restrict__ txt, const float* __restrict__ iw,
    const float* __restrict__ ib,
    const float* __restrict__ video, const float* __restrict__ spatial,
    ushort_t* __restrict__ w1r, ushort_t* __restrict__ w2r,
    ushort_t* __restrict__ rwp, ushort_t* __restrict__ kwp,
    ushort_t* __restrict__ qwp, ushort_t* __restrict__ vwp,
    float* __restrict__ mod, ushort_t* __restrict__ x0h) {
  int bid = blockIdx.x;
  const int tid = threadIdx.x;

  if (bid < 1296) {  // wreorder2 conv1
    int i = bid * TPB + tid;
    if (i < 9 * 9 * 128 * 32) {
      int j = i & 31;
      int oc = (i >> 5) % 128;
      int ts = (i >> 5) / 128;
      int s = ts % 9, t = ts / 9;
      int ic = s * 32 + j;
      float v = (ic < 264) ? c1w[((size_t)oc * 264 + ic) * 9 + t] : 0.f;
      w1r[i] = f2b(v);
    }
    return;
  }
  bid -= 1296;
  if (bid < 1152) {  // wreorder2 conv2
    int i = bid * TPB + tid;
    if (i < 9 * 4 * 256 * 32) {
      int j = i & 31;
      int oc = (i >> 5) % 256;
      int ts = (i >> 5) / 256;
      int s = ts % 4, t = ts / 4;
      int ic = s * 32 + j;
      float v = (ic < 128) ? c2w[((size_t)oc * 128 + ic) * 9 + t] : 0.f;
      w2r[i] = f2b(v);
    }
    return;
  }
  bid -= 1152;
  if (bid < 4 * 432) {  // wprep x4
    int which = bid / 432;
    int i = (bid - which * 432) * TPB + tid;
    if (i < 384 * 288) {
      int n = i / 288, k = i - n * 288;
      const float* src = (which == 0) ? rw : (which == 1) ? kw : (which == 2) ? qw : vw;
      int N = (which == 0) ? 300 : 258;
      float v = (n < N && k < 258) ? src[(size_t)n * 258 + k] : 0.f;
      ushort_t* dst = (which == 0) ? rwp : (which == 1) ? kwp : (which == 2) ? qwp : vwp;
      dst[i] = f2b(v);
    }
    return;
  }
  bid -= 4 * 432;
  if (bid < 32) {  // tmaxmod, b = bid
    int b = bid;
    __shared__ float tm[DS_];
    for (int d = tid; d < DS_; d += TPB) {
      const float* p = txt + ((size_t)b * DS_ + d) * LL;
      float m = p[0];
      for (int l = 1; l < LL; ++l) m = fmaxf(m, p[l]);
      tm[d] = m;
    }
    __syncthreads();
    for (int oc = tid; oc < VF_; oc += TPB) {
      const float* wr = iw + (size_t)oc * DS_;
      float s = ib[oc];
      for (int d = 0; d < DS_; ++d) s += tm[d] * wr[d];
      mod[(size_t)b * VF_ + oc] = s;
    }
    return;
  }
  bid -= 32;
  {  // cat_nhwc
    const int pb = bid & 15;
    const int b = bid >> 4;
    __shared__ ushort_t lds[264][72];
    for (int u = tid; u < 264 * 64; u += TPB) {
      int c = u >> 6, px = u & 63;
      int p = (pb << 6) + px;
      float v = (c < 256) ? video[(((size_t)b * 256 + c) << 10) + p]
                          : spatial[(((size_t)b * 8 + (c - 256)) << 10) + p];
      lds[c][px] = f2b(v);
    }
    __syncthreads();
    for (int u = tid; u < 64 * 36; u += TPB) {
      int px = u / 36, ch = u - px * 36;
      s8v v;
#pragma unroll
      for (int j = 0; j < 8; ++j) {
        int ic = ch * 8 + j;
        v[j] = (ic < 264) ? (short)lds[ic][px] : (short)0;
      }
      *(s8v*)(x0h + ((size_t)((b << 10) + (pb << 6) + px)) * 288 + ch * 8) = v;
    }
  }
}

// ---------------- conv 3x3 via bf16 MFMA implicit GEMM (+GN stats) ----------------
template <int ICG>
__global__ __launch_bounds__(TPB) void k_conv_mfma(const ushort_t* __restrict__ in_h,
                                                   const ushort_t* __restrict__ wr,
                                                   const float* __restrict__ bias,
                                                   float* __restrict__ out,
                                                   float* __restrict__ stats, int Cout) {
  const int ICPAD = ICG * 8;
  const int NS = ICG / 4;
  const int ICGS = 4 * 34 * 8 + 24;
  const int b   = blockIdx.z;
  const int ocb = blockIdx.y << 7;
  const int pxb = blockIdx.x;
  const int tid = threadIdx.x;
  const int w = tid >> 6, lane = tid & 63;
  const int lhi = lane >> 4, llo = lane & 15;

  __shared__ ushort_t in_t[ICG * ICGS];

  for (int u = tid; u < ICG * 8; u += TPB) {
    int icg = u >> 3, rem = u & 7, row = rem >> 1, col = (rem & 1) ? 33 : 0;
    *(s8v*)&in_t[icg * ICGS + (row * 34 + col) * 8] = (s8v){0, 0, 0, 0, 0, 0, 0, 0};
  }
  for (int r = 0; r < 4; ++r) {
    int gy = (pxb << 1) - 1 + r;
    if ((unsigned)gy < 32u) {
      const ushort_t* src = in_h + ((size_t)((b << 10) + (gy << 5))) * ICPAD;
      for (int u = tid; u < 32 * ICG; u += TPB) {
        int px = u / ICG, icg = u - px * ICG;
        *(s8v*)&in_t[icg * ICGS + (r * 34 + px + 1) * 8] = *(const s8v*)(src + u * 8);
      }
    } else {
      for (int u = tid; u < 32 * ICG; u += TPB) {
        int px = u / ICG, icg = u - px * ICG;
        *(s8v*)&in_t[icg * ICGS + (r * 34 + px + 1) * 8] = (s8v){0, 0, 0, 0, 0, 0, 0, 0};
      }
    }
  }
  __syncthreads();

  f4v acc[2][4];
#pragma unroll
  for (int i = 0; i < 2; ++i)
#pragma unroll
    for (int m = 0; m < 4; ++m) acc[i][m] = (f4v){0.f, 0.f, 0.f, 0.f};

  for (int t = 0; t < 9; ++t) {
    const int ky = t / 3, kx = t - ky * 3;
#pragma unroll
    for (int s = 0; s < NS; ++s) {
      const ushort_t* wp = wr + (((size_t)(t * NS + s) * Cout + ocb + w * 32 + llo) << 5) + lhi * 8;
      s8v a0 = *(const s8v*)(wp);
      s8v a1 = *(const s8v*)(wp + (16 << 5));
      const int icg = (s << 2) + lhi;
#pragma unroll
      for (int m = 0; m < 4; ++m) {
        const int row = (m >> 1) + ky;
        const int col = ((m & 1) << 4) + llo + kx;
        s8v bm = *(const s8v*)&in_t[icg * ICGS + (row * 34 + col) * 8];
        acc[0][m] = MFMA16(a0, bm, acc[0][m]);
        acc[1][m] = MFMA16(a1, bm, acc[1][m]);
      }
    }
  }

#pragma unroll
  for (int i = 0; i < 2; ++i) {
#pragma unroll
    for (int r = 0; r < 4; ++r) {
      const int oc = ocb + w * 32 + i * 16 + lhi * 4 + r;
      const float bv = bias[oc];
      float sm = 0.f, sq = 0.f;
#pragma unroll
      for (int m = 0; m < 4; ++m) {
        const int px = (pxb << 6) + (m << 4) + llo;
        float v = acc[i][m][r] + bv;
        out[(((size_t)b * Cout + oc) << 10) + px] = v;
        sm += v;
        sq += v * v;
      }
#pragma unroll
      for (int off = 1; off < 16; off <<= 1) {
        sm += __shfl_xor(sm, off);
        sq += __shfl_xor(sq, off);
      }
      if (llo == 0) {
        size_t sidx = ((((size_t)b * Cout + oc) << 4) + pxb) << 1;
        stats[sidx] = sm;
        stats[sidx + 1] = sq;
      }
    }
  }
}

// ---------------- GN finalize ----------------
__global__ __launch_bounds__(64) void k_gnfin(const float* __restrict__ stats,
                                              const float* __restrict__ gamma,
                                              const float* __restrict__ beta,
                                              float* __restrict__ scale,
                                              float* __restrict__ shift,
                                              int C, int cpg) {
  const int g = blockIdx.x, b = blockIdx.y;
  const int n = cpg << 4;
  float s = 0.f, q = 0.f;
  for (int i = threadIdx.x; i < n; i += 64) {
    int c = g * cpg + (i >> 4), pxb = i & 15;
    size_t idx = ((((size_t)b * C + c) << 4) + pxb) << 1;
    s += stats[idx];
    q += stats[idx + 1];
  }
#pragma unroll
  for (int off = 32; off > 0; off >>= 1) {
    s += __shfl_xor(s, off);
    q += __shfl_xor(q, off);
  }
  const float M = (float)(cpg << 10);
  float mean = s / M;
  float rsig = rsqrtf(q / M - mean * mean + 1e-5f);
  if ((int)threadIdx.x < cpg) {
    int c = g * cpg + threadIdx.x;
    float sc = rsig * gamma[c];
    scale[(size_t)b * C + c] = sc;
    shift[(size_t)b * C + c] = beta[c] - mean * sc;
  }
}

// ---------------- c-major fp32 -> NHWC bf16 with fused GN+ReLU ----------------
__global__ __launch_bounds__(TPB) void k_to_nhwc128(const float* __restrict__ src,
                                                    const float* __restrict__ scale,
                                                    const float* __restrict__ shift,
                                                    ushort_t* __restrict__ dst) {
  const int pb = blockIdx.x;
  const int b  = blockIdx.y;
  const int tid = threadIdx.x;
  __shared__ ushort_t lds[128][72];
  for (int u = tid; u < 128 * 64; u += TPB) {
    int c = u >> 6, px = u & 63;
    int p = (pb << 6) + px;
    float v = src[(((size_t)b * 128 + c) << 10) + p];
    v = fmaxf(v * scale[(size_t)b * 128 + c] + shift[(size_t)b * 128 + c], 0.f);
    lds[c][px] = f2b(v);
  }
  __syncthreads();
  for (int u = tid; u < 64 * 16; u += TPB) {
    int px = u >> 4, ch = u & 15;
    s8v v;
#pragma unroll
    for (int j = 0; j < 8; ++j) v[j] = (short)lds[ch * 8 + j][px];
    *(s8v*)(dst + ((size_t)((b << 10) + (pb << 6) + px)) * 128 + ch * 8) = v;
  }
}

// y2 + fused GN+ReLU + coords -> vso_h bf16 [b][1024][288]
__global__ __launch_bounds__(TPB) void k_build_vsoh(const float* __restrict__ y2,
                                                    const float* __restrict__ scale,
                                                    const float* __restrict__ shift,
                                                    ushort_t* __restrict__ dst) {
  const int pb = blockIdx.x;
  const int b  = blockIdx.y;
  const int tid = threadIdx.x;
  __shared__ ushort_t lds[256][72];
  for (int u = tid; u < 256 * 64; u += TPB) {
    int c = u >> 6, px = u & 63;
    int p = (pb << 6) + px;
    float v = y2[(((size_t)b * 256 + c) << 10) + p];
    v = fmaxf(v * scale[(size_t)b * 256 + c] + shift[(size_t)b * 256 + c], 0.f);
    lds[c][px] = f2b(v);
  }
  __syncthreads();
  for (int u = tid; u < 64 * 36; u += TPB) {
    int px = u / 36, ch = u - px * 36;
    int p = (pb << 6) + px;
    s8v v;
#pragma unroll
    for (int j = 0; j < 8; ++j) {
      int cg = ch * 8 + j;
      float fv;
      if (cg < 256)      { v[j] = (short)lds[cg][px]; continue; }
      else if (cg == 256) fv = -1.f + (2.f / 31.f) * (float)(p & 31);
      else if (cg == 257) fv = -1.f + (2.f / 31.f) * (float)(p >> 5);
      else                fv = 0.f;
      v[j] = (short)f2b(fv);
    }
    *(s8v*)(dst + ((size_t)((b << 10) + p)) * 288 + ch * 8) = v;
  }
}

// ---------------- bf16 MFMA GEMM: out = vso_h @ W^T (+bias [, *mod]) ----------------
// MODE 1: bf16 out [b][1024][288], *mod    (k, q)
// MODE 2: bf16 out chunk-blocked Vt [b][32][272][32]  (v)
// MODE 3: fp32 out transposed [b][300][1024]          (vsr)
template <int MODE>
__global__ __launch_bounds__(TPB) void k_gemm_mfma(const ushort_t* __restrict__ A,
                                                   const ushort_t* __restrict__ Bw,
                                                   void* __restrict__ Cout,
                                                   const float* __restrict__ bias,
                                                   const float* __restrict__ mod) {
  const int b = blockIdx.z;
  const int n0 = blockIdx.x << 7;
  const int m0 = blockIdx.y << 7;
  const int tid = threadIdx.x;
  const int w = tid >> 6, lane = tid & 63;
  const int wr = w >> 1, wc = w & 1;
  const int lhi = lane >> 4, llo = lane & 15;

  __shared__ ushort_t A_l[128][40];
  __shared__ ushort_t B_l[128][40];

  f4v acc[4][4];
#pragma unroll
  for (int i = 0; i < 4; ++i)
#pragma unroll
    for (int j = 0; j < 4; ++j) acc[i][j] = (f4v){0.f, 0.f, 0.f, 0.f};

  const ushort_t* Ab = A + (((size_t)b << 10)) * 288;

  for (int k0 = 0; k0 < 288; k0 += 32) {
    for (int u = tid; u < 512; u += TPB) {
      int row = u >> 2, seg = u & 3;
      *(s8v*)&A_l[row][seg * 8] = *(const s8v*)(Ab + (size_t)(m0 + row) * 288 + k0 + seg * 8);
      *(s8v*)&B_l[row][seg * 8] = *(const s8v*)(Bw + (size_t)(n0 + row) * 288 + k0 + seg * 8);
    }
    __syncthreads();
    s8v am[4], bn[4];
#pragma unroll
    for (int i = 0; i < 4; ++i) am[i] = *(const s8v*)&A_l[wr * 64 + i * 16 + llo][lhi * 8];
#pragma unroll
    for (int j = 0; j < 4; ++j) bn[j] = *(const s8v*)&B_l[wc * 64 + j * 16 + llo][lhi * 8];
#pragma unroll
    for (int i = 0; i < 4; ++i)
#pragma unroll
      for (int j = 0; j < 4; ++j) {
        if (MODE >= 2) acc[i][j] = MFMA16(bn[j], am[i], acc[i][j]);
        else           acc[i][j] = MFMA16(am[i], bn[j], acc[i][j]);
      }
    __syncthreads();
  }

  if (MODE == 1) {
    ushort_t* Cb = (ushort_t*)Cout + (size_t)b * 1024 * 288;
#pragma unroll
    for (int j = 0; j < 4; ++j) {
      int n = n0 + wc * 64 + j * 16 + llo;
      if (n >= 288) continue;
      bool real = n < VF_;
      float bv = real ? bias[n] : 0.f;
      float sm = real ? mod[(size_t)b * VF_ + n] : 0.f;
#pragma unroll
      for (int i = 0; i < 4; ++i)
#pragma unroll
        for (int r = 0; r < 4; ++r) {
          int m = m0 + wr * 64 + i * 16 + lhi * 4 + r;
          Cb[(size_t)m * 288 + n] = f2b(real ? (acc[i][j][r] + bv) * sm : 0.f);
        }
    }
  } else if (MODE == 2) {
    // chunk-blocked transposed store: Vt_blk[b][m>>5][n][m&31]
    ushort_t* Cb = (ushort_t*)Cout + (size_t)b * 32 * 272 * 32;
#pragma unroll
    for (int j = 0; j < 4; ++j)
#pragma unroll
      for (int r = 0; r < 4; ++r) {
        int n = n0 + wc * 64 + j * 16 + lhi * 4 + r;
        if (n >= 272) continue;
        bool real = n < VF_;
        float bv = real ? bias[n] : 0.f;
#pragma unroll
        for (int i = 0; i < 4; ++i) {
          int m = m0 + wr * 64 + i * 16 + llo;
          int mc = m >> 5, mlo = m & 31;
          Cb[(((size_t)mc * 272 + n) << 5) + mlo] = f2b(real ? acc[i][j][r] + bv : 0.f);
        }
      }
  } else {
    // MODE 3: fp32 transposed [300][1024]
    float* Cf = (float*)Cout + (size_t)b * 300 * 1024;
#pragma unroll
    for (int j = 0; j < 4; ++j)
#pragma unroll
      for (int r = 0; r < 4; ++r) {
        int n = n0 + wc * 64 + j * 16 + lhi * 4 + r;
        if (n >= 300) continue;
        float bv = bias[n];
#pragma unroll
        for (int i = 0; i < 4; ++i) {
          int m = m0 + wr * 64 + i * 16 + llo;
          Cf[((size_t)n << 10) + m] = acc[i][j][r] + bv;
        }
      }
  }
}

// ---------------- txt cross-attention (vsr transposed [b][300][1024]) ----------------
__global__ __launch_bounds__(TPB) void k_txtattn(const float* __restrict__ vsrT,
                                                 const float* __restrict__ txt,
                                                 float* __restrict__ out) {
  const int b = blockIdx.y;
  const int p = blockIdx.x * TPB + threadIdx.x;
  __shared__ float tl[DS_ * LL];
  for (int i = threadIdx.x; i < DS_ * LL; i += TPB) tl[i] = txt[(size_t)b * DS_ * LL + i];
  __syncthreads();
  const float* vr = vsrT + ((size_t)b * DS_ << 10) + p;
  float lg[LL];
#pragma unroll
  for (int l = 0; l < LL; ++l) lg[l] = 0.f;
  for (int d = 0; d < DS_; d += 4) {
    float v0 = vr[(size_t)(d + 0) << 10];
    float v1 = vr[(size_t)(d + 1) << 10];
    float v2 = vr[(size_t)(d + 2) << 10];
    float v3 = vr[(size_t)(d + 3) << 10];
    const float* tr = tl + d * LL;
#pragma unroll
    for (int l = 0; l < LL; ++l)
      lg[l] += v0 * tr[l] + v1 * tr[l + 20] + v2 * tr[l + 40] + v3 * tr[l + 60];
  }
  const float sc = 0.057735026919f;
  float mx = lg[0] * sc;
#pragma unroll
  for (int l = 1; l < LL; ++l) mx = fmaxf(mx, lg[l] * sc);
  float sum = 0.f;
#pragma unroll
  for (int l = 0; l < LL; ++l) {
    lg[l] = __expf(lg[l] * sc - mx);
    sum += lg[l];
  }
  float inv = 1.f / sum;
#pragma unroll
  for (int l = 0; l < LL; ++l) lg[l] *= inv;
  float* ob = out + (((size_t)b * 558 + VF_) << 10) + p;
  for (int d = 0; d < DS_; ++d) {
    const float* tr = tl + d * LL;
    float s = 0.f;
#pragma unroll
    for (int l = 0; l < LL; ++l) s += lg[l] * tr[l];
    ob[(size_t)d << 10] = s;
  }
}

// ---------------- video self-attention: bf16 MFMA flash, in-register softmax ----------------
// K,Q: bf16 [b][1024][288]. Vt_blk: bf16 [b][32][272][32].
// QK^T computed swapped (S^T[m][n]) so each lane owns one n column -> lane-local softmax.
__global__ __launch_bounds__(256, 2) void k_flash_mfma(const ushort_t* __restrict__ Kb,
                                                       const ushort_t* __restrict__ Qb,
                                                       const ushort_t* __restrict__ Vtb,
                                                       float* __restrict__ out) {
  const int wg = blockIdx.x;           // 0..511
  const int xcd = wg & 7, s = wg >> 3;
  const int b = xcd * 4 + (s >> 4);
  const int n0 = (s & 15) << 6;
  const int tid = threadIdx.x;
  const int w = tid >> 6, lane = tid & 63;
  const int lhi = lane >> 4;
  const int llo = lane & 15;

  __shared__ ushort_t q_l[32][296];   // stride 296 -> 2-way banks
  __shared__ ushort_t vt_l[272][36];  // stride 36  -> 2-way banks

  s8v kf[9];
  {
    const ushort_t* kp = Kb + ((size_t)(b * 1024 + n0 + w * 16 + llo)) * 288 + lhi * 8;
#pragma unroll
    for (int ks = 0; ks < 9; ++ks) kf[ks] = *(const s8v*)(kp + ks * 32);
  }

  const ushort_t* Qbase = Qb + (((size_t)b << 10)) * 288;
  const ushort_t* Vbase = Vtb + (size_t)b * 32 * 272 * 32;

  s8v qs[5], vs[5];
  auto ISSUE = [&](int mc) {
#pragma unroll
    for (int i = 0; i < 5; ++i) {
      int u = tid + (i << 8);
      if (u < 1152) qs[i] = *(const s8v*)(Qbase + (size_t)((mc << 5) + u / 36) * 288 + (u % 36) * 8);
      if (u < 1088) vs[i] = *(const s8v*)(Vbase + (size_t)mc * 8704 + (u << 3));
    }
  };
  auto WRITE = [&]() {
#pragma unroll
    for (int i = 0; i < 5; ++i) {
      int u = tid + (i << 8);
      if (u < 1152) *(s8v*)&q_l[u / 36][(u % 36) * 8] = qs[i];
      if (u < 1088) *(s8v*)&vt_l[u >> 2][(u & 3) * 8] = vs[i];
    }
  };

  f4v oacc[17];
#pragma unroll
  for (int i = 0; i < 17; ++i) oacc[i] = (f4v){0.f, 0.f, 0.f, 0.f};
  float mreg = -1e30f, lreg = 0.f;  // per-lane: own column n = n0 + w*16 + llo

  const float sc = 0.0622572819f;  // 1/sqrt(258)
  const int srcA = llo + ((lhi & 1) << 5);
  const int srcB = srcA + 16;
  const bool hi2 = lhi >= 2;

  ISSUE(0);
  WRITE();
  __syncthreads();
  ISSUE(1);

  for (int mc = 0; mc < 32; ++mc) {
    // S^T[m][n]: rows m (A = Q rows), cols n (B = K rows)
    f4v sacc0 = {0.f, 0.f, 0.f, 0.f}, sacc1 = {0.f, 0.f, 0.f, 0.f};
#pragma unroll
    for (int ks = 0; ks < 9; ++ks) {
      s8v q0 = *(const s8v*)&q_l[llo][ks * 32 + lhi * 8];
      s8v q1 = *(const s8v*)&q_l[16 + llo][ks * 32 + lhi * 8];
      sacc0 = MFMA16(q0, kf[ks], sacc0);
      sacc1 = MFMA16(q1, kf[ks], sacc1);
    }

    // lane-local online softmax for column n (8 m-values/lane, reduce across lhi groups)
    float pmax = fmaxf(fmaxf(fmaxf(sacc0[0], sacc0[1]), fmaxf(sacc0[2], sacc0[3])),
                       fmaxf(fmaxf(sacc1[0], sacc1[1]), fmaxf(sacc1[2], sacc1[3])));
    pmax = fmaxf(pmax, __shfl_xor(pmax, 16));
    pmax = fmaxf(pmax, __shfl_xor(pmax, 32));
    float mn = fmaxf(mreg, pmax * sc);
    float alpha = __expf(mreg - mn);
    mreg = mn;

    float p0[4], p1[4];
    float rsum = 0.f;
#pragma unroll
    for (int r = 0; r < 4; ++r) {
      p0[r] = __expf(sacc0[r] * sc - mn);
      p1[r] = __expf(sacc1[r] * sc - mn);
      rsum += p0[r] + p1[r];
    }
    rsum += __shfl_xor(rsum, 16);
    rsum += __shfl_xor(rsum, 32);
    lreg = lreg * alpha + rsum;

    // pack P to bf16 pairs and permute into the PV B-fragment (m = lhi*8..+8, col n=llo)
    unsigned u0, u1, u2, u3;
    asm("v_cvt_pk_bf16_f32 %0, %1, %2" : "=v"(u0) : "v"(p0[0]), "v"(p0[1]));
    asm("v_cvt_pk_bf16_f32 %0, %1, %2" : "=v"(u1) : "v"(p0[2]), "v"(p0[3]));
    asm("v_cvt_pk_bf16_f32 %0, %1, %2" : "=v"(u2) : "v"(p1[0]), "v"(p1[1]));
    asm("v_cvt_pk_bf16_f32 %0, %1, %2" : "=v"(u3) : "v"(p1[2]), "v"(p1[3]));
    unsigned s0a = __shfl(u0, srcA, 64), s2a = __shfl(u2, srcA, 64);
    unsigned s1a = __shfl(u1, srcA, 64), s3a = __shfl(u3, srcA, 64);
    unsigned s0b = __shfl(u0, srcB, 64), s2b = __shfl(u2, srcB, 64);
    unsigned s1b = __shfl(u1, srcB, 64), s3b = __shfl(u3, srcB, 64);
    u4v pu;
    pu[0] = hi2 ? s2a : s0a;
    pu[1] = hi2 ? s3a : s1a;
    pu[2] = hi2 ? s2b : s0b;
    pu[3] = hi2 ? s3b : s1b;
    s8v pf = __builtin_bit_cast(s8v, pu);

    // PV (swapped operands): O^T[d][n] += Vt_tile * P
#pragma unroll
    for (int dt = 0; dt < 17; ++dt) {
      s8v vf = *(const s8v*)&vt_l[dt * 16 + llo][lhi * 8];
      f4v o = oacc[dt];
      o[0] *= alpha; o[1] *= alpha; o[2] *= alpha; o[3] *= alpha;
      oacc[dt] = MFMA16(vf, pf, o);
    }

    __syncthreads();  // all waves done reading chunk mc from LDS
    if (mc < 31) {
      WRITE();        // chunk mc+1 -> LDS
      __syncthreads();
      if (mc < 30) ISSUE(mc + 2);
    }
  }

  // epilogue (lreg uniform across lhi for this lane's n)
  float linv = 1.f / lreg;
  const int n = n0 + w * 16 + llo;
#pragma unroll
  for (int dt = 0; dt < 17; ++dt) {
#pragma unroll
    for (int r = 0; r < 4; ++r) {
      int d = dt * 16 + lhi * 4 + r;
      if (d < VF_) out[((size_t)(b * 558 + d) << 10) + n] = oacc[dt][r] * linv;
    }
  }
}

// ---------------- launcher ----------------
extern "C" void kernel_launch(void* const* d_in, const int* in_sizes, int n_in,
                              void* d_out, int out_size, void* d_ws, size_t ws_size,
                              hipStream_t stream) {
  const float* spatial = (const float*)d_in[0];
  const float* video   = (const float*)d_in[1];
  const float* txt     = (const float*)d_in[2];
  const float* c1w = (const float*)d_in[3];
  const float* c1b = (const float*)d_in[4];
  const float* g1g = (const float*)d_in[5];
  const float* g1b = (const float*)d_in[6];
  const float* c2w = (const float*)d_in[7];
  const float* c2b = (const float*)d_in[8];
  const float* g2g = (const float*)d_in[9];
  const float* g2b = (const float*)d_in[10];
  const float* rw  = (const float*)d_in[11];
  const float* rb  = (const float*)d_in[12];
  const float* kw  = (const float*)d_in[13];
  const float* kb  = (const float*)d_in[14];
  const float* qw  = (const float*)d_in[15];
  const float* qb  = (const float*)d_in[16];
  const float* vw  = (const float*)d_in[17];
  const float* vb  = (const float*)d_in[18];
  const float* iw  = (const float*)d_in[19];
  const float* ib  = (const float*)d_in[20];
  float* out = (float*)d_out;
  float* ws = (float*)d_ws;

  // ws layout (float offsets), lifetime-aliased
  ushort_t* x0h    = (ushort_t*)(ws + 0);          // [0, 4.72M) -> conv1
  float*    vsr    = ws + 0;                       // [0, 9.83M)  (transposed [300][1024]) after x1h dead
  float*    y1     = ws + 5000000;                 // [5.0M, 9.2M)
  ushort_t* x1h    = (ushort_t*)(ws + 9300000);    // [9.3M, 11.4M)
  ushort_t* kb16   = (ushort_t*)(ws + 10000000);   // [10.0M, 14.72M)  after x1h dead
  float*    y2     = ws + 11500000;                // [11.5M, 19.9M)
  ushort_t* qb16   = (ushort_t*)(ws + 14800000);   // [14.8M, 19.52M)  after y2 dead
  ushort_t* vsoh   = (ushort_t*)(ws + 20000000);   // [20.0M, 24.72M)
  ushort_t* vtb16  = (ushort_t*)(ws + 24800000);   // [24.8M, 29.26M)
  ushort_t* rwp    = (ushort_t*)(ws + 29300000);
  ushort_t* kwp    = (ushort_t*)(ws + 29360000);
  ushort_t* qwp    = (ushort_t*)(ws + 29420000);
  ushort_t* vwp    = (ushort_t*)(ws + 29480000);
  ushort_t* w1r    = (ushort_t*)(ws + 29540000);
  ushort_t* w2r    = (ushort_t*)(ws + 29710000);
  float*    mod    = ws + 29860000;                // 8,256
  float*    stats1 = ws + 29900000;                // 131,072
  float*    stats2 = ws + 30100000;                // 262,144
  float*    scale1 = ws + 30400000;                // 4,096
  float*    shift1 = ws + 30410000;                // 4,096
  float*    scale2 = ws + 30420000;                // 8,192
  float*    shift2 = ws + 30430000;                // 8,192

  // all prep (weights, mod, concat) in one dispatch
  k_prep<<<dim3(4720), TPB, 0, stream>>>(c1w, c2w, rw, kw, qw, vw, txt, iw, ib,
                                         video, spatial,
                                         w1r, w2r, rwp, kwp, qwp, vwp, mod, x0h);

  // conv1 (MFMA + GN stats); finalize; transpose+GN+relu -> x1h
  k_conv_mfma<36><<<dim3(16, 1, NB), TPB, 0, stream>>>(x0h, w1r, c1b, y1, stats1, C1);
  k_gnfin<<<dim3(32, NB), 64, 0, stream>>>(stats1, g1g, g1b, scale1, shift1, C1, 4);
  k_to_nhwc128<<<dim3(16, NB), TPB, 0, stream>>>(y1, scale1, shift1, x1h);

  // conv2 (MFMA + GN stats); finalize; vsoh (GN+relu+coords)
  k_conv_mfma<16><<<dim3(16, 2, NB), TPB, 0, stream>>>(x1h, w2r, c2b, y2, stats2, C2);
  k_gnfin<<<dim3(32, NB), 64, 0, stream>>>(stats2, g2g, g2b, scale2, shift2, C2, 8);
  k_build_vsoh<<<dim3(16, NB), TPB, 0, stream>>>(y2, scale2, shift2, vsoh);

  // vsr (transposed fp32 [300][1024]) = vso @ reduce_w^T + reduce_b
  k_gemm_mfma<3><<<dim3(3, 8, NB), TPB, 0, stream>>>(vsoh, rwp, (void*)vsr, rb, nullptr);

  // txt attention -> out channels [258, 558)
  k_txtattn<<<dim3(4, NB), TPB, 0, stream>>>(vsr, txt, out);

  // k, q (bf16 [m][288], *mod), v (bf16 chunk-blocked Vt)
  k_gemm_mfma<1><<<dim3(3, 8, NB), TPB, 0, stream>>>(vsoh, kwp, (void*)kb16, kb, mod);
  k_gemm_mfma<1><<<dim3(3, 8, NB), TPB, 0, stream>>>(vsoh, qwp, (void*)qb16, qb, mod);
  k_gemm_mfma<2><<<dim3(3, 8, NB), TPB, 0, stream>>>(vsoh, vwp, (void*)vtb16, vb, nullptr);

  // video self-attention (bf16 MFMA flash) -> out channels [0, 258)
  k_flash_mfma<<<dim3(512), 256, 0, stream>>>(kb16, qb16, vtb16, out);
}